// Round 1
// 850.469 us; speedup vs baseline: 1.3691x; 1.3691x over previous
//
#include <hip/hip_runtime.h>

#define BSZ 4
#define TSEQ 4096
#define DM 1024
#define NH 16
#define HD 64
#define BT (BSZ * TSEQ)
#define INV_LOSCALE (1.0f / 4096.0f)

using f32x4 = __attribute__((ext_vector_type(4))) float;
using f16x8 = __attribute__((ext_vector_type(8))) _Float16;
using u32x2 = __attribute__((ext_vector_type(2))) unsigned;
using u32x4 = __attribute__((ext_vector_type(4))) unsigned;

typedef const __attribute__((address_space(1))) void* gas_ptr;
typedef __attribute__((address_space(3))) void* las_ptr;

// Async global->LDS, 16 B per lane. LDS dest must be uniform-base + lane*16
// within each wave; we always pass base + tid*16 which satisfies that.
__device__ __forceinline__ void gload16(const void* g, void* l) {
    __builtin_amdgcn_global_load_lds((gas_ptr)g, (las_ptr)l, 16, 0, 0);
}

// f16 RTN split: x = hi + lo/4096 + r. lo pre-scaled by 4096 (denormal immunity).
__device__ __forceinline__ void split1(float x, _Float16& h, _Float16& l) {
    h = (_Float16)x;
    l = (_Float16)((x - (float)h) * 4096.0f);
}
__device__ __forceinline__ unsigned pack2(_Float16 a, _Float16 b) {
    return (unsigned)__builtin_bit_cast(unsigned short, a) |
           ((unsigned)__builtin_bit_cast(unsigned short, b) << 16);
}
__device__ __forceinline__ f32x4 mfma_f16(f16x8 a, f16x8 b, f32x4 c) {
    return __builtin_amdgcn_mfma_f32_16x16x32_f16(a, b, c, 0, 0, 0);
}

// ---------------------------------------------------------------------------
// Fragment-linear layout: row-major [R][1024] fp32 -> per 64-row panel, per
// 32-k step, a 64x32 tile stored as 256 x 16B chunks ordered
// chunk = [rb(4)][kquad(4)][l15(16)], i.e. exactly the order a wave's 64
// lanes read f16x8 fragments (lane i -> bytes i*16). Element (row,k) lives at
// chunk ((row>>4)*4 + ((k&31)>>3))*16 + (row&15), elem (k&7).
// ---------------------------------------------------------------------------
__global__ __launch_bounds__(256) void fragsplit_kernel(const float* __restrict__ in,
        _Float16* __restrict__ hi, _Float16* __restrict__ lo) {
    const int C = blockIdx.x * 256 + threadIdx.x;      // global chunk id
    const int l15 = C & 15, quad = (C >> 4) & 3, rb = (C >> 6) & 3;
    const int s = (C >> 8) & 31, panel = C >> 13;
    const size_t src = ((size_t)(panel * 64 + rb * 16 + l15)) * DM + s * 32 + quad * 8;
    f32x4 v0 = *(const f32x4*)&in[src];
    f32x4 v1 = *(const f32x4*)&in[src + 4];
    _Float16 h[8], l[8];
    #pragma unroll
    for (int j = 0; j < 4; ++j) { split1(v0[j], h[j], l[j]); split1(v1[j], h[4 + j], l[4 + j]); }
    ((u32x4*)hi)[C] = (u32x4){pack2(h[0],h[1]), pack2(h[2],h[3]), pack2(h[4],h[5]), pack2(h[6],h[7])};
    ((u32x4*)lo)[C] = (u32x4){pack2(l[0],l[1]), pack2(l[2],l[3]), pack2(l[4],l[5]), pack2(l[6],l[7])};
}

// ---------------------------------------------------------------------------
// Wq/Wk/Wv [h][k][n] -> transposed fragment-linear hi/lo f16 (panel = head).
// ---------------------------------------------------------------------------
__global__ __launch_bounds__(256) void wsplit_kernel(
    const float* __restrict__ Wq, const float* __restrict__ Wk, const float* __restrict__ Wv,
    _Float16* __restrict__ qh, _Float16* __restrict__ ql,
    _Float16* __restrict__ kh, _Float16* __restrict__ kl,
    _Float16* __restrict__ vh, _Float16* __restrict__ vl) {
    const int tid = threadIdx.x;
    const int k0 = blockIdx.x * 64, h = blockIdx.y, w = blockIdx.z;
    const float* __restrict__ W = (w == 0) ? Wq : (w == 1) ? Wk : Wv;
    _Float16* __restrict__ dh = (w == 0) ? qh : (w == 1) ? kh : vh;
    _Float16* __restrict__ dl = (w == 0) ? ql : (w == 1) ? kl : vl;
    __shared__ __align__(16) float ws_[64][68];
    #pragma unroll
    for (int it = 0; it < 4; ++it) {
        int idx = it * 256 + tid;
        int r = idx >> 4, c4 = (idx & 15) * 4;
        *(f32x4*)&ws_[r][c4] = *(const f32x4*)&W[((size_t)h * DM + k0 + r) * HD + c4];
    }
    __syncthreads();
    const int n = tid >> 2, kq16 = (tid & 3) * 16;
    _Float16 hh[16], ll[16];
    #pragma unroll
    for (int j = 0; j < 16; ++j) split1(ws_[kq16 + j][n], hh[j], ll[j]);
    #pragma unroll
    for (int c = 0; c < 2; ++c) {
        int kg = k0 + kq16 + c * 8;
        int s = kg >> 5, quad = (kg >> 3) & 3;
        size_t chunk = (size_t)(h * 32 + s) * 256 + ((n >> 4) * 4 + quad) * 16 + (n & 15);
        ((u32x4*)dh)[chunk] = (u32x4){pack2(hh[c*8+0],hh[c*8+1]), pack2(hh[c*8+2],hh[c*8+3]),
                                      pack2(hh[c*8+4],hh[c*8+5]), pack2(hh[c*8+6],hh[c*8+7])};
        ((u32x4*)dl)[chunk] = (u32x4){pack2(ll[c*8+0],ll[c*8+1]), pack2(ll[c*8+2],ll[c*8+3]),
                                      pack2(ll[c*8+4],ll[c*8+5]), pack2(ll[c*8+6],ll[c*8+7])};
    }
}

// ---------------------------------------------------------------------------
// Kernel 1: kh = (kv@Wk+bk)^2, vh = kv@Wv+bv via 3-term f16-split MFMA.
// All staging via global_load_lds from fragment-linear buffers; all fragment
// ds_reads lane-linear (conflict-free). LDS union: staging (24K) reused as
// khs/vhs fp32 scratch (32K) for the rank-64 reduction. atomicAdd commit.
// ---------------------------------------------------------------------------
__global__ __launch_bounds__(256, 3) void kv_stats_kernel(
    const _Float16* __restrict__ kv_hi, const _Float16* __restrict__ kv_lo,
    const _Float16* __restrict__ wkt_hi, const _Float16* __restrict__ wkt_lo,
    const _Float16* __restrict__ wvt_hi, const _Float16* __restrict__ wvt_lo,
    const float* __restrict__ bk, const float* __restrict__ bv,
    float* __restrict__ kv_sum, float* __restrict__ ksum)
{
    const int tid = threadIdx.x;
    const int lane = tid & 63, wave = tid >> 6, quad = lane >> 4, l15 = lane & 15;
    const int b = blockIdx.z, h = blockIdx.y, bx = blockIdx.x;

    __shared__ __align__(16) char smem[32768];
    _Float16* a_hi = (_Float16*)smem;                 // 4K each
    _Float16* a_lo = (_Float16*)(smem + 4096);
    _Float16* bkh_ = (_Float16*)(smem + 8192);
    _Float16* bkl_ = (_Float16*)(smem + 12288);
    _Float16* bvh_ = (_Float16*)(smem + 16384);
    _Float16* bvl_ = (_Float16*)(smem + 20480);
    float* khs = (float*)smem;                        // epilogue reuse (16K each)
    float* vhs = (float*)(smem + 16384);

    const int isV = wave >> 1, w1 = wave & 1;
    f32x4 acc_h[2][4] = {}, acc_c[2][4] = {};

    const size_t atile = (size_t)(b * 64 + bx) * 32;  // A tile index base (per panel)
    const size_t btile = (size_t)h * 32;              // B tile index base (per head)
    const int co = tid * 8;                           // f16 chunk offset in tile

    for (int s = 0; s < 32; ++s) {
        const size_t ao = (atile + s) * 2048 + co;
        const size_t bo = (btile + s) * 2048 + co;
        gload16(&kv_hi[ao],  (char*)a_hi + tid * 16);
        gload16(&kv_lo[ao],  (char*)a_lo + tid * 16);
        gload16(&wkt_hi[bo], (char*)bkh_ + tid * 16);
        gload16(&wkt_lo[bo], (char*)bkl_ + tid * 16);
        gload16(&wvt_hi[bo], (char*)bvh_ + tid * 16);
        gload16(&wvt_lo[bo], (char*)bvl_ + tid * 16);
        __syncthreads();                              // vmcnt drain -> tiles ready
        const _Float16* __restrict__ bh = isV ? bvh_ : bkh_;
        const _Float16* __restrict__ bl = isV ? bvl_ : bkl_;
        f16x8 afh[2], afl[2], bfh[4], bfl[4];
        #pragma unroll
        for (int mt = 0; mt < 2; ++mt) {              // lane-linear 1KB wave reads
            afh[mt] = *(const f16x8*)&a_hi[(w1 * 2 + mt) * 512 + lane * 8];
            afl[mt] = *(const f16x8*)&a_lo[(w1 * 2 + mt) * 512 + lane * 8];
        }
        #pragma unroll
        for (int nt = 0; nt < 4; ++nt) {
            bfh[nt] = *(const f16x8*)&bh[nt * 512 + lane * 8];
            bfl[nt] = *(const f16x8*)&bl[nt * 512 + lane * 8];
        }
        #pragma unroll
        for (int mt = 0; mt < 2; ++mt)
            #pragma unroll
            for (int nt = 0; nt < 4; ++nt) {
                acc_h[mt][nt] = mfma_f16(afh[mt], bfh[nt], acc_h[mt][nt]);
                acc_c[mt][nt] = mfma_f16(afh[mt], bfl[nt], acc_c[mt][nt]);
                acc_c[mt][nt] = mfma_f16(afl[mt], bfh[nt], acc_c[mt][nt]);
            }
        __syncthreads();
    }

    // epilogue: combine hi+lo/4096 + bias; square kh. khs/vhs alias staging —
    // safe: last loop barrier separates final MFMA reads from these writes.
    {
        const float* __restrict__ bias = (isV ? bv : bk) + h * HD;
        float* __restrict__ outs = isV ? vhs : khs;
        float bia[4];
        #pragma unroll
        for (int nt = 0; nt < 4; ++nt) bia[nt] = bias[nt * 16 + l15];
        #pragma unroll
        for (int mt = 0; mt < 2; ++mt)
            #pragma unroll
            for (int nt = 0; nt < 4; ++nt)
                #pragma unroll
                for (int r = 0; r < 4; ++r) {
                    int t = w1 * 32 + mt * 16 + quad * 4 + r;
                    float v = acc_h[mt][nt][r] + INV_LOSCALE * acc_c[mt][nt][r] + bia[nt];
                    if (!isV) v = v * v;              // wave-uniform branch
                    outs[t * 64 + nt * 16 + l15] = v;
                }
    }
    __syncthreads();

    const int ty = tid >> 4, tx = tid & 15;
    f32x4 akv[4] = {};
    float aks[4] = {0.f, 0.f, 0.f, 0.f};
    #pragma unroll 4
    for (int t = 0; t < 64; ++t) {
        f32x4 kd = *(const f32x4*)&khs[t * 64 + ty * 4];
        f32x4 ve = *(const f32x4*)&vhs[t * 64 + tx * 4];
        #pragma unroll
        for (int i = 0; i < 4; ++i) {
            aks[i] += kd[i];
            akv[i] += kd[i] * ve;
        }
    }
    float* kvp = kv_sum + (size_t)(b * NH + h) * HD * HD;
    #pragma unroll
    for (int i = 0; i < 4; ++i)
        #pragma unroll
        for (int j = 0; j < 4; ++j)
            atomicAdd(&kvp[(ty * 4 + i) * HD + tx * 4 + j], akv[i][j]);
    if (tx == 0) {
        float* ksp = ksum + (b * NH + h) * HD;
        #pragma unroll
        for (int i = 0; i < 4; ++i) atomicAdd(&ksp[ty * 4 + i], aks[i]);
    }
}

// ---------------------------------------------------------------------------
// Kernel 2: qh = q@Wq+bq (A split on the fly into fragment-linear LDS, B via
// global_load_lds); z from registers; attn = z*(qh2@kv_sum) written directly
// in fragment-linear hi/lo f16 for out_proj. kvs reloaded post-loop into the
// dead staging region (LDS union).
// ---------------------------------------------------------------------------
__global__ __launch_bounds__(256, 3) void q_attn_kernel(
    const float* __restrict__ q,
    const _Float16* __restrict__ wqt_hi, const _Float16* __restrict__ wqt_lo,
    const float* __restrict__ bq,
    const float* __restrict__ kv_sum, const float* __restrict__ ksum,
    _Float16* __restrict__ attn_hi, _Float16* __restrict__ attn_lo)
{
    const int tid = threadIdx.x;
    const int lane = tid & 63, wave = tid >> 6, quad = lane >> 4, l15 = lane & 15;
    const int b = blockIdx.z, h = blockIdx.y, bx = blockIdx.x;
    const int t0 = bx * 64;

    __shared__ __align__(16) char smem[16384];        // staging, later kvs
    _Float16* a_hi = (_Float16*)smem;
    _Float16* a_lo = (_Float16*)(smem + 4096);
    _Float16* b_hi = (_Float16*)(smem + 8192);
    _Float16* b_lo = (_Float16*)(smem + 12288);
    __shared__ __align__(16) float qs[64 * 68];
    __shared__ float z_s[64], ks_s[64];

    if (tid < 64) ks_s[tid] = ksum[(b * NH + h) * HD + tid];

    // A-staging chunk for this thread: chunk id == tid (row arb*16+al15, k aquad*8..)
    const int arb = tid >> 6, aquad = (tid >> 4) & 3, al15 = tid & 15;
    const float* __restrict__ qrow =
        q + ((size_t)b * TSEQ + t0 + arb * 16 + al15) * DM + aquad * 8;

    const size_t btile = (size_t)h * 32;
    f32x4 acc_h[4] = {}, acc_c[4] = {};

    f32x4 v0 = *(const f32x4*)&qrow[0];
    f32x4 v1 = *(const f32x4*)&qrow[4];
    for (int s = 0; s < 32; ++s) {
        { // split current q tile into fragment-linear LDS (lane-linear writes)
            _Float16 hh[8], ll[8];
            #pragma unroll
            for (int j = 0; j < 4; ++j) { split1(v0[j], hh[j], ll[j]); split1(v1[j], hh[4+j], ll[4+j]); }
            *(u32x4*)((char*)a_hi + tid * 16) =
                (u32x4){pack2(hh[0],hh[1]), pack2(hh[2],hh[3]), pack2(hh[4],hh[5]), pack2(hh[6],hh[7])};
            *(u32x4*)((char*)a_lo + tid * 16) =
                (u32x4){pack2(ll[0],ll[1]), pack2(ll[2],ll[3]), pack2(ll[4],ll[5]), pack2(ll[6],ll[7])};
        }
        const size_t bo = (btile + s) * 2048 + tid * 8;
        gload16(&wqt_hi[bo], (char*)b_hi + tid * 16);
        gload16(&wqt_lo[bo], (char*)b_lo + tid * 16);
        __syncthreads();
        if (s < 31) {                                 // prefetch next q tile under MFMA
            v0 = *(const f32x4*)&qrow[(s + 1) * 32];
            v1 = *(const f32x4*)&qrow[(s + 1) * 32 + 4];
        }
        f16x8 afh = *(const f16x8*)&a_hi[wave * 512 + lane * 8];
        f16x8 afl = *(const f16x8*)&a_lo[wave * 512 + lane * 8];
        f16x8 bfh[4], bfl[4];
        #pragma unroll
        for (int nt = 0; nt < 4; ++nt) {
            bfh[nt] = *(const f16x8*)&b_hi[nt * 512 + lane * 8];
            bfl[nt] = *(const f16x8*)&b_lo[nt * 512 + lane * 8];
        }
        #pragma unroll
        for (int nt = 0; nt < 4; ++nt) {
            acc_h[nt] = mfma_f16(afh, bfh[nt], acc_h[nt]);
            acc_c[nt] = mfma_f16(afh, bfl[nt], acc_c[nt]);
            acc_c[nt] = mfma_f16(afl, bfh[nt], acc_c[nt]);
        }
        __syncthreads();
    }

    // epilogue: qh2 -> qs; z via shfl over the 16 n-lanes
    {
        const int mrow0 = wave * 16;
        const float* __restrict__ bias = bq + h * HD;
        float zp[4] = {0.f, 0.f, 0.f, 0.f};
        #pragma unroll
        for (int nt = 0; nt < 4; ++nt) {
            int d = nt * 16 + l15;
            float bia = bias[d];
            float ks  = ks_s[d];
            #pragma unroll
            for (int r = 0; r < 4; ++r) {
                int t = mrow0 + quad * 4 + r;
                float v = acc_h[nt][r] + INV_LOSCALE * acc_c[nt][r] + bia;
                float v2 = v * v;
                qs[t * 68 + d] = v2;
                zp[r] = fmaf(v2, ks, zp[r]);
            }
        }
        #pragma unroll
        for (int r = 0; r < 4; ++r) {
            float p = zp[r];
            p += __shfl_xor(p, 1);
            p += __shfl_xor(p, 2);
            p += __shfl_xor(p, 4);
            p += __shfl_xor(p, 8);
            if (l15 == 0) z_s[mrow0 + quad * 4 + r] = 1.f / (p + 1e-6f);
        }
    }
    __syncthreads();

    // reload kv_sum into dead staging region
    float* kvs = (float*)smem;
    {
        const float* __restrict__ kvp = kv_sum + (size_t)(b * NH + h) * HD * HD;
        #pragma unroll
        for (int it = 0; it < 4; ++it) {
            int idx = it * 256 + tid;
            int r = idx >> 4, c = (idx & 15) * 4;
            *(f32x4*)&kvs[r * 64 + c] = *(const f32x4*)&kvp[r * HD + c];
        }
    }
    __syncthreads();

    // mini-GEMM: sv[t][e] = sum_d qs[t][d]*kvs[d][e]; write attn fragment-linear
    const int ty = tid >> 4, tx = tid & 15;
    f32x4 sv[4] = {};
    #pragma unroll 4
    for (int d = 0; d < 64; d += 4) {
        f32x4 b0 = *(const f32x4*)&kvs[(d + 0) * 64 + tx * 4];
        f32x4 b1 = *(const f32x4*)&kvs[(d + 1) * 64 + tx * 4];
        f32x4 b2 = *(const f32x4*)&kvs[(d + 2) * 64 + tx * 4];
        f32x4 b3 = *(const f32x4*)&kvs[(d + 3) * 64 + tx * 4];
        #pragma unroll
        for (int i = 0; i < 4; ++i) {
            f32x4 av = *(const f32x4*)&qs[(ty * 4 + i) * 68 + d];
            sv[i] += av.x * b0 + av.y * b1 + av.z * b2 + av.w * b3;
        }
    }
    const size_t opanel = (size_t)b * 64 + bx;
    const int s_out = h * 2 + (tx >> 3);              // k-step of col h*64+tx*4
    const int kq = (tx >> 1) & 3;                     // k-quad within step
    const int rem8 = (tx & 1) * 8;                    // byte offset within chunk
    #pragma unroll
    for (int i = 0; i < 4; ++i) {
        int t = ty * 4 + i;
        f32x4 o = sv[i] * z_s[t];
        _Float16 hh[4], ll[4];
        #pragma unroll
        for (int j = 0; j < 4; ++j) split1(o[j], hh[j], ll[j]);
        size_t cb = (((opanel * 32 + s_out) * 256 + ((t >> 4) * 4 + kq) * 16 + (t & 15)) << 4) + rem8;
        *(u32x2*)((char*)attn_hi + cb) = (u32x2){pack2(hh[0], hh[1]), pack2(hh[2], hh[3])};
        *(u32x2*)((char*)attn_lo + cb) = (u32x2){pack2(ll[0], ll[1]), pack2(ll[2], ll[3])};
    }
}

// ---------------------------------------------------------------------------
// Kernel 3: out = attn @ Wo^T + bo. Both operands fragment-linear; 6x
// global_load_lds per thread per K-step; LDS union with fp32 epilogue scratch.
// ---------------------------------------------------------------------------
__global__ __launch_bounds__(256, 3) void out_proj_kernel(
    const _Float16* __restrict__ attn_hi, const _Float16* __restrict__ attn_lo,
    const _Float16* __restrict__ wo_hi, const _Float16* __restrict__ wo_lo,
    const float* __restrict__ bo, float* __restrict__ out)
{
    const int tid = threadIdx.x;
    const int lane = tid & 63, wave = tid >> 6, quad = lane >> 4, l15 = lane & 15;
    const int n0 = blockIdx.x * 64;
    const size_t m0 = (size_t)blockIdx.y * 128;

    __shared__ __align__(16) char smem[32768];
    _Float16* a_hi = (_Float16*)smem;                 // 2 panels, 8K
    _Float16* a_lo = (_Float16*)(smem + 8192);
    _Float16* b_hi = (_Float16*)(smem + 16384);
    _Float16* b_lo = (_Float16*)(smem + 20480);
    float* cs = (float*)smem;                         // epilogue reuse, 32K

    const size_t ap0 = (m0 >> 6) * 32, ap1 = ap0 + 32;
    const size_t bpn = (size_t)(n0 >> 6) * 32;

    f32x4 acc_h[2][4] = {}, acc_c[2][4] = {};
    for (int s = 0; s < 32; ++s) {
        const size_t co = tid * 8;
        gload16(&attn_hi[(ap0 + s) * 2048 + co], (char*)a_hi + tid * 16);
        gload16(&attn_hi[(ap1 + s) * 2048 + co], (char*)a_hi + 4096 + tid * 16);
        gload16(&attn_lo[(ap0 + s) * 2048 + co], (char*)a_lo + tid * 16);
        gload16(&attn_lo[(ap1 + s) * 2048 + co], (char*)a_lo + 4096 + tid * 16);
        gload16(&wo_hi[(bpn + s) * 2048 + co], (char*)b_hi + tid * 16);
        gload16(&wo_lo[(bpn + s) * 2048 + co], (char*)b_lo + tid * 16);
        __syncthreads();
        f16x8 afh[2], afl[2], bfh[4], bfl[4];
        #pragma unroll
        for (int mt = 0; mt < 2; ++mt) {              // global rb = wave*2+mt, linear
            afh[mt] = *(const f16x8*)&a_hi[(wave * 2 + mt) * 512 + lane * 8];
            afl[mt] = *(const f16x8*)&a_lo[(wave * 2 + mt) * 512 + lane * 8];
        }
        #pragma unroll
        for (int nt = 0; nt < 4; ++nt) {
            bfh[nt] = *(const f16x8*)&b_hi[nt * 512 + lane * 8];
            bfl[nt] = *(const f16x8*)&b_lo[nt * 512 + lane * 8];
        }
        #pragma unroll
        for (int mt = 0; mt < 2; ++mt)
            #pragma unroll
            for (int nt = 0; nt < 4; ++nt) {
                acc_h[mt][nt] = mfma_f16(afh[mt], bfh[nt], acc_h[mt][nt]);
                acc_c[mt][nt] = mfma_f16(afh[mt], bfl[nt], acc_c[mt][nt]);
                acc_c[mt][nt] = mfma_f16(afl[mt], bfh[nt], acc_c[mt][nt]);
            }
        __syncthreads();
    }

    {
        float bia[4];
        #pragma unroll
        for (int nt = 0; nt < 4; ++nt) bia[nt] = bo[n0 + nt * 16 + l15];
        #pragma unroll
        for (int mt = 0; mt < 2; ++mt)
            #pragma unroll
            for (int nt = 0; nt < 4; ++nt)
                #pragma unroll
                for (int r = 0; r < 4; ++r) {
                    int t = wave * 32 + mt * 16 + quad * 4 + r;
                    cs[t * 64 + nt * 16 + l15] =
                        acc_h[mt][nt][r] + INV_LOSCALE * acc_c[mt][nt][r] + bia[nt];
                }
    }
    __syncthreads();
    #pragma unroll
    for (int it = 0; it < 8; ++it) {
        int idx = it * 256 + tid;
        int r = idx >> 4, c = (idx & 15) * 4;
        *(f32x4*)&out[(m0 + r) * DM + n0 + c] = *(f32x4*)&cs[r * 64 + c];
    }
}

// ---------------------------------------------------------------------------
extern "C" void kernel_launch(void* const* d_in, const int* in_sizes, int n_in,
                              void* d_out, int out_size, void* d_ws, size_t ws_size,
                              hipStream_t stream) {
    const float* q  = (const float*)d_in[0];
    const float* kv = (const float*)d_in[1];
    const float* Wq = (const float*)d_in[2];
    const float* bq = (const float*)d_in[3];
    const float* Wk = (const float*)d_in[4];
    const float* bk = (const float*)d_in[5];
    const float* Wv = (const float*)d_in[6];
    const float* bv = (const float*)d_in[7];
    const float* Wo = (const float*)d_in[8];
    const float* bo = (const float*)d_in[9];
    float* out = (float*)d_out;

    // workspace carve-up (~84.9 MB)
    char* p = (char*)d_ws;
    float* kv_sum = (float*)p;              p += (size_t)BSZ * NH * HD * HD * 4;
    float* ksum   = (float*)p;              p += (size_t)BSZ * NH * HD * 4;
    _Float16* wqt_hi = (_Float16*)p;        p += (size_t)NH * HD * DM * 2;
    _Float16* wqt_lo = (_Float16*)p;        p += (size_t)NH * HD * DM * 2;
    _Float16* wkt_hi = (_Float16*)p;        p += (size_t)NH * HD * DM * 2;
    _Float16* wkt_lo = (_Float16*)p;        p += (size_t)NH * HD * DM * 2;
    _Float16* wvt_hi = (_Float16*)p;        p += (size_t)NH * HD * DM * 2;
    _Float16* wvt_lo = (_Float16*)p;        p += (size_t)NH * HD * DM * 2;
    _Float16* wo_hi  = (_Float16*)p;        p += (size_t)DM * DM * 2;
    _Float16* wo_lo  = (_Float16*)p;        p += (size_t)DM * DM * 2;
    _Float16* buf_hi = (_Float16*)p;        p += (size_t)BT * DM * 2;   // kv frags, then attn frags
    _Float16* buf_lo = (_Float16*)p;        p += (size_t)BT * DM * 2;

    size_t zero_bytes = ((size_t)BSZ * NH * HD * HD + (size_t)BSZ * NH * HD) * sizeof(float);
    hipMemsetAsync(d_ws, 0, zero_bytes, stream);

    fragsplit_kernel<<<(BT * DM / 8) / 256, 256, 0, stream>>>(kv, buf_hi, buf_lo);
    wsplit_kernel<<<dim3(DM / 64, NH, 3), 256, 0, stream>>>(
        Wq, Wk, Wv, wqt_hi, wqt_lo, wkt_hi, wkt_lo, wvt_hi, wvt_lo);
    fragsplit_kernel<<<(DM * DM / 8) / 256, 256, 0, stream>>>(Wo, wo_hi, wo_lo);

    kv_stats_kernel<<<dim3(TSEQ / 64, NH, BSZ), 256, 0, stream>>>(
        buf_hi, buf_lo, wkt_hi, wkt_lo, wvt_hi, wvt_lo, bk, bv, kv_sum, ksum);
    q_attn_kernel<<<dim3(TSEQ / 64, NH, BSZ), 256, 0, stream>>>(
        q, wqt_hi, wqt_lo, bq, kv_sum, ksum, buf_hi, buf_lo);   // kv frags dead; reuse as attn
    out_proj_kernel<<<dim3(DM / 64, BT / 128), 256, 0, stream>>>(
        buf_hi, buf_lo, wo_hi, wo_lo, bo, out);
}

// Round 2
// 825.670 us; speedup vs baseline: 1.4102x; 1.0300x over previous
//
#include <hip/hip_runtime.h>

#define BSZ 4
#define TSEQ 4096
#define DM 1024
#define NH 16
#define HD 64
#define BT (BSZ * TSEQ)
#define INV_LOSCALE (1.0f / 4096.0f)

using f32x4 = __attribute__((ext_vector_type(4))) float;
using f16x8 = __attribute__((ext_vector_type(8))) _Float16;
using u32x2 = __attribute__((ext_vector_type(2))) unsigned;
using u32x4 = __attribute__((ext_vector_type(4))) unsigned;

typedef const __attribute__((address_space(1))) void* gas_ptr;
typedef __attribute__((address_space(3))) void* las_ptr;

// Async global->LDS, 16 B per lane. LDS dest = uniform base + lane*16.
__device__ __forceinline__ void gload16(const void* g, void* l) {
    __builtin_amdgcn_global_load_lds((gas_ptr)g, (las_ptr)l, 16, 0, 0);
}

// f16 RTN split: x = hi + lo/4096 + r. lo pre-scaled by 4096 (denormal immunity).
__device__ __forceinline__ void split1(float x, _Float16& h, _Float16& l) {
    h = (_Float16)x;
    l = (_Float16)((x - (float)h) * 4096.0f);
}
__device__ __forceinline__ unsigned pack2(_Float16 a, _Float16 b) {
    return (unsigned)__builtin_bit_cast(unsigned short, a) |
           ((unsigned)__builtin_bit_cast(unsigned short, b) << 16);
}
__device__ __forceinline__ f32x4 mfma_f16(f16x8 a, f16x8 b, f32x4 c) {
    return __builtin_amdgcn_mfma_f32_16x16x32_f16(a, b, c, 0, 0, 0);
}

// ---------------------------------------------------------------------------
// Fragment-linear layout: row-major [R][1024] fp32 -> per 64-row panel, per
// 32-k step, a 64x32 tile stored as 256 x 16B chunks ordered
// chunk = [rb(4)][kquad(4)][l15(16)] (lane i of a wave reads bytes i*16).
// ---------------------------------------------------------------------------
__global__ __launch_bounds__(256) void fragsplit_kernel(const float* __restrict__ in,
        _Float16* __restrict__ hi, _Float16* __restrict__ lo) {
    const int C = blockIdx.x * 256 + threadIdx.x;      // global chunk id
    const int l15 = C & 15, quad = (C >> 4) & 3, rb = (C >> 6) & 3;
    const int s = (C >> 8) & 31, panel = C >> 13;
    const size_t src = ((size_t)(panel * 64 + rb * 16 + l15)) * DM + s * 32 + quad * 8;
    f32x4 v0 = *(const f32x4*)&in[src];
    f32x4 v1 = *(const f32x4*)&in[src + 4];
    _Float16 h[8], l[8];
    #pragma unroll
    for (int j = 0; j < 4; ++j) { split1(v0[j], h[j], l[j]); split1(v1[j], h[4 + j], l[4 + j]); }
    ((u32x4*)hi)[C] = (u32x4){pack2(h[0],h[1]), pack2(h[2],h[3]), pack2(h[4],h[5]), pack2(h[6],h[7])};
    ((u32x4*)lo)[C] = (u32x4){pack2(l[0],l[1]), pack2(l[2],l[3]), pack2(l[4],l[5]), pack2(l[6],l[7])};
}

// ---------------------------------------------------------------------------
// Wq/Wk/Wv [h][k][n] -> transposed fragment-linear hi/lo f16 (panel = head).
// ---------------------------------------------------------------------------
__global__ __launch_bounds__(256) void wsplit_kernel(
    const float* __restrict__ Wq, const float* __restrict__ Wk, const float* __restrict__ Wv,
    _Float16* __restrict__ qh, _Float16* __restrict__ ql,
    _Float16* __restrict__ kh, _Float16* __restrict__ kl,
    _Float16* __restrict__ vh, _Float16* __restrict__ vl) {
    const int tid = threadIdx.x;
    const int k0 = blockIdx.x * 64, h = blockIdx.y, w = blockIdx.z;
    const float* __restrict__ W = (w == 0) ? Wq : (w == 1) ? Wk : Wv;
    _Float16* __restrict__ dh = (w == 0) ? qh : (w == 1) ? kh : vh;
    _Float16* __restrict__ dl = (w == 0) ? ql : (w == 1) ? kl : vl;
    __shared__ __align__(16) float ws_[64][68];
    #pragma unroll
    for (int it = 0; it < 4; ++it) {
        int idx = it * 256 + tid;
        int r = idx >> 4, c4 = (idx & 15) * 4;
        *(f32x4*)&ws_[r][c4] = *(const f32x4*)&W[((size_t)h * DM + k0 + r) * HD + c4];
    }
    __syncthreads();
    const int n = tid >> 2, kq16 = (tid & 3) * 16;
    _Float16 hh[16], ll[16];
    #pragma unroll
    for (int j = 0; j < 16; ++j) split1(ws_[kq16 + j][n], hh[j], ll[j]);
    #pragma unroll
    for (int c = 0; c < 2; ++c) {
        int kg = k0 + kq16 + c * 8;
        int s = kg >> 5, quad = (kg >> 3) & 3;
        size_t chunk = (size_t)(h * 32 + s) * 256 + ((n >> 4) * 4 + quad) * 16 + (n & 15);
        ((u32x4*)dh)[chunk] = (u32x4){pack2(hh[c*8+0],hh[c*8+1]), pack2(hh[c*8+2],hh[c*8+3]),
                                      pack2(hh[c*8+4],hh[c*8+5]), pack2(hh[c*8+6],hh[c*8+7])};
        ((u32x4*)dl)[chunk] = (u32x4){pack2(ll[c*8+0],ll[c*8+1]), pack2(ll[c*8+2],ll[c*8+3]),
                                      pack2(ll[c*8+4],ll[c*8+5]), pack2(ll[c*8+6],ll[c*8+7])};
    }
}

// ---------------------------------------------------------------------------
// Kernel 1: kh = (kv@Wk+bk)^2, vh = kv@Wv+bv via 3-term f16-split MFMA.
// 2-phase double-buffered global_load_lds staging (T3 minimum template):
// issue tile s+1's 6 loads before computing tile s; ONE __syncthreads per
// step (drains vmcnt after the compute phase covered the latency).
// Each block processes 4 consecutive t-tiles, accumulating the rank-64
// reduction in registers -> 4x fewer atomics (WRITE_SIZE 266 -> ~67 MB).
// ---------------------------------------------------------------------------
__global__ __launch_bounds__(256, 3) void kv_stats_kernel(
    const _Float16* __restrict__ kv_hi, const _Float16* __restrict__ kv_lo,
    const _Float16* __restrict__ wkt_hi, const _Float16* __restrict__ wkt_lo,
    const _Float16* __restrict__ wvt_hi, const _Float16* __restrict__ wvt_lo,
    const float* __restrict__ bk, const float* __restrict__ bv,
    float* __restrict__ kv_sum, float* __restrict__ ksum)
{
    const int tid = threadIdx.x;
    const int lane = tid & 63, wave = tid >> 6, quad = lane >> 4, l15 = lane & 15;
    const int b = blockIdx.z, h = blockIdx.y, bx = blockIdx.x;

    // dbuf staging: buffer p at p*24576; within: a_hi 0, a_lo 4K, bkh 8K,
    // bkl 12K, bvh 16K, bvl 20K. Epilogue scratch khs/vhs alias (post-barrier).
    __shared__ __align__(16) char smem[49152];
    float* khs = (float*)smem;
    float* vhs = (float*)(smem + 16384);

    const int isV = wave >> 1, w1 = wave & 1;
    const size_t btile = (size_t)h * 32;
    const int ty = tid >> 4, tx = tid & 15;

    f32x4 akv[4] = {};
    float aks[4] = {0.f, 0.f, 0.f, 0.f};

    for (int sub = 0; sub < 4; ++sub) {
        const size_t atile = (size_t)(b * 64 + bx * 4 + sub) * 32;
        auto stage = [&](int p, int s) {
            char* dst = smem + p * 24576 + tid * 16;
            const size_t ao = (atile + s) * 2048 + tid * 8;
            const size_t bo = (btile + s) * 2048 + tid * 8;
            gload16(&kv_hi[ao],  dst);
            gload16(&kv_lo[ao],  dst + 4096);
            gload16(&wkt_hi[bo], dst + 8192);
            gload16(&wkt_lo[bo], dst + 12288);
            gload16(&wvt_hi[bo], dst + 16384);
            gload16(&wvt_lo[bo], dst + 20480);
        };

        f32x4 acc_h[2][4] = {}, acc_c[2][4] = {};
        stage(0, 0);
        __syncthreads();
        for (int s = 0; s < 32; ++s) {
            const int p = s & 1;
            if (s < 31) stage(p ^ 1, s + 1);          // prefetch next tile
            const char* bufc = smem + p * 24576;
            const _Float16* a_hi = (const _Float16*)bufc;
            const _Float16* a_lo = (const _Float16*)(bufc + 4096);
            const _Float16* bh = (const _Float16*)(bufc + (isV ? 16384 : 8192));
            const _Float16* bl = (const _Float16*)(bufc + (isV ? 20480 : 12288));
            f16x8 afh[2], afl[2], bfh[4], bfl[4];
            #pragma unroll
            for (int mt = 0; mt < 2; ++mt) {          // lane-linear, conflict-free
                afh[mt] = *(const f16x8*)&a_hi[(w1 * 2 + mt) * 512 + lane * 8];
                afl[mt] = *(const f16x8*)&a_lo[(w1 * 2 + mt) * 512 + lane * 8];
            }
            #pragma unroll
            for (int nt = 0; nt < 4; ++nt) {
                bfh[nt] = *(const f16x8*)&bh[nt * 512 + lane * 8];
                bfl[nt] = *(const f16x8*)&bl[nt * 512 + lane * 8];
            }
            #pragma unroll
            for (int mt = 0; mt < 2; ++mt)
                #pragma unroll
                for (int nt = 0; nt < 4; ++nt) {
                    acc_h[mt][nt] = mfma_f16(afh[mt], bfh[nt], acc_h[mt][nt]);
                    acc_c[mt][nt] = mfma_f16(afh[mt], bfl[nt], acc_c[mt][nt]);
                    acc_c[mt][nt] = mfma_f16(afl[mt], bfh[nt], acc_c[mt][nt]);
                }
            __syncthreads();                          // drains next tile's loads
        }

        // epilogue: combine hi+lo/4096 + bias; square kh. Scratch aliases
        // staging -- safe: final loop barrier separates MFMA reads from writes.
        {
            const float* __restrict__ bias = (isV ? bv : bk) + h * HD;
            float* __restrict__ outs = isV ? vhs : khs;
            float bia[4];
            #pragma unroll
            for (int nt = 0; nt < 4; ++nt) bia[nt] = bias[nt * 16 + l15];
            #pragma unroll
            for (int mt = 0; mt < 2; ++mt)
                #pragma unroll
                for (int nt = 0; nt < 4; ++nt)
                    #pragma unroll
                    for (int r = 0; r < 4; ++r) {
                        int t = w1 * 32 + mt * 16 + quad * 4 + r;
                        float v = acc_h[mt][nt][r] + INV_LOSCALE * acc_c[mt][nt][r] + bia[nt];
                        if (!isV) v = v * v;          // wave-uniform branch
                        outs[t * 64 + nt * 16 + l15] = v;
                    }
        }
        __syncthreads();

        #pragma unroll 4
        for (int t = 0; t < 64; ++t) {
            f32x4 kd = *(const f32x4*)&khs[t * 64 + ty * 4];
            f32x4 ve = *(const f32x4*)&vhs[t * 64 + tx * 4];
            #pragma unroll
            for (int i = 0; i < 4; ++i) {
                aks[i] += kd[i];
                akv[i] += kd[i] * ve;
            }
        }
        __syncthreads();                              // scratch dead before next sub's staging
    }

    float* kvp = kv_sum + (size_t)(b * NH + h) * HD * HD;
    #pragma unroll
    for (int i = 0; i < 4; ++i)
        #pragma unroll
        for (int j = 0; j < 4; ++j)
            atomicAdd(&kvp[(ty * 4 + i) * HD + tx * 4 + j], akv[i][j]);
    if (tx == 0) {
        float* ksp = ksum + (b * NH + h) * HD;
        #pragma unroll
        for (int i = 0; i < 4; ++i) atomicAdd(&ksp[ty * 4 + i], aks[i]);
    }
}

// ---------------------------------------------------------------------------
// Kernel 2: qh = q@Wq+bq; 2-phase dbuf: A split-written one tile ahead from
// registers prefetched two tiles ahead; B via global_load_lds one tile ahead.
// z from registers; attn = z*(qh2@kv_sum) written fragment-linear.
// ---------------------------------------------------------------------------
__global__ __launch_bounds__(256, 3) void q_attn_kernel(
    const float* __restrict__ q,
    const _Float16* __restrict__ wqt_hi, const _Float16* __restrict__ wqt_lo,
    const float* __restrict__ bq,
    const float* __restrict__ kv_sum, const float* __restrict__ ksum,
    _Float16* __restrict__ attn_hi, _Float16* __restrict__ attn_lo)
{
    const int tid = threadIdx.x;
    const int lane = tid & 63, wave = tid >> 6, quad = lane >> 4, l15 = lane & 15;
    const int b = blockIdx.z, h = blockIdx.y, bx = blockIdx.x;
    const int t0 = bx * 64;

    // dbuf staging: buffer p at p*16384: a_hi 0, a_lo 4K, b_hi 8K, b_lo 12K.
    __shared__ __align__(16) char smem[32768];
    __shared__ __align__(16) float qs[64 * 68];
    __shared__ float z_s[64], ks_s[64];

    if (tid < 64) ks_s[tid] = ksum[(b * NH + h) * HD + tid];

    const int arb = tid >> 6, aquad = (tid >> 4) & 3, al15 = tid & 15;
    const float* __restrict__ qrow =
        q + ((size_t)b * TSEQ + t0 + arb * 16 + al15) * DM + aquad * 8;
    const size_t btile = (size_t)h * 32;

    auto asplit_write = [&](int p, f32x4 v0, f32x4 v1) {
        _Float16 hh[8], ll[8];
        #pragma unroll
        for (int j = 0; j < 4; ++j) { split1(v0[j], hh[j], ll[j]); split1(v1[j], hh[4+j], ll[4+j]); }
        char* dst = smem + p * 16384 + tid * 16;
        *(u32x4*)dst =
            (u32x4){pack2(hh[0],hh[1]), pack2(hh[2],hh[3]), pack2(hh[4],hh[5]), pack2(hh[6],hh[7])};
        *(u32x4*)(dst + 4096) =
            (u32x4){pack2(ll[0],ll[1]), pack2(ll[2],ll[3]), pack2(ll[4],ll[5]), pack2(ll[6],ll[7])};
    };
    auto stageB = [&](int p, int s) {
        char* dst = smem + p * 16384 + 8192 + tid * 16;
        const size_t bo = (btile + s) * 2048 + tid * 8;
        gload16(&wqt_hi[bo], dst);
        gload16(&wqt_lo[bo], dst + 4096);
    };

    f32x4 acc_h[4] = {}, acc_c[4] = {};
    f32x4 v0 = *(const f32x4*)&qrow[0];
    f32x4 v1 = *(const f32x4*)&qrow[4];
    asplit_write(0, v0, v1);                          // tile 0 -> buf 0
    stageB(0, 0);
    v0 = *(const f32x4*)&qrow[32];                    // tile 1 regs
    v1 = *(const f32x4*)&qrow[36];
    __syncthreads();

    for (int s = 0; s < 32; ++s) {
        const int p = s & 1;
        if (s < 31) {
            stageB(p ^ 1, s + 1);                     // prefetch next B tile
            asplit_write(p ^ 1, v0, v1);              // split next A tile
            if (s < 30) {                             // q regs two tiles ahead
                v0 = *(const f32x4*)&qrow[(s + 2) * 32];
                v1 = *(const f32x4*)&qrow[(s + 2) * 32 + 4];
            }
        }
        const char* bufc = smem + p * 16384;
        f16x8 afh = *(const f16x8*)((const _Float16*)bufc + wave * 512 + lane * 8);
        f16x8 afl = *(const f16x8*)((const _Float16*)(bufc + 4096) + wave * 512 + lane * 8);
        f16x8 bfh[4], bfl[4];
        #pragma unroll
        for (int nt = 0; nt < 4; ++nt) {
            bfh[nt] = *(const f16x8*)((const _Float16*)(bufc + 8192) + nt * 512 + lane * 8);
            bfl[nt] = *(const f16x8*)((const _Float16*)(bufc + 12288) + nt * 512 + lane * 8);
        }
        #pragma unroll
        for (int nt = 0; nt < 4; ++nt) {
            acc_h[nt] = mfma_f16(afh, bfh[nt], acc_h[nt]);
            acc_c[nt] = mfma_f16(afh, bfl[nt], acc_c[nt]);
            acc_c[nt] = mfma_f16(afl, bfh[nt], acc_c[nt]);
        }
        __syncthreads();
    }

    // epilogue: qh2 -> qs; z via shfl over the 16 n-lanes
    {
        const int mrow0 = wave * 16;
        const float* __restrict__ bias = bq + h * HD;
        float zp[4] = {0.f, 0.f, 0.f, 0.f};
        #pragma unroll
        for (int nt = 0; nt < 4; ++nt) {
            int d = nt * 16 + l15;
            float bia = bias[d];
            float ks  = ks_s[d];
            #pragma unroll
            for (int r = 0; r < 4; ++r) {
                int t = mrow0 + quad * 4 + r;
                float v = acc_h[nt][r] + INV_LOSCALE * acc_c[nt][r] + bia;
                float v2 = v * v;
                qs[t * 68 + d] = v2;
                zp[r] = fmaf(v2, ks, zp[r]);
            }
        }
        #pragma unroll
        for (int r = 0; r < 4; ++r) {
            float p = zp[r];
            p += __shfl_xor(p, 1);
            p += __shfl_xor(p, 2);
            p += __shfl_xor(p, 4);
            p += __shfl_xor(p, 8);
            if (l15 == 0) z_s[mrow0 + quad * 4 + r] = 1.f / (p + 1e-6f);
        }
    }
    __syncthreads();

    // reload kv_sum into dead staging region
    float* kvs = (float*)smem;
    {
        const float* __restrict__ kvp = kv_sum + (size_t)(b * NH + h) * HD * HD;
        #pragma unroll
        for (int it = 0; it < 4; ++it) {
            int idx = it * 256 + tid;
            int r = idx >> 4, c = (idx & 15) * 4;
            *(f32x4*)&kvs[r * 64 + c] = *(const f32x4*)&kvp[r * HD + c];
        }
    }
    __syncthreads();

    // mini-GEMM: sv[t][e] = sum_d qs[t][d]*kvs[d][e]; write attn fragment-linear
    const int ty = tid >> 4, tx = tid & 15;
    f32x4 sv[4] = {};
    #pragma unroll 4
    for (int d = 0; d < 64; d += 4) {
        f32x4 b0 = *(const f32x4*)&kvs[(d + 0) * 64 + tx * 4];
        f32x4 b1 = *(const f32x4*)&kvs[(d + 1) * 64 + tx * 4];
        f32x4 b2 = *(const f32x4*)&kvs[(d + 2) * 64 + tx * 4];
        f32x4 b3 = *(const f32x4*)&kvs[(d + 3) * 64 + tx * 4];
        #pragma unroll
        for (int i = 0; i < 4; ++i) {
            f32x4 av = *(const f32x4*)&qs[(ty * 4 + i) * 68 + d];
            sv[i] += av.x * b0 + av.y * b1 + av.z * b2 + av.w * b3;
        }
    }
    const size_t opanel = (size_t)b * 64 + bx;
    const int s_out = h * 2 + (tx >> 3);              // k-step of col h*64+tx*4
    const int kq = (tx >> 1) & 3;                     // k-quad within step
    const int rem8 = (tx & 1) * 8;                    // byte offset within chunk
    #pragma unroll
    for (int i = 0; i < 4; ++i) {
        int t = ty * 4 + i;
        f32x4 o = sv[i] * z_s[t];
        _Float16 hh[4], ll[4];
        #pragma unroll
        for (int j = 0; j < 4; ++j) split1(o[j], hh[j], ll[j]);
        size_t cb = (((opanel * 32 + s_out) * 256 + ((t >> 4) * 4 + kq) * 16 + (t & 15)) << 4) + rem8;
        *(u32x2*)((char*)attn_hi + cb) = (u32x2){pack2(hh[0], hh[1]), pack2(hh[2], hh[3])};
        *(u32x2*)((char*)attn_lo + cb) = (u32x2){pack2(ll[0], ll[1]), pack2(ll[2], ll[3])};
    }
}

// ---------------------------------------------------------------------------
// Kernel 3: out = attn @ Wo^T + bo. 2-phase dbuf global_load_lds staging.
// Buffer p at p*24576: a_hi panel0 0 / panel1 4K, a_lo 8K/12K, b_hi 16K,
// b_lo 20K. fp32 epilogue scratch aliases.
// ---------------------------------------------------------------------------
__global__ __launch_bounds__(256, 3) void out_proj_kernel(
    const _Float16* __restrict__ attn_hi, const _Float16* __restrict__ attn_lo,
    const _Float16* __restrict__ wo_hi, const _Float16* __restrict__ wo_lo,
    const float* __restrict__ bo, float* __restrict__ out)
{
    const int tid = threadIdx.x;
    const int lane = tid & 63, wave = tid >> 6, quad = lane >> 4, l15 = lane & 15;
    const int n0 = blockIdx.x * 64;
    const size_t m0 = (size_t)blockIdx.y * 128;

    __shared__ __align__(16) char smem[49152];
    float* cs = (float*)smem;                         // epilogue reuse, 32K

    const size_t ap0 = (m0 >> 6) * 32, ap1 = ap0 + 32;
    const size_t bpn = (size_t)(n0 >> 6) * 32;

    auto stage = [&](int p, int s) {
        char* dst = smem + p * 24576 + tid * 16;
        const size_t co = (size_t)s * 2048 + tid * 8;
        gload16(&attn_hi[ap0 * 2048 + co], dst);
        gload16(&attn_hi[ap1 * 2048 + co], dst + 4096);
        gload16(&attn_lo[ap0 * 2048 + co], dst + 8192);
        gload16(&attn_lo[ap1 * 2048 + co], dst + 12288);
        gload16(&wo_hi[bpn * 2048 + co],  dst + 16384);
        gload16(&wo_lo[bpn * 2048 + co],  dst + 20480);
    };

    const int panel = wave >> 1;                      // rows 0-63 / 64-127
    f32x4 acc_h[2][4] = {}, acc_c[2][4] = {};
    stage(0, 0);
    __syncthreads();
    for (int s = 0; s < 32; ++s) {
        const int p = s & 1;
        if (s < 31) stage(p ^ 1, s + 1);
        const char* bufc = smem + p * 24576;
        f16x8 afh[2], afl[2], bfh[4], bfl[4];
        #pragma unroll
        for (int mt = 0; mt < 2; ++mt) {
            int rbl = (wave & 1) * 2 + mt;            // row-block within panel
            afh[mt] = *(const f16x8*)((const _Float16*)(bufc + panel * 4096) + rbl * 512 + lane * 8);
            afl[mt] = *(const f16x8*)((const _Float16*)(bufc + 8192 + panel * 4096) + rbl * 512 + lane * 8);
        }
        #pragma unroll
        for (int nt = 0; nt < 4; ++nt) {
            bfh[nt] = *(const f16x8*)((const _Float16*)(bufc + 16384) + nt * 512 + lane * 8);
            bfl[nt] = *(const f16x8*)((const _Float16*)(bufc + 20480) + nt * 512 + lane * 8);
        }
        #pragma unroll
        for (int mt = 0; mt < 2; ++mt)
            #pragma unroll
            for (int nt = 0; nt < 4; ++nt) {
                acc_h[mt][nt] = mfma_f16(afh[mt], bfh[nt], acc_h[mt][nt]);
                acc_c[mt][nt] = mfma_f16(afh[mt], bfl[nt], acc_c[mt][nt]);
                acc_c[mt][nt] = mfma_f16(afl[mt], bfh[nt], acc_c[mt][nt]);
            }
        __syncthreads();
    }

    {
        float bia[4];
        #pragma unroll
        for (int nt = 0; nt < 4; ++nt) bia[nt] = bo[n0 + nt * 16 + l15];
        #pragma unroll
        for (int mt = 0; mt < 2; ++mt)
            #pragma unroll
            for (int nt = 0; nt < 4; ++nt)
                #pragma unroll
                for (int r = 0; r < 4; ++r) {
                    int t = wave * 32 + mt * 16 + quad * 4 + r;   // panel*64 + rbl*16 rows
                    cs[t * 64 + nt * 16 + l15] =
                        acc_h[mt][nt][r] + INV_LOSCALE * acc_c[mt][nt][r] + bia[nt];
                }
    }
    __syncthreads();
    #pragma unroll
    for (int it = 0; it < 8; ++it) {
        int idx = it * 256 + tid;
        int r = idx >> 4, c = (idx & 15) * 4;
        *(f32x4*)&out[(m0 + r) * DM + n0 + c] = *(f32x4*)&cs[r * 64 + c];
    }
}

// ---------------------------------------------------------------------------
extern "C" void kernel_launch(void* const* d_in, const int* in_sizes, int n_in,
                              void* d_out, int out_size, void* d_ws, size_t ws_size,
                              hipStream_t stream) {
    const float* q  = (const float*)d_in[0];
    const float* kv = (const float*)d_in[1];
    const float* Wq = (const float*)d_in[2];
    const float* bq = (const float*)d_in[3];
    const float* Wk = (const float*)d_in[4];
    const float* bk = (const float*)d_in[5];
    const float* Wv = (const float*)d_in[6];
    const float* bv = (const float*)d_in[7];
    const float* Wo = (const float*)d_in[8];
    const float* bo = (const float*)d_in[9];
    float* out = (float*)d_out;

    // workspace carve-up (~84.9 MB)
    char* p = (char*)d_ws;
    float* kv_sum = (float*)p;              p += (size_t)BSZ * NH * HD * HD * 4;
    float* ksum   = (float*)p;              p += (size_t)BSZ * NH * HD * 4;
    _Float16* wqt_hi = (_Float16*)p;        p += (size_t)NH * HD * DM * 2;
    _Float16* wqt_lo = (_Float16*)p;        p += (size_t)NH * HD * DM * 2;
    _Float16* wkt_hi = (_Float16*)p;        p += (size_t)NH * HD * DM * 2;
    _Float16* wkt_lo = (_Float16*)p;        p += (size_t)NH * HD * DM * 2;
    _Float16* wvt_hi = (_Float16*)p;        p += (size_t)NH * HD * DM * 2;
    _Float16* wvt_lo = (_Float16*)p;        p += (size_t)NH * HD * DM * 2;
    _Float16* wo_hi  = (_Float16*)p;        p += (size_t)DM * DM * 2;
    _Float16* wo_lo  = (_Float16*)p;        p += (size_t)DM * DM * 2;
    _Float16* buf_hi = (_Float16*)p;        p += (size_t)BT * DM * 2;   // kv frags, then attn frags
    _Float16* buf_lo = (_Float16*)p;        p += (size_t)BT * DM * 2;

    size_t zero_bytes = ((size_t)BSZ * NH * HD * HD + (size_t)BSZ * NH * HD) * sizeof(float);
    hipMemsetAsync(d_ws, 0, zero_bytes, stream);

    fragsplit_kernel<<<(BT * DM / 8) / 256, 256, 0, stream>>>(kv, buf_hi, buf_lo);
    wsplit_kernel<<<dim3(DM / 64, NH, 3), 256, 0, stream>>>(
        Wq, Wk, Wv, wqt_hi, wqt_lo, wkt_hi, wkt_lo, wvt_hi, wvt_lo);
    fragsplit_kernel<<<(DM * DM / 8) / 256, 256, 0, stream>>>(Wo, wo_hi, wo_lo);

    kv_stats_kernel<<<dim3(TSEQ / 256, NH, BSZ), 256, 0, stream>>>(
        buf_hi, buf_lo, wkt_hi, wkt_lo, wvt_hi, wvt_lo, bk, bv, kv_sum, ksum);
    q_attn_kernel<<<dim3(TSEQ / 64, NH, BSZ), 256, 0, stream>>>(
        q, wqt_hi, wqt_lo, bq, kv_sum, ksum, buf_hi, buf_lo);   // kv frags dead; reuse as attn
    out_proj_kernel<<<dim3(DM / 64, BT / 128), 256, 0, stream>>>(
        buf_hi, buf_lo, wo_hi, wo_lo, bo, out);
}

// Round 3
// 803.205 us; speedup vs baseline: 1.4497x; 1.0280x over previous
//
#include <hip/hip_runtime.h>

#define BSZ 4
#define TSEQ 4096
#define DM 1024
#define NH 16
#define HD 64
#define BT (BSZ * TSEQ)
#define INV_LOSCALE (1.0f / 4096.0f)

using f32x4 = __attribute__((ext_vector_type(4))) float;
using f16x8 = __attribute__((ext_vector_type(8))) _Float16;
using u32x2 = __attribute__((ext_vector_type(2))) unsigned;
using u32x4 = __attribute__((ext_vector_type(4))) unsigned;

typedef const __attribute__((address_space(1))) void* gas_ptr;
typedef __attribute__((address_space(3))) void* las_ptr;

// Async global->LDS, 16 B per lane. LDS dest = uniform base + lane*16.
__device__ __forceinline__ void gload16(const void* g, void* l) {
    __builtin_amdgcn_global_load_lds((gas_ptr)g, (las_ptr)l, 16, 0, 0);
}

// f16 RTN split: x = hi + lo/4096 + r. lo pre-scaled by 4096 (denormal immunity).
__device__ __forceinline__ void split1(float x, _Float16& h, _Float16& l) {
    h = (_Float16)x;
    l = (_Float16)((x - (float)h) * 4096.0f);
}
__device__ __forceinline__ unsigned pack2(_Float16 a, _Float16 b) {
    return (unsigned)__builtin_bit_cast(unsigned short, a) |
           ((unsigned)__builtin_bit_cast(unsigned short, b) << 16);
}
__device__ __forceinline__ f32x4 mfma_f16(f16x8 a, f16x8 b, f32x4 c) {
    return __builtin_amdgcn_mfma_f32_16x16x32_f16(a, b, c, 0, 0, 0);
}

// ---------------------------------------------------------------------------
// Fragment-linear layout: row-major [R][1024] fp32 -> per 64-row panel, per
// 32-k step, a 64x32 tile stored as 256 x 16B chunks ordered
// chunk = [rb(4)][kquad(4)][l15(16)] (lane i of a wave reads bytes i*16).
// ---------------------------------------------------------------------------
__global__ __launch_bounds__(256) void fragsplit_kernel(const float* __restrict__ in,
        _Float16* __restrict__ hi, _Float16* __restrict__ lo) {
    const int C = blockIdx.x * 256 + threadIdx.x;      // global chunk id
    const int l15 = C & 15, quad = (C >> 4) & 3, rb = (C >> 6) & 3;
    const int s = (C >> 8) & 31, panel = C >> 13;
    const size_t src = ((size_t)(panel * 64 + rb * 16 + l15)) * DM + s * 32 + quad * 8;
    f32x4 v0 = *(const f32x4*)&in[src];
    f32x4 v1 = *(const f32x4*)&in[src + 4];
    _Float16 h[8], l[8];
    #pragma unroll
    for (int j = 0; j < 4; ++j) { split1(v0[j], h[j], l[j]); split1(v1[j], h[4 + j], l[4 + j]); }
    ((u32x4*)hi)[C] = (u32x4){pack2(h[0],h[1]), pack2(h[2],h[3]), pack2(h[4],h[5]), pack2(h[6],h[7])};
    ((u32x4*)lo)[C] = (u32x4){pack2(l[0],l[1]), pack2(l[2],l[3]), pack2(l[4],l[5]), pack2(l[6],l[7])};
}

// ---------------------------------------------------------------------------
// Wq/Wk/Wv [h][k][n] -> transposed fragment-linear hi/lo f16 (panel = head).
// ---------------------------------------------------------------------------
__global__ __launch_bounds__(256) void wsplit_kernel(
    const float* __restrict__ Wq, const float* __restrict__ Wk, const float* __restrict__ Wv,
    _Float16* __restrict__ qh, _Float16* __restrict__ ql,
    _Float16* __restrict__ kh, _Float16* __restrict__ kl,
    _Float16* __restrict__ vh, _Float16* __restrict__ vl) {
    const int tid = threadIdx.x;
    const int k0 = blockIdx.x * 64, h = blockIdx.y, w = blockIdx.z;
    const float* __restrict__ W = (w == 0) ? Wq : (w == 1) ? Wk : Wv;
    _Float16* __restrict__ dh = (w == 0) ? qh : (w == 1) ? kh : vh;
    _Float16* __restrict__ dl = (w == 0) ? ql : (w == 1) ? kl : vl;
    __shared__ __align__(16) float ws_[64][68];
    #pragma unroll
    for (int it = 0; it < 4; ++it) {
        int idx = it * 256 + tid;
        int r = idx >> 4, c4 = (idx & 15) * 4;
        *(f32x4*)&ws_[r][c4] = *(const f32x4*)&W[((size_t)h * DM + k0 + r) * HD + c4];
    }
    __syncthreads();
    const int n = tid >> 2, kq16 = (tid & 3) * 16;
    _Float16 hh[16], ll[16];
    #pragma unroll
    for (int j = 0; j < 16; ++j) split1(ws_[kq16 + j][n], hh[j], ll[j]);
    #pragma unroll
    for (int c = 0; c < 2; ++c) {
        int kg = k0 + kq16 + c * 8;
        int s = kg >> 5, quad = (kg >> 3) & 3;
        size_t chunk = (size_t)(h * 32 + s) * 256 + ((n >> 4) * 4 + quad) * 16 + (n & 15);
        ((u32x4*)dh)[chunk] = (u32x4){pack2(hh[c*8+0],hh[c*8+1]), pack2(hh[c*8+2],hh[c*8+3]),
                                      pack2(hh[c*8+4],hh[c*8+5]), pack2(hh[c*8+6],hh[c*8+7])};
        ((u32x4*)dl)[chunk] = (u32x4){pack2(ll[c*8+0],ll[c*8+1]), pack2(ll[c*8+2],ll[c*8+3]),
                                      pack2(ll[c*8+4],ll[c*8+5]), pack2(ll[c*8+6],ll[c*8+7])};
    }
}

// ---------------------------------------------------------------------------
// Kernel 1: kh = (kv@Wk+bk)^2, vh = kv@Wv+bv via 3-term f16-split MFMA.
// T4 counted-vmcnt pipeline: raw s_barrier (NO vmcnt(0) drain); steady-state
// s_waitcnt vmcnt(6) keeps the next tile's 6 global_load_lds in flight
// across the barrier. 4 t-tiles per block -> one atomic commit.
// ---------------------------------------------------------------------------
__global__ __launch_bounds__(256, 3) void kv_stats_kernel(
    const _Float16* __restrict__ kv_hi, const _Float16* __restrict__ kv_lo,
    const _Float16* __restrict__ wkt_hi, const _Float16* __restrict__ wkt_lo,
    const _Float16* __restrict__ wvt_hi, const _Float16* __restrict__ wvt_lo,
    const float* __restrict__ bk, const float* __restrict__ bv,
    float* __restrict__ kv_sum, float* __restrict__ ksum)
{
    const int tid = threadIdx.x;
    const int lane = tid & 63, wave = tid >> 6, quad = lane >> 4, l15 = lane & 15;
    const int b = blockIdx.z, h = blockIdx.y, bx = blockIdx.x;

    // dbuf staging: buffer p at p*24576; within: a_hi 0, a_lo 4K, bkh 8K,
    // bkl 12K, bvh 16K, bvl 20K. Epilogue scratch khs/vhs alias (post-barrier).
    __shared__ __align__(16) char smem[49152];
    float* khs = (float*)smem;
    float* vhs = (float*)(smem + 16384);

    const int isV = wave >> 1, w1 = wave & 1;
    const size_t btile = (size_t)h * 32;
    const int ty = tid >> 4, tx = tid & 15;

    f32x4 akv[4] = {};
    float aks[4] = {0.f, 0.f, 0.f, 0.f};

    for (int sub = 0; sub < 4; ++sub) {
        const size_t atile = (size_t)(b * 64 + bx * 4 + sub) * 32;
        auto stage = [&](int p, int s) {
            char* dst = smem + p * 24576 + tid * 16;
            const size_t ao = (atile + s) * 2048 + tid * 8;
            const size_t bo = (btile + s) * 2048 + tid * 8;
            gload16(&kv_hi[ao],  dst);
            gload16(&kv_lo[ao],  dst + 4096);
            gload16(&wkt_hi[bo], dst + 8192);
            gload16(&wkt_lo[bo], dst + 12288);
            gload16(&wvt_hi[bo], dst + 16384);
            gload16(&wvt_lo[bo], dst + 20480);
        };

        f32x4 acc_h[2][4] = {}, acc_c[2][4] = {};
        stage(0, 0);                                  // tile 0 in flight (6)
        for (int s = 0; s < 32; ++s) {
            const int p = s & 1;
            if (s < 31) {
                stage(p ^ 1, s + 1);                  // 12 outstanding
                asm volatile("s_waitcnt vmcnt(6)" ::: "memory");  // tile s done, s+1 in flight
            } else {
                asm volatile("s_waitcnt vmcnt(0)" ::: "memory");
            }
            __builtin_amdgcn_s_barrier();
            __builtin_amdgcn_sched_barrier(0);
            const char* bufc = smem + p * 24576;
            const _Float16* a_hi = (const _Float16*)bufc;
            const _Float16* a_lo = (const _Float16*)(bufc + 4096);
            const _Float16* bh = (const _Float16*)(bufc + (isV ? 16384 : 8192));
            const _Float16* bl = (const _Float16*)(bufc + (isV ? 20480 : 12288));
            f16x8 afh[2], afl[2], bfh[4], bfl[4];
            #pragma unroll
            for (int mt = 0; mt < 2; ++mt) {          // lane-linear, conflict-free
                afh[mt] = *(const f16x8*)&a_hi[(w1 * 2 + mt) * 512 + lane * 8];
                afl[mt] = *(const f16x8*)&a_lo[(w1 * 2 + mt) * 512 + lane * 8];
            }
            #pragma unroll
            for (int nt = 0; nt < 4; ++nt) {
                bfh[nt] = *(const f16x8*)&bh[nt * 512 + lane * 8];
                bfl[nt] = *(const f16x8*)&bl[nt * 512 + lane * 8];
            }
            #pragma unroll
            for (int mt = 0; mt < 2; ++mt)
                #pragma unroll
                for (int nt = 0; nt < 4; ++nt) {
                    acc_h[mt][nt] = mfma_f16(afh[mt], bfh[nt], acc_h[mt][nt]);
                    acc_c[mt][nt] = mfma_f16(afh[mt], bfl[nt], acc_c[mt][nt]);
                    acc_c[mt][nt] = mfma_f16(afl[mt], bfh[nt], acc_c[mt][nt]);
                }
            __builtin_amdgcn_s_barrier();             // tile p consumed; s+1 may overwrite
            __builtin_amdgcn_sched_barrier(0);
        }

        // epilogue: combine hi+lo/4096 + bias; square kh. Scratch aliases
        // staging -- safe: vmcnt(0) at s=31 + final barrier drained everything.
        {
            const float* __restrict__ bias = (isV ? bv : bk) + h * HD;
            float* __restrict__ outs = isV ? vhs : khs;
            float bia[4];
            #pragma unroll
            for (int nt = 0; nt < 4; ++nt) bia[nt] = bias[nt * 16 + l15];
            #pragma unroll
            for (int mt = 0; mt < 2; ++mt)
                #pragma unroll
                for (int nt = 0; nt < 4; ++nt)
                    #pragma unroll
                    for (int r = 0; r < 4; ++r) {
                        int t = w1 * 32 + mt * 16 + quad * 4 + r;
                        float v = acc_h[mt][nt][r] + INV_LOSCALE * acc_c[mt][nt][r] + bia[nt];
                        if (!isV) v = v * v;          // wave-uniform branch
                        outs[t * 64 + nt * 16 + l15] = v;
                    }
        }
        __syncthreads();

        #pragma unroll 4
        for (int t = 0; t < 64; ++t) {
            f32x4 kd = *(const f32x4*)&khs[t * 64 + ty * 4];
            f32x4 ve = *(const f32x4*)&vhs[t * 64 + tx * 4];
            #pragma unroll
            for (int i = 0; i < 4; ++i) {
                aks[i] += kd[i];
                akv[i] += kd[i] * ve;
            }
        }
        __syncthreads();                              // scratch dead before next sub's staging
    }

    float* kvp = kv_sum + (size_t)(b * NH + h) * HD * HD;
    #pragma unroll
    for (int i = 0; i < 4; ++i)
        #pragma unroll
        for (int j = 0; j < 4; ++j)
            atomicAdd(&kvp[(ty * 4 + i) * HD + tx * 4 + j], akv[i][j]);
    if (tx == 0) {
        float* ksp = ksum + (b * NH + h) * HD;
        #pragma unroll
        for (int i = 0; i < 4; ++i) atomicAdd(&ksp[ty * 4 + i], aks[i]);
    }
}

// ---------------------------------------------------------------------------
// Kernel 2: qh = q@Wq+bq; T4 pipeline. Per iter vmem: 2 gload_lds (B, tile
// s+1) + 2 reg loads (q, tile s+2). The asplit's use of the q regs makes the
// compiler retire the older B loads; manual vmcnt(4) is belt-and-braces.
// Explicit lgkmcnt(0) before the barrier makes asplit's ds_writes visible
// (raw s_barrier does not drain lgkm).
// ---------------------------------------------------------------------------
__global__ __launch_bounds__(256, 3) void q_attn_kernel(
    const float* __restrict__ q,
    const _Float16* __restrict__ wqt_hi, const _Float16* __restrict__ wqt_lo,
    const float* __restrict__ bq,
    const float* __restrict__ kv_sum, const float* __restrict__ ksum,
    _Float16* __restrict__ attn_hi, _Float16* __restrict__ attn_lo)
{
    const int tid = threadIdx.x;
    const int lane = tid & 63, wave = tid >> 6, quad = lane >> 4, l15 = lane & 15;
    const int b = blockIdx.z, h = blockIdx.y, bx = blockIdx.x;
    const int t0 = bx * 64;

    // dbuf staging: buffer p at p*16384: a_hi 0, a_lo 4K, b_hi 8K, b_lo 12K.
    __shared__ __align__(16) char smem[32768];
    __shared__ __align__(16) float qs[64 * 68];
    __shared__ float z_s[64], ks_s[64];

    if (tid < 64) ks_s[tid] = ksum[(b * NH + h) * HD + tid];

    const int arb = tid >> 6, aquad = (tid >> 4) & 3, al15 = tid & 15;
    const float* __restrict__ qrow =
        q + ((size_t)b * TSEQ + t0 + arb * 16 + al15) * DM + aquad * 8;
    const size_t btile = (size_t)h * 32;

    auto asplit_write = [&](int p, f32x4 v0, f32x4 v1) {
        _Float16 hh[8], ll[8];
        #pragma unroll
        for (int j = 0; j < 4; ++j) { split1(v0[j], hh[j], ll[j]); split1(v1[j], hh[4+j], ll[4+j]); }
        char* dst = smem + p * 16384 + tid * 16;
        *(u32x4*)dst =
            (u32x4){pack2(hh[0],hh[1]), pack2(hh[2],hh[3]), pack2(hh[4],hh[5]), pack2(hh[6],hh[7])};
        *(u32x4*)(dst + 4096) =
            (u32x4){pack2(ll[0],ll[1]), pack2(ll[2],ll[3]), pack2(ll[4],ll[5]), pack2(ll[6],ll[7])};
    };
    auto stageB = [&](int p, int s) {
        char* dst = smem + p * 16384 + 8192 + tid * 16;
        const size_t bo = (btile + s) * 2048 + tid * 8;
        gload16(&wqt_hi[bo], dst);
        gload16(&wqt_lo[bo], dst + 4096);
    };

    f32x4 acc_h[4] = {}, acc_c[4] = {};
    f32x4 v0 = *(const f32x4*)&qrow[0];
    f32x4 v1 = *(const f32x4*)&qrow[4];
    asplit_write(0, v0, v1);                          // tile 0 -> buf 0
    stageB(0, 0);                                     // B0 in flight (2)
    v0 = *(const f32x4*)&qrow[32];                    // tile 1 regs in flight (2)
    v1 = *(const f32x4*)&qrow[36];
    asm volatile("s_waitcnt vmcnt(2) lgkmcnt(0)" ::: "memory");  // B0 done; A0 writes visible
    __builtin_amdgcn_s_barrier();
    __builtin_amdgcn_sched_barrier(0);

    for (int s = 0; s < 32; ++s) {
        const int p = s & 1;
        if (s < 31) {
            stageB(p ^ 1, s + 1);                     // prefetch next B tile
            asplit_write(p ^ 1, v0, v1);              // split next A tile (waits q regs)
            if (s < 30) {                             // q regs two tiles ahead
                v0 = *(const f32x4*)&qrow[(s + 2) * 32];
                v1 = *(const f32x4*)&qrow[(s + 2) * 32 + 4];
            }
            asm volatile("s_waitcnt vmcnt(4) lgkmcnt(0)" ::: "memory");  // B_s done; A writes visible
        } else {
            asm volatile("s_waitcnt vmcnt(0)" ::: "memory");
        }
        __builtin_amdgcn_s_barrier();
        __builtin_amdgcn_sched_barrier(0);
        const char* bufc = smem + p * 16384;
        f16x8 afh = *(const f16x8*)((const _Float16*)bufc + wave * 512 + lane * 8);
        f16x8 afl = *(const f16x8*)((const _Float16*)(bufc + 4096) + wave * 512 + lane * 8);
        f16x8 bfh[4], bfl[4];
        #pragma unroll
        for (int nt = 0; nt < 4; ++nt) {
            bfh[nt] = *(const f16x8*)((const _Float16*)(bufc + 8192) + nt * 512 + lane * 8);
            bfl[nt] = *(const f16x8*)((const _Float16*)(bufc + 12288) + nt * 512 + lane * 8);
        }
        #pragma unroll
        for (int nt = 0; nt < 4; ++nt) {
            acc_h[nt] = mfma_f16(afh, bfh[nt], acc_h[nt]);
            acc_c[nt] = mfma_f16(afh, bfl[nt], acc_c[nt]);
            acc_c[nt] = mfma_f16(afl, bfh[nt], acc_c[nt]);
        }
        __builtin_amdgcn_s_barrier();                 // buf p consumed
        __builtin_amdgcn_sched_barrier(0);
    }

    // epilogue: qh2 -> qs; z via shfl over the 16 n-lanes
    {
        const int mrow0 = wave * 16;
        const float* __restrict__ bias = bq + h * HD;
        float zp[4] = {0.f, 0.f, 0.f, 0.f};
        #pragma unroll
        for (int nt = 0; nt < 4; ++nt) {
            int d = nt * 16 + l15;
            float bia = bias[d];
            float ks  = ks_s[d];
            #pragma unroll
            for (int r = 0; r < 4; ++r) {
                int t = mrow0 + quad * 4 + r;
                float v = acc_h[nt][r] + INV_LOSCALE * acc_c[nt][r] + bia;
                float v2 = v * v;
                qs[t * 68 + d] = v2;
                zp[r] = fmaf(v2, ks, zp[r]);
            }
        }
        #pragma unroll
        for (int r = 0; r < 4; ++r) {
            float p = zp[r];
            p += __shfl_xor(p, 1);
            p += __shfl_xor(p, 2);
            p += __shfl_xor(p, 4);
            p += __shfl_xor(p, 8);
            if (l15 == 0) z_s[mrow0 + quad * 4 + r] = 1.f / (p + 1e-6f);
        }
    }
    __syncthreads();

    // reload kv_sum into dead staging region
    float* kvs = (float*)smem;
    {
        const float* __restrict__ kvp = kv_sum + (size_t)(b * NH + h) * HD * HD;
        #pragma unroll
        for (int it = 0; it < 4; ++it) {
            int idx = it * 256 + tid;
            int r = idx >> 4, c = (idx & 15) * 4;
            *(f32x4*)&kvs[r * 64 + c] = *(const f32x4*)&kvp[r * HD + c];
        }
    }
    __syncthreads();

    // mini-GEMM: sv[t][e] = sum_d qs[t][d]*kvs[d][e]; write attn fragment-linear
    const int ty = tid >> 4, tx = tid & 15;
    f32x4 sv[4] = {};
    #pragma unroll 4
    for (int d = 0; d < 64; d += 4) {
        f32x4 b0 = *(const f32x4*)&kvs[(d + 0) * 64 + tx * 4];
        f32x4 b1 = *(const f32x4*)&kvs[(d + 1) * 64 + tx * 4];
        f32x4 b2 = *(const f32x4*)&kvs[(d + 2) * 64 + tx * 4];
        f32x4 b3 = *(const f32x4*)&kvs[(d + 3) * 64 + tx * 4];
        #pragma unroll
        for (int i = 0; i < 4; ++i) {
            f32x4 av = *(const f32x4*)&qs[(ty * 4 + i) * 68 + d];
            sv[i] += av.x * b0 + av.y * b1 + av.z * b2 + av.w * b3;
        }
    }
    const size_t opanel = (size_t)b * 64 + bx;
    const int s_out = h * 2 + (tx >> 3);              // k-step of col h*64+tx*4
    const int kq = (tx >> 1) & 3;                     // k-quad within step
    const int rem8 = (tx & 1) * 8;                    // byte offset within chunk
    #pragma unroll
    for (int i = 0; i < 4; ++i) {
        int t = ty * 4 + i;
        f32x4 o = sv[i] * z_s[t];
        _Float16 hh[4], ll[4];
        #pragma unroll
        for (int j = 0; j < 4; ++j) split1(o[j], hh[j], ll[j]);
        size_t cb = (((opanel * 32 + s_out) * 256 + ((t >> 4) * 4 + kq) * 16 + (t & 15)) << 4) + rem8;
        *(u32x2*)((char*)attn_hi + cb) = (u32x2){pack2(hh[0], hh[1]), pack2(hh[2], hh[3])};
        *(u32x2*)((char*)attn_lo + cb) = (u32x2){pack2(ll[0], ll[1]), pack2(ll[2], ll[3])};
    }
}

// ---------------------------------------------------------------------------
// Kernel 3: out = attn @ Wo^T + bo. T4 counted-vmcnt pipeline, 6 loads/stage.
// Buffer p at p*24576: a_hi panel0 0 / panel1 4K, a_lo 8K/12K, b_hi 16K,
// b_lo 20K. fp32 epilogue scratch aliases.
// ---------------------------------------------------------------------------
__global__ __launch_bounds__(256, 3) void out_proj_kernel(
    const _Float16* __restrict__ attn_hi, const _Float16* __restrict__ attn_lo,
    const _Float16* __restrict__ wo_hi, const _Float16* __restrict__ wo_lo,
    const float* __restrict__ bo, float* __restrict__ out)
{
    const int tid = threadIdx.x;
    const int lane = tid & 63, wave = tid >> 6, quad = lane >> 4, l15 = lane & 15;
    const int n0 = blockIdx.x * 64;
    const size_t m0 = (size_t)blockIdx.y * 128;

    __shared__ __align__(16) char smem[49152];
    float* cs = (float*)smem;                         // epilogue reuse, 32K

    const size_t ap0 = (m0 >> 6) * 32, ap1 = ap0 + 32;
    const size_t bpn = (size_t)(n0 >> 6) * 32;

    auto stage = [&](int p, int s) {
        char* dst = smem + p * 24576 + tid * 16;
        const size_t co = (size_t)s * 2048 + tid * 8;
        gload16(&attn_hi[ap0 * 2048 + co], dst);
        gload16(&attn_hi[ap1 * 2048 + co], dst + 4096);
        gload16(&attn_lo[ap0 * 2048 + co], dst + 8192);
        gload16(&attn_lo[ap1 * 2048 + co], dst + 12288);
        gload16(&wo_hi[bpn * 2048 + co],  dst + 16384);
        gload16(&wo_lo[bpn * 2048 + co],  dst + 20480);
    };

    const int panel = wave >> 1;                      // rows 0-63 / 64-127
    f32x4 acc_h[2][4] = {}, acc_c[2][4] = {};
    stage(0, 0);
    for (int s = 0; s < 32; ++s) {
        const int p = s & 1;
        if (s < 31) {
            stage(p ^ 1, s + 1);
            asm volatile("s_waitcnt vmcnt(6)" ::: "memory");
        } else {
            asm volatile("s_waitcnt vmcnt(0)" ::: "memory");
        }
        __builtin_amdgcn_s_barrier();
        __builtin_amdgcn_sched_barrier(0);
        const char* bufc = smem + p * 24576;
        f16x8 afh[2], afl[2], bfh[4], bfl[4];
        #pragma unroll
        for (int mt = 0; mt < 2; ++mt) {
            int rbl = (wave & 1) * 2 + mt;            // row-block within panel
            afh[mt] = *(const f16x8*)((const _Float16*)(bufc + panel * 4096) + rbl * 512 + lane * 8);
            afl[mt] = *(const f16x8*)((const _Float16*)(bufc + 8192 + panel * 4096) + rbl * 512 + lane * 8);
        }
        #pragma unroll
        for (int nt = 0; nt < 4; ++nt) {
            bfh[nt] = *(const f16x8*)((const _Float16*)(bufc + 16384) + nt * 512 + lane * 8);
            bfl[nt] = *(const f16x8*)((const _Float16*)(bufc + 20480) + nt * 512 + lane * 8);
        }
        #pragma unroll
        for (int mt = 0; mt < 2; ++mt)
            #pragma unroll
            for (int nt = 0; nt < 4; ++nt) {
                acc_h[mt][nt] = mfma_f16(afh[mt], bfh[nt], acc_h[mt][nt]);
                acc_c[mt][nt] = mfma_f16(afh[mt], bfl[nt], acc_c[mt][nt]);
                acc_c[mt][nt] = mfma_f16(afl[mt], bfh[nt], acc_c[mt][nt]);
            }
        __builtin_amdgcn_s_barrier();
        __builtin_amdgcn_sched_barrier(0);
    }

    {
        float bia[4];
        #pragma unroll
        for (int nt = 0; nt < 4; ++nt) bia[nt] = bo[n0 + nt * 16 + l15];
        #pragma unroll
        for (int mt = 0; mt < 2; ++mt)
            #pragma unroll
            for (int nt = 0; nt < 4; ++nt)
                #pragma unroll
                for (int r = 0; r < 4; ++r) {
                    int t = wave * 32 + mt * 16 + quad * 4 + r;   // panel*64 + rbl*16 rows
                    cs[t * 64 + nt * 16 + l15] =
                        acc_h[mt][nt][r] + INV_LOSCALE * acc_c[mt][nt][r] + bia[nt];
                }
    }
    __syncthreads();
    #pragma unroll
    for (int it = 0; it < 8; ++it) {
        int idx = it * 256 + tid;
        int r = idx >> 4, c = (idx & 15) * 4;
        *(f32x4*)&out[(m0 + r) * DM + n0 + c] = *(f32x4*)&cs[r * 64 + c];
    }
}

// ---------------------------------------------------------------------------
extern "C" void kernel_launch(void* const* d_in, const int* in_sizes, int n_in,
                              void* d_out, int out_size, void* d_ws, size_t ws_size,
                              hipStream_t stream) {
    const float* q  = (const float*)d_in[0];
    const float* kv = (const float*)d_in[1];
    const float* Wq = (const float*)d_in[2];
    const float* bq = (const float*)d_in[3];
    const float* Wk = (const float*)d_in[4];
    const float* bk = (const float*)d_in[5];
    const float* Wv = (const float*)d_in[6];
    const float* bv = (const float*)d_in[7];
    const float* Wo = (const float*)d_in[8];
    const float* bo = (const float*)d_in[9];
    float* out = (float*)d_out;

    // workspace carve-up (~84.9 MB)
    char* p = (char*)d_ws;
    float* kv_sum = (float*)p;              p += (size_t)BSZ * NH * HD * HD * 4;
    float* ksum   = (float*)p;              p += (size_t)BSZ * NH * HD * 4;
    _Float16* wqt_hi = (_Float16*)p;        p += (size_t)NH * HD * DM * 2;
    _Float16* wqt_lo = (_Float16*)p;        p += (size_t)NH * HD * DM * 2;
    _Float16* wkt_hi = (_Float16*)p;        p += (size_t)NH * HD * DM * 2;
    _Float16* wkt_lo = (_Float16*)p;        p += (size_t)NH * HD * DM * 2;
    _Float16* wvt_hi = (_Float16*)p;        p += (size_t)NH * HD * DM * 2;
    _Float16* wvt_lo = (_Float16*)p;        p += (size_t)NH * HD * DM * 2;
    _Float16* wo_hi  = (_Float16*)p;        p += (size_t)DM * DM * 2;
    _Float16* wo_lo  = (_Float16*)p;        p += (size_t)DM * DM * 2;
    _Float16* buf_hi = (_Float16*)p;        p += (size_t)BT * DM * 2;   // kv frags, then attn frags
    _Float16* buf_lo = (_Float16*)p;        p += (size_t)BT * DM * 2;

    size_t zero_bytes = ((size_t)BSZ * NH * HD * HD + (size_t)BSZ * NH * HD) * sizeof(float);
    hipMemsetAsync(d_ws, 0, zero_bytes, stream);

    fragsplit_kernel<<<(BT * DM / 8) / 256, 256, 0, stream>>>(kv, buf_hi, buf_lo);
    wsplit_kernel<<<dim3(DM / 64, NH, 3), 256, 0, stream>>>(
        Wq, Wk, Wv, wqt_hi, wqt_lo, wkt_hi, wkt_lo, wvt_hi, wvt_lo);
    fragsplit_kernel<<<(DM * DM / 8) / 256, 256, 0, stream>>>(Wo, wo_hi, wo_lo);

    kv_stats_kernel<<<dim3(TSEQ / 256, NH, BSZ), 256, 0, stream>>>(
        buf_hi, buf_lo, wkt_hi, wkt_lo, wvt_hi, wvt_lo, bk, bv, kv_sum, ksum);
    q_attn_kernel<<<dim3(TSEQ / 64, NH, BSZ), 256, 0, stream>>>(
        q, wqt_hi, wqt_lo, bq, kv_sum, ksum, buf_hi, buf_lo);   // kv frags dead; reuse as attn
    out_proj_kernel<<<dim3(DM / 64, BT / 128), 256, 0, stream>>>(
        buf_hi, buf_lo, wo_hi, wo_lo, bo, out);
}

// Round 4
// 735.712 us; speedup vs baseline: 1.5827x; 1.0917x over previous
//
#include <hip/hip_runtime.h>

#define BSZ 4
#define TSEQ 4096
#define DM 1024
#define NH 16
#define HD 64
#define BT (BSZ * TSEQ)
#define INV_LOSCALE (1.0f / 4096.0f)

using f32x4 = __attribute__((ext_vector_type(4))) float;
using f16x8 = __attribute__((ext_vector_type(8))) _Float16;
using u32x2 = __attribute__((ext_vector_type(2))) unsigned;
using u32x4 = __attribute__((ext_vector_type(4))) unsigned;

typedef const __attribute__((address_space(1))) void* gas_ptr;
typedef __attribute__((address_space(3))) void* las_ptr;

// Async global->LDS, 16 B per lane. LDS dest = uniform base + lane*16.
__device__ __forceinline__ void gload16(const void* g, void* l) {
    __builtin_amdgcn_global_load_lds((gas_ptr)g, (las_ptr)l, 16, 0, 0);
}

// f16 RTN split: x = hi + lo/4096 + r. lo pre-scaled by 4096 (denormal immunity).
__device__ __forceinline__ void split1(float x, _Float16& h, _Float16& l) {
    h = (_Float16)x;
    l = (_Float16)((x - (float)h) * 4096.0f);
}
__device__ __forceinline__ unsigned pack2(_Float16 a, _Float16 b) {
    return (unsigned)__builtin_bit_cast(unsigned short, a) |
           ((unsigned)__builtin_bit_cast(unsigned short, b) << 16);
}
__device__ __forceinline__ f32x4 mfma_f16(f16x8 a, f16x8 b, f32x4 c) {
    return __builtin_amdgcn_mfma_f32_16x16x32_f16(a, b, c, 0, 0, 0);
}

// ---------------------------------------------------------------------------
// Fragment-linear layout: row-major [R][1024] fp32 -> per 64-row panel, per
// 32-k step, a 64x32 tile stored as 256 x 16B chunks ordered
// chunk = [rb(4)][kquad(4)][l15(16)] (lane i of a wave reads bytes i*16).
// ---------------------------------------------------------------------------
__global__ __launch_bounds__(256) void fragsplit_kernel(const float* __restrict__ in,
        _Float16* __restrict__ hi, _Float16* __restrict__ lo) {
    const int C = blockIdx.x * 256 + threadIdx.x;      // global chunk id
    const int l15 = C & 15, quad = (C >> 4) & 3, rb = (C >> 6) & 3;
    const int s = (C >> 8) & 31, panel = C >> 13;
    const size_t src = ((size_t)(panel * 64 + rb * 16 + l15)) * DM + s * 32 + quad * 8;
    f32x4 v0 = *(const f32x4*)&in[src];
    f32x4 v1 = *(const f32x4*)&in[src + 4];
    _Float16 h[8], l[8];
    #pragma unroll
    for (int j = 0; j < 4; ++j) { split1(v0[j], h[j], l[j]); split1(v1[j], h[4 + j], l[4 + j]); }
    ((u32x4*)hi)[C] = (u32x4){pack2(h[0],h[1]), pack2(h[2],h[3]), pack2(h[4],h[5]), pack2(h[6],h[7])};
    ((u32x4*)lo)[C] = (u32x4){pack2(l[0],l[1]), pack2(l[2],l[3]), pack2(l[4],l[5]), pack2(l[6],l[7])};
}

// ---------------------------------------------------------------------------
// Wq/Wk/Wv [h][k][n] -> transposed fragment-linear hi/lo f16 (panel = head).
// ---------------------------------------------------------------------------
__global__ __launch_bounds__(256) void wsplit_kernel(
    const float* __restrict__ Wq, const float* __restrict__ Wk, const float* __restrict__ Wv,
    _Float16* __restrict__ qh, _Float16* __restrict__ ql,
    _Float16* __restrict__ kh, _Float16* __restrict__ kl,
    _Float16* __restrict__ vh, _Float16* __restrict__ vl) {
    const int tid = threadIdx.x;
    const int k0 = blockIdx.x * 64, h = blockIdx.y, w = blockIdx.z;
    const float* __restrict__ W = (w == 0) ? Wq : (w == 1) ? Wk : Wv;
    _Float16* __restrict__ dh = (w == 0) ? qh : (w == 1) ? kh : vh;
    _Float16* __restrict__ dl = (w == 0) ? ql : (w == 1) ? kl : vl;
    __shared__ __align__(16) float ws_[64][68];
    #pragma unroll
    for (int it = 0; it < 4; ++it) {
        int idx = it * 256 + tid;
        int r = idx >> 4, c4 = (idx & 15) * 4;
        *(f32x4*)&ws_[r][c4] = *(const f32x4*)&W[((size_t)h * DM + k0 + r) * HD + c4];
    }
    __syncthreads();
    const int n = tid >> 2, kq16 = (tid & 3) * 16;
    _Float16 hh[16], ll[16];
    #pragma unroll
    for (int j = 0; j < 16; ++j) split1(ws_[kq16 + j][n], hh[j], ll[j]);
    #pragma unroll
    for (int c = 0; c < 2; ++c) {
        int kg = k0 + kq16 + c * 8;
        int s = kg >> 5, quad = (kg >> 3) & 3;
        size_t chunk = (size_t)(h * 32 + s) * 256 + ((n >> 4) * 4 + quad) * 16 + (n & 15);
        ((u32x4*)dh)[chunk] = (u32x4){pack2(hh[c*8+0],hh[c*8+1]), pack2(hh[c*8+2],hh[c*8+3]),
                                      pack2(hh[c*8+4],hh[c*8+5]), pack2(hh[c*8+6],hh[c*8+7])};
        ((u32x4*)dl)[chunk] = (u32x4){pack2(ll[c*8+0],ll[c*8+1]), pack2(ll[c*8+2],ll[c*8+3]),
                                      pack2(ll[c*8+4],ll[c*8+5]), pack2(ll[c*8+6],ll[c*8+7])};
    }
}

// ---------------------------------------------------------------------------
// Kernel 1: kh = (kv@Wk+bk)^2, vh = kv@Wv+bv via 3-term f16-split MFMA.
// T4 counted-vmcnt pipeline; 4 t-tiles per block -> one atomic commit.
// ---------------------------------------------------------------------------
__global__ __launch_bounds__(256, 3) void kv_stats_kernel(
    const _Float16* __restrict__ kv_hi, const _Float16* __restrict__ kv_lo,
    const _Float16* __restrict__ wkt_hi, const _Float16* __restrict__ wkt_lo,
    const _Float16* __restrict__ wvt_hi, const _Float16* __restrict__ wvt_lo,
    const float* __restrict__ bk, const float* __restrict__ bv,
    float* __restrict__ kv_sum, float* __restrict__ ksum)
{
    const int tid = threadIdx.x;
    const int lane = tid & 63, wave = tid >> 6, quad = lane >> 4, l15 = lane & 15;
    const int b = blockIdx.z, h = blockIdx.y, bx = blockIdx.x;

    __shared__ __align__(16) char smem[49152];
    float* khs = (float*)smem;
    float* vhs = (float*)(smem + 16384);

    const int isV = wave >> 1, w1 = wave & 1;
    const size_t btile = (size_t)h * 32;
    const int ty = tid >> 4, tx = tid & 15;

    f32x4 akv[4] = {};
    float aks[4] = {0.f, 0.f, 0.f, 0.f};

    for (int sub = 0; sub < 4; ++sub) {
        const size_t atile = (size_t)(b * 64 + bx * 4 + sub) * 32;
        auto stage = [&](int p, int s) {
            char* dst = smem + p * 24576 + tid * 16;
            const size_t ao = (atile + s) * 2048 + tid * 8;
            const size_t bo = (btile + s) * 2048 + tid * 8;
            gload16(&kv_hi[ao],  dst);
            gload16(&kv_lo[ao],  dst + 4096);
            gload16(&wkt_hi[bo], dst + 8192);
            gload16(&wkt_lo[bo], dst + 12288);
            gload16(&wvt_hi[bo], dst + 16384);
            gload16(&wvt_lo[bo], dst + 20480);
        };

        f32x4 acc_h[2][4] = {}, acc_c[2][4] = {};
        stage(0, 0);                                  // tile 0 in flight (6)
        for (int s = 0; s < 32; ++s) {
            const int p = s & 1;
            if (s < 31) {
                stage(p ^ 1, s + 1);                  // 12 outstanding
                asm volatile("s_waitcnt vmcnt(6)" ::: "memory");
            } else {
                asm volatile("s_waitcnt vmcnt(0)" ::: "memory");
            }
            __builtin_amdgcn_s_barrier();
            __builtin_amdgcn_sched_barrier(0);
            const char* bufc = smem + p * 24576;
            const _Float16* a_hi = (const _Float16*)bufc;
            const _Float16* a_lo = (const _Float16*)(bufc + 4096);
            const _Float16* bh = (const _Float16*)(bufc + (isV ? 16384 : 8192));
            const _Float16* bl = (const _Float16*)(bufc + (isV ? 20480 : 12288));
            f16x8 afh[2], afl[2], bfh[4], bfl[4];
            #pragma unroll
            for (int mt = 0; mt < 2; ++mt) {
                afh[mt] = *(const f16x8*)&a_hi[(w1 * 2 + mt) * 512 + lane * 8];
                afl[mt] = *(const f16x8*)&a_lo[(w1 * 2 + mt) * 512 + lane * 8];
            }
            #pragma unroll
            for (int nt = 0; nt < 4; ++nt) {
                bfh[nt] = *(const f16x8*)&bh[nt * 512 + lane * 8];
                bfl[nt] = *(const f16x8*)&bl[nt * 512 + lane * 8];
            }
            #pragma unroll
            for (int mt = 0; mt < 2; ++mt)
                #pragma unroll
                for (int nt = 0; nt < 4; ++nt) {
                    acc_h[mt][nt] = mfma_f16(afh[mt], bfh[nt], acc_h[mt][nt]);
                    acc_c[mt][nt] = mfma_f16(afh[mt], bfl[nt], acc_c[mt][nt]);
                    acc_c[mt][nt] = mfma_f16(afl[mt], bfh[nt], acc_c[mt][nt]);
                }
            __builtin_amdgcn_s_barrier();
            __builtin_amdgcn_sched_barrier(0);
        }

        {
            const float* __restrict__ bias = (isV ? bv : bk) + h * HD;
            float* __restrict__ outs = isV ? vhs : khs;
            float bia[4];
            #pragma unroll
            for (int nt = 0; nt < 4; ++nt) bia[nt] = bias[nt * 16 + l15];
            #pragma unroll
            for (int mt = 0; mt < 2; ++mt)
                #pragma unroll
                for (int nt = 0; nt < 4; ++nt)
                    #pragma unroll
                    for (int r = 0; r < 4; ++r) {
                        int t = w1 * 32 + mt * 16 + quad * 4 + r;
                        float v = acc_h[mt][nt][r] + INV_LOSCALE * acc_c[mt][nt][r] + bia[nt];
                        if (!isV) v = v * v;          // wave-uniform branch
                        outs[t * 64 + nt * 16 + l15] = v;
                    }
        }
        __syncthreads();

        #pragma unroll 4
        for (int t = 0; t < 64; ++t) {
            f32x4 kd = *(const f32x4*)&khs[t * 64 + ty * 4];
            f32x4 ve = *(const f32x4*)&vhs[t * 64 + tx * 4];
            #pragma unroll
            for (int i = 0; i < 4; ++i) {
                aks[i] += kd[i];
                akv[i] += kd[i] * ve;
            }
        }
        __syncthreads();
    }

    float* kvp = kv_sum + (size_t)(b * NH + h) * HD * HD;
    #pragma unroll
    for (int i = 0; i < 4; ++i)
        #pragma unroll
        for (int j = 0; j < 4; ++j)
            atomicAdd(&kvp[(ty * 4 + i) * HD + tx * 4 + j], akv[i][j]);
    if (tx == 0) {
        float* ksp = ksum + (b * NH + h) * HD;
        #pragma unroll
        for (int i = 0; i < 4; ++i) atomicAdd(&ksp[ty * 4 + i], aks[i]);
    }
}

// ---------------------------------------------------------------------------
// Kernel 2a (pre-split q path): qh = qf@Wq+bq with ALL staging via
// global_load_lds (4/step, steady-state vmcnt(4)); kills the 16x-redundant
// per-head q split VALU work. Epilogue identical to 2b.
// ---------------------------------------------------------------------------
__global__ __launch_bounds__(256, 3) void q_attn_ps_kernel(
    const _Float16* __restrict__ qf_hi, const _Float16* __restrict__ qf_lo,
    const _Float16* __restrict__ wqt_hi, const _Float16* __restrict__ wqt_lo,
    const float* __restrict__ bq,
    const float* __restrict__ kv_sum, const float* __restrict__ ksum,
    _Float16* __restrict__ attn_hi, _Float16* __restrict__ attn_lo)
{
    const int tid = threadIdx.x;
    const int lane = tid & 63, wave = tid >> 6, quad = lane >> 4, l15 = lane & 15;
    const int b = blockIdx.z, h = blockIdx.y, bx = blockIdx.x;

    // dbuf staging: buffer p at p*16384: a_hi 0, a_lo 4K, b_hi 8K, b_lo 12K.
    __shared__ __align__(16) char smem[32768];
    __shared__ __align__(16) float qs[64 * 68];
    __shared__ float z_s[64], ks_s[64];

    if (tid < 64) ks_s[tid] = ksum[(b * NH + h) * HD + tid];

    const size_t atile = (size_t)(b * 64 + bx) * 32;
    const size_t btile = (size_t)h * 32;

    auto stage = [&](int p, int s) {
        char* dst = smem + p * 16384 + tid * 16;
        const size_t ao = (atile + s) * 2048 + tid * 8;
        const size_t bo = (btile + s) * 2048 + tid * 8;
        gload16(&qf_hi[ao],  dst);
        gload16(&qf_lo[ao],  dst + 4096);
        gload16(&wqt_hi[bo], dst + 8192);
        gload16(&wqt_lo[bo], dst + 12288);
    };

    f32x4 acc_h[4] = {}, acc_c[4] = {};
    stage(0, 0);                                      // 4 in flight
    for (int s = 0; s < 32; ++s) {
        const int p = s & 1;
        if (s < 31) {
            stage(p ^ 1, s + 1);                      // 8 outstanding
            asm volatile("s_waitcnt vmcnt(4)" ::: "memory");  // tile s ready
        } else {
            asm volatile("s_waitcnt vmcnt(0)" ::: "memory");
        }
        __builtin_amdgcn_s_barrier();
        __builtin_amdgcn_sched_barrier(0);
        const char* bufc = smem + p * 16384;
        f16x8 afh = *(const f16x8*)((const _Float16*)bufc + wave * 512 + lane * 8);
        f16x8 afl = *(const f16x8*)((const _Float16*)(bufc + 4096) + wave * 512 + lane * 8);
        f16x8 bfh[4], bfl[4];
        #pragma unroll
        for (int nt = 0; nt < 4; ++nt) {
            bfh[nt] = *(const f16x8*)((const _Float16*)(bufc + 8192) + nt * 512 + lane * 8);
            bfl[nt] = *(const f16x8*)((const _Float16*)(bufc + 12288) + nt * 512 + lane * 8);
        }
        #pragma unroll
        for (int nt = 0; nt < 4; ++nt) {
            acc_h[nt] = mfma_f16(afh, bfh[nt], acc_h[nt]);
            acc_c[nt] = mfma_f16(afh, bfl[nt], acc_c[nt]);
            acc_c[nt] = mfma_f16(afl, bfh[nt], acc_c[nt]);
        }
        __builtin_amdgcn_s_barrier();                 // buf p consumed
        __builtin_amdgcn_sched_barrier(0);
    }

    // epilogue: qh2 -> qs; z via shfl over the 16 n-lanes
    {
        const int mrow0 = wave * 16;
        const float* __restrict__ bias = bq + h * HD;
        float zp[4] = {0.f, 0.f, 0.f, 0.f};
        #pragma unroll
        for (int nt = 0; nt < 4; ++nt) {
            int d = nt * 16 + l15;
            float bia = bias[d];
            float ks  = ks_s[d];
            #pragma unroll
            for (int r = 0; r < 4; ++r) {
                int t = mrow0 + quad * 4 + r;
                float v = acc_h[nt][r] + INV_LOSCALE * acc_c[nt][r] + bia;
                float v2 = v * v;
                qs[t * 68 + d] = v2;
                zp[r] = fmaf(v2, ks, zp[r]);
            }
        }
        #pragma unroll
        for (int r = 0; r < 4; ++r) {
            float p = zp[r];
            p += __shfl_xor(p, 1);
            p += __shfl_xor(p, 2);
            p += __shfl_xor(p, 4);
            p += __shfl_xor(p, 8);
            if (l15 == 0) z_s[mrow0 + quad * 4 + r] = 1.f / (p + 1e-6f);
        }
    }
    __syncthreads();

    // reload kv_sum into dead staging region
    float* kvs = (float*)smem;
    {
        const float* __restrict__ kvp = kv_sum + (size_t)(b * NH + h) * HD * HD;
        #pragma unroll
        for (int it = 0; it < 4; ++it) {
            int idx = it * 256 + tid;
            int r = idx >> 4, c = (idx & 15) * 4;
            *(f32x4*)&kvs[r * 64 + c] = *(const f32x4*)&kvp[r * HD + c];
        }
    }
    __syncthreads();

    // mini-GEMM: sv[t][e] = sum_d qs[t][d]*kvs[d][e]; write attn fragment-linear
    const int ty = tid >> 4, tx = tid & 15;
    f32x4 sv[4] = {};
    #pragma unroll 4
    for (int d = 0; d < 64; d += 4) {
        f32x4 b0 = *(const f32x4*)&kvs[(d + 0) * 64 + tx * 4];
        f32x4 b1 = *(const f32x4*)&kvs[(d + 1) * 64 + tx * 4];
        f32x4 b2 = *(const f32x4*)&kvs[(d + 2) * 64 + tx * 4];
        f32x4 b3 = *(const f32x4*)&kvs[(d + 3) * 64 + tx * 4];
        #pragma unroll
        for (int i = 0; i < 4; ++i) {
            f32x4 av = *(const f32x4*)&qs[(ty * 4 + i) * 68 + d];
            sv[i] += av.x * b0 + av.y * b1 + av.z * b2 + av.w * b3;
        }
    }
    const size_t opanel = (size_t)b * 64 + bx;
    const int s_out = h * 2 + (tx >> 3);
    const int kq = (tx >> 1) & 3;
    const int rem8 = (tx & 1) * 8;
    #pragma unroll
    for (int i = 0; i < 4; ++i) {
        int t = ty * 4 + i;
        f32x4 o = sv[i] * z_s[t];
        _Float16 hh[4], ll[4];
        #pragma unroll
        for (int j = 0; j < 4; ++j) split1(o[j], hh[j], ll[j]);
        size_t cb = (((opanel * 32 + s_out) * 256 + ((t >> 4) * 4 + kq) * 16 + (t & 15)) << 4) + rem8;
        *(u32x2*)((char*)attn_hi + cb) = (u32x2){pack2(hh[0], hh[1]), pack2(hh[2], hh[3])};
        *(u32x2*)((char*)attn_lo + cb) = (u32x2){pack2(ll[0], ll[1]), pack2(ll[2], ll[3])};
    }
}

// ---------------------------------------------------------------------------
// Kernel 2b (fallback, ws too small): on-the-fly q split. Identical to R3.
// ---------------------------------------------------------------------------
__global__ __launch_bounds__(256, 3) void q_attn_kernel(
    const float* __restrict__ q,
    const _Float16* __restrict__ wqt_hi, const _Float16* __restrict__ wqt_lo,
    const float* __restrict__ bq,
    const float* __restrict__ kv_sum, const float* __restrict__ ksum,
    _Float16* __restrict__ attn_hi, _Float16* __restrict__ attn_lo)
{
    const int tid = threadIdx.x;
    const int lane = tid & 63, wave = tid >> 6, quad = lane >> 4, l15 = lane & 15;
    const int b = blockIdx.z, h = blockIdx.y, bx = blockIdx.x;
    const int t0 = bx * 64;

    __shared__ __align__(16) char smem[32768];
    __shared__ __align__(16) float qs[64 * 68];
    __shared__ float z_s[64], ks_s[64];

    if (tid < 64) ks_s[tid] = ksum[(b * NH + h) * HD + tid];

    const int arb = tid >> 6, aquad = (tid >> 4) & 3, al15 = tid & 15;
    const float* __restrict__ qrow =
        q + ((size_t)b * TSEQ + t0 + arb * 16 + al15) * DM + aquad * 8;
    const size_t btile = (size_t)h * 32;

    auto asplit_write = [&](int p, f32x4 v0, f32x4 v1) {
        _Float16 hh[8], ll[8];
        #pragma unroll
        for (int j = 0; j < 4; ++j) { split1(v0[j], hh[j], ll[j]); split1(v1[j], hh[4+j], ll[4+j]); }
        char* dst = smem + p * 16384 + tid * 16;
        *(u32x4*)dst =
            (u32x4){pack2(hh[0],hh[1]), pack2(hh[2],hh[3]), pack2(hh[4],hh[5]), pack2(hh[6],hh[7])};
        *(u32x4*)(dst + 4096) =
            (u32x4){pack2(ll[0],ll[1]), pack2(ll[2],ll[3]), pack2(ll[4],ll[5]), pack2(ll[6],ll[7])};
    };
    auto stageB = [&](int p, int s) {
        char* dst = smem + p * 16384 + 8192 + tid * 16;
        const size_t bo = (btile + s) * 2048 + tid * 8;
        gload16(&wqt_hi[bo], dst);
        gload16(&wqt_lo[bo], dst + 4096);
    };

    f32x4 acc_h[4] = {}, acc_c[4] = {};
    f32x4 v0 = *(const f32x4*)&qrow[0];
    f32x4 v1 = *(const f32x4*)&qrow[4];
    asplit_write(0, v0, v1);
    stageB(0, 0);
    v0 = *(const f32x4*)&qrow[32];
    v1 = *(const f32x4*)&qrow[36];
    asm volatile("s_waitcnt vmcnt(2) lgkmcnt(0)" ::: "memory");
    __builtin_amdgcn_s_barrier();
    __builtin_amdgcn_sched_barrier(0);

    for (int s = 0; s < 32; ++s) {
        const int p = s & 1;
        if (s < 31) {
            stageB(p ^ 1, s + 1);
            asplit_write(p ^ 1, v0, v1);
            if (s < 30) {
                v0 = *(const f32x4*)&qrow[(s + 2) * 32];
                v1 = *(const f32x4*)&qrow[(s + 2) * 32 + 4];
            }
            asm volatile("s_waitcnt vmcnt(4) lgkmcnt(0)" ::: "memory");
        } else {
            asm volatile("s_waitcnt vmcnt(0)" ::: "memory");
        }
        __builtin_amdgcn_s_barrier();
        __builtin_amdgcn_sched_barrier(0);
        const char* bufc = smem + p * 16384;
        f16x8 afh = *(const f16x8*)((const _Float16*)bufc + wave * 512 + lane * 8);
        f16x8 afl = *(const f16x8*)((const _Float16*)(bufc + 4096) + wave * 512 + lane * 8);
        f16x8 bfh[4], bfl[4];
        #pragma unroll
        for (int nt = 0; nt < 4; ++nt) {
            bfh[nt] = *(const f16x8*)((const _Float16*)(bufc + 8192) + nt * 512 + lane * 8);
            bfl[nt] = *(const f16x8*)((const _Float16*)(bufc + 12288) + nt * 512 + lane * 8);
        }
        #pragma unroll
        for (int nt = 0; nt < 4; ++nt) {
            acc_h[nt] = mfma_f16(afh, bfh[nt], acc_h[nt]);
            acc_c[nt] = mfma_f16(afh, bfl[nt], acc_c[nt]);
            acc_c[nt] = mfma_f16(afl, bfh[nt], acc_c[nt]);
        }
        __builtin_amdgcn_s_barrier();
        __builtin_amdgcn_sched_barrier(0);
    }

    {
        const int mrow0 = wave * 16;
        const float* __restrict__ bias = bq + h * HD;
        float zp[4] = {0.f, 0.f, 0.f, 0.f};
        #pragma unroll
        for (int nt = 0; nt < 4; ++nt) {
            int d = nt * 16 + l15;
            float bia = bias[d];
            float ks  = ks_s[d];
            #pragma unroll
            for (int r = 0; r < 4; ++r) {
                int t = mrow0 + quad * 4 + r;
                float v = acc_h[nt][r] + INV_LOSCALE * acc_c[nt][r] + bia;
                float v2 = v * v;
                qs[t * 68 + d] = v2;
                zp[r] = fmaf(v2, ks, zp[r]);
            }
        }
        #pragma unroll
        for (int r = 0; r < 4; ++r) {
            float p = zp[r];
            p += __shfl_xor(p, 1);
            p += __shfl_xor(p, 2);
            p += __shfl_xor(p, 4);
            p += __shfl_xor(p, 8);
            if (l15 == 0) z_s[mrow0 + quad * 4 + r] = 1.f / (p + 1e-6f);
        }
    }
    __syncthreads();

    float* kvs = (float*)smem;
    {
        const float* __restrict__ kvp = kv_sum + (size_t)(b * NH + h) * HD * HD;
        #pragma unroll
        for (int it = 0; it < 4; ++it) {
            int idx = it * 256 + tid;
            int r = idx >> 4, c = (idx & 15) * 4;
            *(f32x4*)&kvs[r * 64 + c] = *(const f32x4*)&kvp[r * HD + c];
        }
    }
    __syncthreads();

    const int ty = tid >> 4, tx = tid & 15;
    f32x4 sv[4] = {};
    #pragma unroll 4
    for (int d = 0; d < 64; d += 4) {
        f32x4 b0 = *(const f32x4*)&kvs[(d + 0) * 64 + tx * 4];
        f32x4 b1 = *(const f32x4*)&kvs[(d + 1) * 64 + tx * 4];
        f32x4 b2 = *(const f32x4*)&kvs[(d + 2) * 64 + tx * 4];
        f32x4 b3 = *(const f32x4*)&kvs[(d + 3) * 64 + tx * 4];
        #pragma unroll
        for (int i = 0; i < 4; ++i) {
            f32x4 av = *(const f32x4*)&qs[(ty * 4 + i) * 68 + d];
            sv[i] += av.x * b0 + av.y * b1 + av.z * b2 + av.w * b3;
        }
    }
    const size_t opanel = (size_t)b * 64 + bx;
    const int s_out = h * 2 + (tx >> 3);
    const int kq = (tx >> 1) & 3;
    const int rem8 = (tx & 1) * 8;
    #pragma unroll
    for (int i = 0; i < 4; ++i) {
        int t = ty * 4 + i;
        f32x4 o = sv[i] * z_s[t];
        _Float16 hh[4], ll[4];
        #pragma unroll
        for (int j = 0; j < 4; ++j) split1(o[j], hh[j], ll[j]);
        size_t cb = (((opanel * 32 + s_out) * 256 + ((t >> 4) * 4 + kq) * 16 + (t & 15)) << 4) + rem8;
        *(u32x2*)((char*)attn_hi + cb) = (u32x2){pack2(hh[0], hh[1]), pack2(hh[2], hh[3])};
        *(u32x2*)((char*)attn_lo + cb) = (u32x2){pack2(ll[0], ll[1]), pack2(ll[2], ll[3])};
    }
}

// ---------------------------------------------------------------------------
// Kernel 3: out = attn @ Wo^T + bo. T4 counted-vmcnt pipeline, 6 loads/stage.
// ---------------------------------------------------------------------------
__global__ __launch_bounds__(256, 3) void out_proj_kernel(
    const _Float16* __restrict__ attn_hi, const _Float16* __restrict__ attn_lo,
    const _Float16* __restrict__ wo_hi, const _Float16* __restrict__ wo_lo,
    const float* __restrict__ bo, float* __restrict__ out)
{
    const int tid = threadIdx.x;
    const int lane = tid & 63, wave = tid >> 6, quad = lane >> 4, l15 = lane & 15;
    const int n0 = blockIdx.x * 64;
    const size_t m0 = (size_t)blockIdx.y * 128;

    __shared__ __align__(16) char smem[49152];
    float* cs = (float*)smem;

    const size_t ap0 = (m0 >> 6) * 32, ap1 = ap0 + 32;
    const size_t bpn = (size_t)(n0 >> 6) * 32;

    auto stage = [&](int p, int s) {
        char* dst = smem + p * 24576 + tid * 16;
        const size_t co = (size_t)s * 2048 + tid * 8;
        gload16(&attn_hi[ap0 * 2048 + co], dst);
        gload16(&attn_hi[ap1 * 2048 + co], dst + 4096);
        gload16(&attn_lo[ap0 * 2048 + co], dst + 8192);
        gload16(&attn_lo[ap1 * 2048 + co], dst + 12288);
        gload16(&wo_hi[bpn * 2048 + co],  dst + 16384);
        gload16(&wo_lo[bpn * 2048 + co],  dst + 20480);
    };

    const int panel = wave >> 1;
    f32x4 acc_h[2][4] = {}, acc_c[2][4] = {};
    stage(0, 0);
    for (int s = 0; s < 32; ++s) {
        const int p = s & 1;
        if (s < 31) {
            stage(p ^ 1, s + 1);
            asm volatile("s_waitcnt vmcnt(6)" ::: "memory");
        } else {
            asm volatile("s_waitcnt vmcnt(0)" ::: "memory");
        }
        __builtin_amdgcn_s_barrier();
        __builtin_amdgcn_sched_barrier(0);
        const char* bufc = smem + p * 24576;
        f16x8 afh[2], afl[2], bfh[4], bfl[4];
        #pragma unroll
        for (int mt = 0; mt < 2; ++mt) {
            int rbl = (wave & 1) * 2 + mt;
            afh[mt] = *(const f16x8*)((const _Float16*)(bufc + panel * 4096) + rbl * 512 + lane * 8);
            afl[mt] = *(const f16x8*)((const _Float16*)(bufc + 8192 + panel * 4096) + rbl * 512 + lane * 8);
        }
        #pragma unroll
        for (int nt = 0; nt < 4; ++nt) {
            bfh[nt] = *(const f16x8*)((const _Float16*)(bufc + 16384) + nt * 512 + lane * 8);
            bfl[nt] = *(const f16x8*)((const _Float16*)(bufc + 20480) + nt * 512 + lane * 8);
        }
        #pragma unroll
        for (int mt = 0; mt < 2; ++mt)
            #pragma unroll
            for (int nt = 0; nt < 4; ++nt) {
                acc_h[mt][nt] = mfma_f16(afh[mt], bfh[nt], acc_h[mt][nt]);
                acc_c[mt][nt] = mfma_f16(afh[mt], bfl[nt], acc_c[mt][nt]);
                acc_c[mt][nt] = mfma_f16(afl[mt], bfh[nt], acc_c[mt][nt]);
            }
        __builtin_amdgcn_s_barrier();
        __builtin_amdgcn_sched_barrier(0);
    }

    {
        float bia[4];
        #pragma unroll
        for (int nt = 0; nt < 4; ++nt) bia[nt] = bo[n0 + nt * 16 + l15];
        #pragma unroll
        for (int mt = 0; mt < 2; ++mt)
            #pragma unroll
            for (int nt = 0; nt < 4; ++nt)
                #pragma unroll
                for (int r = 0; r < 4; ++r) {
                    int t = wave * 32 + mt * 16 + quad * 4 + r;
                    cs[t * 64 + nt * 16 + l15] =
                        acc_h[mt][nt][r] + INV_LOSCALE * acc_c[mt][nt][r] + bia[nt];
                }
    }
    __syncthreads();
    #pragma unroll
    for (int it = 0; it < 8; ++it) {
        int idx = it * 256 + tid;
        int r = idx >> 4, c = (idx & 15) * 4;
        *(f32x4*)&out[(m0 + r) * DM + n0 + c] = *(f32x4*)&cs[r * 64 + c];
    }
}

// ---------------------------------------------------------------------------
extern "C" void kernel_launch(void* const* d_in, const int* in_sizes, int n_in,
                              void* d_out, int out_size, void* d_ws, size_t ws_size,
                              hipStream_t stream) {
    const float* q  = (const float*)d_in[0];
    const float* kv = (const float*)d_in[1];
    const float* Wq = (const float*)d_in[2];
    const float* bq = (const float*)d_in[3];
    const float* Wk = (const float*)d_in[4];
    const float* bk = (const float*)d_in[5];
    const float* Wv = (const float*)d_in[6];
    const float* bv = (const float*)d_in[7];
    const float* Wo = (const float*)d_in[8];
    const float* bo = (const float*)d_in[9];
    float* out = (float*)d_out;

    // workspace carve-up: fixed ~85 MB; optional q-frag pair +64 MiB (gated).
    char* p = (char*)d_ws;
    float* kv_sum = (float*)p;              p += (size_t)BSZ * NH * HD * HD * 4;
    float* ksum   = (float*)p;              p += (size_t)BSZ * NH * HD * 4;
    _Float16* wqt_hi = (_Float16*)p;        p += (size_t)NH * HD * DM * 2;
    _Float16* wqt_lo = (_Float16*)p;        p += (size_t)NH * HD * DM * 2;
    _Float16* wkt_hi = (_Float16*)p;        p += (size_t)NH * HD * DM * 2;
    _Float16* wkt_lo = (_Float16*)p;        p += (size_t)NH * HD * DM * 2;
    _Float16* wvt_hi = (_Float16*)p;        p += (size_t)NH * HD * DM * 2;
    _Float16* wvt_lo = (_Float16*)p;        p += (size_t)NH * HD * DM * 2;
    _Float16* wo_hi  = (_Float16*)p;        p += (size_t)DM * DM * 2;
    _Float16* wo_lo  = (_Float16*)p;        p += (size_t)DM * DM * 2;
    _Float16* buf_hi = (_Float16*)p;        p += (size_t)BT * DM * 2;   // kv frags, then attn frags
    _Float16* buf_lo = (_Float16*)p;        p += (size_t)BT * DM * 2;
    _Float16* qf_hi  = (_Float16*)p;        p += (size_t)BT * DM * 2;   // optional q frags
    _Float16* qf_lo  = (_Float16*)p;        p += (size_t)BT * DM * 2;
    const bool big = ws_size >= (size_t)(p - (char*)d_ws);

    size_t zero_bytes = ((size_t)BSZ * NH * HD * HD + (size_t)BSZ * NH * HD) * sizeof(float);
    hipMemsetAsync(d_ws, 0, zero_bytes, stream);

    fragsplit_kernel<<<(BT * DM / 8) / 256, 256, 0, stream>>>(kv, buf_hi, buf_lo);
    wsplit_kernel<<<dim3(DM / 64, NH, 3), 256, 0, stream>>>(
        Wq, Wk, Wv, wqt_hi, wqt_lo, wkt_hi, wkt_lo, wvt_hi, wvt_lo);
    fragsplit_kernel<<<(DM * DM / 8) / 256, 256, 0, stream>>>(Wo, wo_hi, wo_lo);
    if (big)
        fragsplit_kernel<<<(BT * DM / 8) / 256, 256, 0, stream>>>(q, qf_hi, qf_lo);

    kv_stats_kernel<<<dim3(TSEQ / 256, NH, BSZ), 256, 0, stream>>>(
        buf_hi, buf_lo, wkt_hi, wkt_lo, wvt_hi, wvt_lo, bk, bv, kv_sum, ksum);
    if (big)
        q_attn_ps_kernel<<<dim3(TSEQ / 64, NH, BSZ), 256, 0, stream>>>(
            qf_hi, qf_lo, wqt_hi, wqt_lo, bq, kv_sum, ksum, buf_hi, buf_lo);
    else
        q_attn_kernel<<<dim3(TSEQ / 64, NH, BSZ), 256, 0, stream>>>(
            q, wqt_hi, wqt_lo, bq, kv_sum, ksum, buf_hi, buf_lo);
    out_proj_kernel<<<dim3(DM / 64, BT / 128), 256, 0, stream>>>(
        buf_hi, buf_lo, wo_hi, wo_lo, bo, out);
}

// Round 5
// 650.470 us; speedup vs baseline: 1.7901x; 1.1310x over previous
//
#include <hip/hip_runtime.h>

#define BSZ 4
#define TSEQ 4096
#define DM 1024
#define NH 16
#define HD 64
#define BT (BSZ * TSEQ)
#define INV_LOSCALE (1.0f / 4096.0f)

using f32x4 = __attribute__((ext_vector_type(4))) float;
using f16x8 = __attribute__((ext_vector_type(8))) _Float16;
using u32x2 = __attribute__((ext_vector_type(2))) unsigned;
using u32x4 = __attribute__((ext_vector_type(4))) unsigned;

typedef const __attribute__((address_space(1))) void* gas_ptr;
typedef __attribute__((address_space(3))) void* las_ptr;

// Async global->LDS, 16 B per lane. LDS dest = uniform base + lane*16.
__device__ __forceinline__ void gload16(const void* g, void* l) {
    __builtin_amdgcn_global_load_lds((gas_ptr)g, (las_ptr)l, 16, 0, 0);
}

// f16 RTN split: x = hi + lo/4096 + r. lo pre-scaled by 4096 (denormal immunity).
__device__ __forceinline__ void split1(float x, _Float16& h, _Float16& l) {
    h = (_Float16)x;
    l = (_Float16)((x - (float)h) * 4096.0f);
}
__device__ __forceinline__ unsigned pack2(_Float16 a, _Float16 b) {
    return (unsigned)__builtin_bit_cast(unsigned short, a) |
           ((unsigned)__builtin_bit_cast(unsigned short, b) << 16);
}
__device__ __forceinline__ f32x4 mfma_f16(f16x8 a, f16x8 b, f32x4 c) {
    return __builtin_amdgcn_mfma_f32_16x16x32_f16(a, b, c, 0, 0, 0);
}

// ---------------------------------------------------------------------------
// Fragment-linear layout: row-major [R][1024] fp32 -> per 64-row panel, per
// 32-k step, a 64x32 tile stored as 256 x 16B chunks ordered
// chunk = [rb(4)][kquad(4)][l15(16)] (lane i of a wave reads bytes i*16).
// ---------------------------------------------------------------------------
__global__ __launch_bounds__(256) void fragsplit_kernel(const float* __restrict__ in,
        _Float16* __restrict__ hi, _Float16* __restrict__ lo) {
    const int C = blockIdx.x * 256 + threadIdx.x;      // global chunk id
    const int l15 = C & 15, quad = (C >> 4) & 3, rb = (C >> 6) & 3;
    const int s = (C >> 8) & 31, panel = C >> 13;
    const size_t src = ((size_t)(panel * 64 + rb * 16 + l15)) * DM + s * 32 + quad * 8;
    f32x4 v0 = *(const f32x4*)&in[src];
    f32x4 v1 = *(const f32x4*)&in[src + 4];
    _Float16 h[8], l[8];
    #pragma unroll
    for (int j = 0; j < 4; ++j) { split1(v0[j], h[j], l[j]); split1(v1[j], h[4 + j], l[4 + j]); }
    ((u32x4*)hi)[C] = (u32x4){pack2(h[0],h[1]), pack2(h[2],h[3]), pack2(h[4],h[5]), pack2(h[6],h[7])};
    ((u32x4*)lo)[C] = (u32x4){pack2(l[0],l[1]), pack2(l[2],l[3]), pack2(l[4],l[5]), pack2(l[6],l[7])};
}

// ---------------------------------------------------------------------------
// Wq/Wk/Wv [h][k][n] -> transposed fragment-linear hi/lo f16 (panel = head).
// ---------------------------------------------------------------------------
__global__ __launch_bounds__(256) void wsplit_kernel(
    const float* __restrict__ Wq, const float* __restrict__ Wk, const float* __restrict__ Wv,
    _Float16* __restrict__ qh, _Float16* __restrict__ ql,
    _Float16* __restrict__ kh, _Float16* __restrict__ kl,
    _Float16* __restrict__ vh, _Float16* __restrict__ vl) {
    const int tid = threadIdx.x;
    const int k0 = blockIdx.x * 64, h = blockIdx.y, w = blockIdx.z;
    const float* __restrict__ W = (w == 0) ? Wq : (w == 1) ? Wk : Wv;
    _Float16* __restrict__ dh = (w == 0) ? qh : (w == 1) ? kh : vh;
    _Float16* __restrict__ dl = (w == 0) ? ql : (w == 1) ? kl : vl;
    __shared__ __align__(16) float ws_[64][68];
    #pragma unroll
    for (int it = 0; it < 4; ++it) {
        int idx = it * 256 + tid;
        int r = idx >> 4, c4 = (idx & 15) * 4;
        *(f32x4*)&ws_[r][c4] = *(const f32x4*)&W[((size_t)h * DM + k0 + r) * HD + c4];
    }
    __syncthreads();
    const int n = tid >> 2, kq16 = (tid & 3) * 16;
    _Float16 hh[16], ll[16];
    #pragma unroll
    for (int j = 0; j < 16; ++j) split1(ws_[kq16 + j][n], hh[j], ll[j]);
    #pragma unroll
    for (int c = 0; c < 2; ++c) {
        int kg = k0 + kq16 + c * 8;
        int s = kg >> 5, quad = (kg >> 3) & 3;
        size_t chunk = (size_t)(h * 32 + s) * 256 + ((n >> 4) * 4 + quad) * 16 + (n & 15);
        ((u32x4*)dh)[chunk] = (u32x4){pack2(hh[c*8+0],hh[c*8+1]), pack2(hh[c*8+2],hh[c*8+3]),
                                      pack2(hh[c*8+4],hh[c*8+5]), pack2(hh[c*8+6],hh[c*8+7])};
        ((u32x4*)dl)[chunk] = (u32x4){pack2(ll[c*8+0],ll[c*8+1]), pack2(ll[c*8+2],ll[c*8+3]),
                                      pack2(ll[c*8+4],ll[c*8+5]), pack2(ll[c*8+6],ll[c*8+7])};
    }
}

// ---------------------------------------------------------------------------
// Kernel 1: kh = (kv@Wk+bk)^2, vh = kv@Wv+bv via 3-term f16-split MFMA.
// M=128 k-step tiles (two fragment panels) halve the per-head weight
// re-read stream (16 KB weights now feed 128 rows instead of 64).
// T4 counted-vmcnt pipeline, 8 loads/step, steady vmcnt(8).
// 2 subs x 128 rows = 256 rows/block -> one atomic commit.
// ---------------------------------------------------------------------------
__global__ __launch_bounds__(256, 2) void kv_stats_kernel(
    const _Float16* __restrict__ kv_hi, const _Float16* __restrict__ kv_lo,
    const _Float16* __restrict__ wkt_hi, const _Float16* __restrict__ wkt_lo,
    const _Float16* __restrict__ wvt_hi, const _Float16* __restrict__ wvt_lo,
    const float* __restrict__ bk, const float* __restrict__ bv,
    float* __restrict__ kv_sum, float* __restrict__ ksum)
{
    const int tid = threadIdx.x;
    const int lane = tid & 63, wave = tid >> 6, quad = lane >> 4, l15 = lane & 15;
    const int b = blockIdx.z, h = blockIdx.y, bx = blockIdx.x;

    // dbuf staging: buffer p at p*32768; within: a_hi 0 (2 panels, 8K),
    // a_lo 8K, wk_hi 16K, wk_lo 20K, wv_hi 24K, wv_lo 28K.
    // Epilogue scratch khs/vhs (32K each) alias both buffers post-drain.
    __shared__ __align__(16) char smem[65536];
    float* khs = (float*)smem;
    float* vhs = (float*)(smem + 32768);

    const int isV = wave >> 1, half = wave & 1;
    const size_t btile = (size_t)h * 32;
    const int ty = tid >> 4, tx = tid & 15;

    f32x4 akv[4] = {};
    float aks[4] = {0.f, 0.f, 0.f, 0.f};

    for (int sub = 0; sub < 2; ++sub) {
        const size_t apan = (size_t)(b * 64 + bx * 4 + sub * 2);   // 2 panels/step
        auto stage = [&](int p, int s) {
            char* dst = smem + p * 32768 + tid * 16;
            const size_t a0 = (apan * 32 + s) * 2048 + tid * 8;
            const size_t a1 = ((apan + 1) * 32 + s) * 2048 + tid * 8;
            const size_t bo = (btile + s) * 2048 + tid * 8;
            gload16(&kv_hi[a0], dst);
            gload16(&kv_hi[a1], dst + 4096);
            gload16(&kv_lo[a0], dst + 8192);
            gload16(&kv_lo[a1], dst + 12288);
            gload16(&wkt_hi[bo], dst + 16384);
            gload16(&wkt_lo[bo], dst + 20480);
            gload16(&wvt_hi[bo], dst + 24576);
            gload16(&wvt_lo[bo], dst + 28672);
        };

        f32x4 acc_h[4][4] = {}, acc_c[4][4] = {};
        stage(0, 0);                                  // tile 0 in flight (8)
        for (int s = 0; s < 32; ++s) {
            const int p = s & 1;
            if (s < 31) {
                stage(p ^ 1, s + 1);                  // 16 outstanding
                asm volatile("s_waitcnt vmcnt(8)" ::: "memory");
            } else {
                asm volatile("s_waitcnt vmcnt(0)" ::: "memory");
            }
            __builtin_amdgcn_s_barrier();
            __builtin_amdgcn_sched_barrier(0);
            const char* bufc = smem + p * 32768;
            const _Float16* a_hi = (const _Float16*)bufc;
            const _Float16* a_lo = (const _Float16*)(bufc + 8192);
            const _Float16* bh = (const _Float16*)(bufc + (isV ? 24576 : 16384));
            const _Float16* bl = (const _Float16*)(bufc + (isV ? 28672 : 20480));
            f16x8 afh[4], afl[4], bfh[4], bfl[4];
            #pragma unroll
            for (int mt = 0; mt < 4; ++mt) {          // wave's 64 rows: half*64..
                afh[mt] = *(const f16x8*)&a_hi[half * 2048 + mt * 512 + lane * 8];
                afl[mt] = *(const f16x8*)&a_lo[half * 2048 + mt * 512 + lane * 8];
            }
            #pragma unroll
            for (int nt = 0; nt < 4; ++nt) {
                bfh[nt] = *(const f16x8*)&bh[nt * 512 + lane * 8];
                bfl[nt] = *(const f16x8*)&bl[nt * 512 + lane * 8];
            }
            #pragma unroll
            for (int mt = 0; mt < 4; ++mt)
                #pragma unroll
                for (int nt = 0; nt < 4; ++nt) {
                    acc_h[mt][nt] = mfma_f16(afh[mt], bfh[nt], acc_h[mt][nt]);
                    acc_c[mt][nt] = mfma_f16(afh[mt], bfl[nt], acc_c[mt][nt]);
                    acc_c[mt][nt] = mfma_f16(afl[mt], bfh[nt], acc_c[mt][nt]);
                }
            __builtin_amdgcn_s_barrier();
            __builtin_amdgcn_sched_barrier(0);
        }

        // epilogue: combine hi+lo/4096 + bias; square kh. 128x64 per side.
        {
            const float* __restrict__ bias = (isV ? bv : bk) + h * HD;
            float* __restrict__ outs = isV ? vhs : khs;
            float bia[4];
            #pragma unroll
            for (int nt = 0; nt < 4; ++nt) bia[nt] = bias[nt * 16 + l15];
            #pragma unroll
            for (int mt = 0; mt < 4; ++mt)
                #pragma unroll
                for (int nt = 0; nt < 4; ++nt)
                    #pragma unroll
                    for (int r = 0; r < 4; ++r) {
                        int t = half * 64 + mt * 16 + quad * 4 + r;
                        float v = acc_h[mt][nt][r] + INV_LOSCALE * acc_c[mt][nt][r] + bia[nt];
                        if (!isV) v = v * v;          // wave-uniform branch
                        outs[t * 64 + nt * 16 + l15] = v;
                    }
        }
        __syncthreads();

        #pragma unroll 4
        for (int t = 0; t < 128; ++t) {
            f32x4 kd = *(const f32x4*)&khs[t * 64 + ty * 4];
            f32x4 ve = *(const f32x4*)&vhs[t * 64 + tx * 4];
            #pragma unroll
            for (int i = 0; i < 4; ++i) {
                aks[i] += kd[i];
                akv[i] += kd[i] * ve;
            }
        }
        __syncthreads();
    }

    float* kvp = kv_sum + (size_t)(b * NH + h) * HD * HD;
    #pragma unroll
    for (int i = 0; i < 4; ++i)
        #pragma unroll
        for (int j = 0; j < 4; ++j)
            atomicAdd(&kvp[(ty * 4 + i) * HD + tx * 4 + j], akv[i][j]);
    if (tx == 0) {
        float* ksp = ksum + (b * NH + h) * HD;
        #pragma unroll
        for (int i = 0; i < 4; ++i) atomicAdd(&ksp[ty * 4 + i], aks[i]);
    }
}

// ---------------------------------------------------------------------------
// Kernel 2a (pre-split q path): qh = qf@Wq+bq, M=128 k-step tiles (halved
// weight stream + barrier count). 6 loads/step, steady vmcnt(6).
// ---------------------------------------------------------------------------
__global__ __launch_bounds__(256, 3) void q_attn_ps_kernel(
    const _Float16* __restrict__ qf_hi, const _Float16* __restrict__ qf_lo,
    const _Float16* __restrict__ wqt_hi, const _Float16* __restrict__ wqt_lo,
    const float* __restrict__ bq,
    const float* __restrict__ kv_sum, const float* __restrict__ ksum,
    _Float16* __restrict__ attn_hi, _Float16* __restrict__ attn_lo)
{
    const int tid = threadIdx.x;
    const int lane = tid & 63, wave = tid >> 6, quad = lane >> 4, l15 = lane & 15;
    const int b = blockIdx.z, h = blockIdx.y, bx = blockIdx.x;

    // dbuf staging: buffer p at p*24576: a_hi 0 (2 panels, 8K), a_lo 8K,
    // b_hi 16K, b_lo 20K. Post-loop union: qs [0,34816), kvs [34816,51200).
    __shared__ __align__(16) char smem[51200];
    __shared__ float z_s[128], ks_s[64];

    if (tid < 64) ks_s[tid] = ksum[(b * NH + h) * HD + tid];

    const size_t apan = (size_t)(b * 64 + bx * 2);
    const size_t btile = (size_t)h * 32;

    auto stage = [&](int p, int s) {
        char* dst = smem + p * 24576 + tid * 16;
        const size_t a0 = (apan * 32 + s) * 2048 + tid * 8;
        const size_t a1 = ((apan + 1) * 32 + s) * 2048 + tid * 8;
        const size_t bo = (btile + s) * 2048 + tid * 8;
        gload16(&qf_hi[a0], dst);
        gload16(&qf_hi[a1], dst + 4096);
        gload16(&qf_lo[a0], dst + 8192);
        gload16(&qf_lo[a1], dst + 12288);
        gload16(&wqt_hi[bo], dst + 16384);
        gload16(&wqt_lo[bo], dst + 20480);
    };

    f32x4 acc_h[2][4] = {}, acc_c[2][4] = {};
    stage(0, 0);                                      // 6 in flight
    for (int s = 0; s < 32; ++s) {
        const int p = s & 1;
        if (s < 31) {
            stage(p ^ 1, s + 1);                      // 12 outstanding
            asm volatile("s_waitcnt vmcnt(6)" ::: "memory");
        } else {
            asm volatile("s_waitcnt vmcnt(0)" ::: "memory");
        }
        __builtin_amdgcn_s_barrier();
        __builtin_amdgcn_sched_barrier(0);
        const char* bufc = smem + p * 24576;
        const _Float16* a_hi = (const _Float16*)bufc;
        const _Float16* a_lo = (const _Float16*)(bufc + 8192);
        f16x8 afh[2], afl[2], bfh[4], bfl[4];
        #pragma unroll
        for (int mt = 0; mt < 2; ++mt) {              // wave rows: wave*32 + mt*16
            int fo = (wave * 2 + mt) * 512 + lane * 8;
            afh[mt] = *(const f16x8*)&a_hi[fo];
            afl[mt] = *(const f16x8*)&a_lo[fo];
        }
        #pragma unroll
        for (int nt = 0; nt < 4; ++nt) {
            bfh[nt] = *(const f16x8*)((const _Float16*)(bufc + 16384) + nt * 512 + lane * 8);
            bfl[nt] = *(const f16x8*)((const _Float16*)(bufc + 20480) + nt * 512 + lane * 8);
        }
        #pragma unroll
        for (int mt = 0; mt < 2; ++mt)
            #pragma unroll
            for (int nt = 0; nt < 4; ++nt) {
                acc_h[mt][nt] = mfma_f16(afh[mt], bfh[nt], acc_h[mt][nt]);
                acc_c[mt][nt] = mfma_f16(afh[mt], bfl[nt], acc_c[mt][nt]);
                acc_c[mt][nt] = mfma_f16(afl[mt], bfh[nt], acc_c[mt][nt]);
            }
        __builtin_amdgcn_s_barrier();
        __builtin_amdgcn_sched_barrier(0);
    }

    // epilogue: qh2 -> qs (stride 68); z via shfl over the 16 n-lanes
    float* qs = (float*)smem;
    {
        const float* __restrict__ bias = bq + h * HD;
        float zp[2][4] = {};
        #pragma unroll
        for (int nt = 0; nt < 4; ++nt) {
            int d = nt * 16 + l15;
            float bia = bias[d];
            float ks  = ks_s[d];
            #pragma unroll
            for (int mt = 0; mt < 2; ++mt)
                #pragma unroll
                for (int r = 0; r < 4; ++r) {
                    int t = wave * 32 + mt * 16 + quad * 4 + r;
                    float v = acc_h[mt][nt][r] + INV_LOSCALE * acc_c[mt][nt][r] + bia;
                    float v2 = v * v;
                    qs[t * 68 + d] = v2;
                    zp[mt][r] = fmaf(v2, ks, zp[mt][r]);
                }
        }
        #pragma unroll
        for (int mt = 0; mt < 2; ++mt)
            #pragma unroll
            for (int r = 0; r < 4; ++r) {
                float p = zp[mt][r];
                p += __shfl_xor(p, 1);
                p += __shfl_xor(p, 2);
                p += __shfl_xor(p, 4);
                p += __shfl_xor(p, 8);
                if (l15 == 0) z_s[wave * 32 + mt * 16 + quad * 4 + r] = 1.f / (p + 1e-6f);
            }
    }
    __syncthreads();

    // reload kv_sum into LDS past qs
    float* kvs = (float*)(smem + 34816);
    {
        const float* __restrict__ kvp = kv_sum + (size_t)(b * NH + h) * HD * HD;
        #pragma unroll
        for (int it = 0; it < 4; ++it) {
            int idx = it * 256 + tid;
            int r = idx >> 4, c = (idx & 15) * 4;
            *(f32x4*)&kvs[r * 64 + c] = *(const f32x4*)&kvp[r * HD + c];
        }
    }
    __syncthreads();

    // mini-GEMM: sv[t][e] = sum_d qs[t][d]*kvs[d][e]; 8 rows/thread.
    const int ty = tid >> 4, tx = tid & 15;
    f32x4 sv[8] = {};
    #pragma unroll 4
    for (int d = 0; d < 64; d += 4) {
        f32x4 b0 = *(const f32x4*)&kvs[(d + 0) * 64 + tx * 4];
        f32x4 b1 = *(const f32x4*)&kvs[(d + 1) * 64 + tx * 4];
        f32x4 b2 = *(const f32x4*)&kvs[(d + 2) * 64 + tx * 4];
        f32x4 b3 = *(const f32x4*)&kvs[(d + 3) * 64 + tx * 4];
        #pragma unroll
        for (int i = 0; i < 8; ++i) {
            f32x4 av = *(const f32x4*)&qs[(ty * 8 + i) * 68 + d];
            sv[i] += av.x * b0 + av.y * b1 + av.z * b2 + av.w * b3;
        }
    }
    const int s_out = h * 2 + (tx >> 3);              // k-step of col h*64+tx*4
    const int kq = (tx >> 1) & 3;                     // k-quad within step
    const int rem8 = (tx & 1) * 8;                    // byte offset within chunk
    #pragma unroll
    for (int i = 0; i < 8; ++i) {
        int t = ty * 8 + i;
        const size_t opanel = (size_t)b * 64 + bx * 2 + (t >> 6);
        const int tt = t & 63;
        f32x4 o = sv[i] * z_s[t];
        _Float16 hh[4], ll[4];
        #pragma unroll
        for (int j = 0; j < 4; ++j) split1(o[j], hh[j], ll[j]);
        size_t cb = (((opanel * 32 + s_out) * 256 + ((tt >> 4) * 4 + kq) * 16 + (tt & 15)) << 4) + rem8;
        *(u32x2*)((char*)attn_hi + cb) = (u32x2){pack2(hh[0], hh[1]), pack2(hh[2], hh[3])};
        *(u32x2*)((char*)attn_lo + cb) = (u32x2){pack2(ll[0], ll[1]), pack2(ll[2], ll[3])};
    }
}

// ---------------------------------------------------------------------------
// Kernel 2b (fallback, ws too small): on-the-fly q split (R3 version).
// ---------------------------------------------------------------------------
__global__ __launch_bounds__(256, 3) void q_attn_kernel(
    const float* __restrict__ q,
    const _Float16* __restrict__ wqt_hi, const _Float16* __restrict__ wqt_lo,
    const float* __restrict__ bq,
    const float* __restrict__ kv_sum, const float* __restrict__ ksum,
    _Float16* __restrict__ attn_hi, _Float16* __restrict__ attn_lo)
{
    const int tid = threadIdx.x;
    const int lane = tid & 63, wave = tid >> 6, quad = lane >> 4, l15 = lane & 15;
    const int b = blockIdx.z, h = blockIdx.y, bx = blockIdx.x;
    const int t0 = bx * 64;

    __shared__ __align__(16) char smem[32768];
    __shared__ __align__(16) float qs[64 * 68];
    __shared__ float z_s[64], ks_s[64];

    if (tid < 64) ks_s[tid] = ksum[(b * NH + h) * HD + tid];

    const int arb = tid >> 6, aquad = (tid >> 4) & 3, al15 = tid & 15;
    const float* __restrict__ qrow =
        q + ((size_t)b * TSEQ + t0 + arb * 16 + al15) * DM + aquad * 8;
    const size_t btile = (size_t)h * 32;

    auto asplit_write = [&](int p, f32x4 v0, f32x4 v1) {
        _Float16 hh[8], ll[8];
        #pragma unroll
        for (int j = 0; j < 4; ++j) { split1(v0[j], hh[j], ll[j]); split1(v1[j], hh[4+j], ll[4+j]); }
        char* dst = smem + p * 16384 + tid * 16;
        *(u32x4*)dst =
            (u32x4){pack2(hh[0],hh[1]), pack2(hh[2],hh[3]), pack2(hh[4],hh[5]), pack2(hh[6],hh[7])};
        *(u32x4*)(dst + 4096) =
            (u32x4){pack2(ll[0],ll[1]), pack2(ll[2],ll[3]), pack2(ll[4],ll[5]), pack2(ll[6],ll[7])};
    };
    auto stageB = [&](int p, int s) {
        char* dst = smem + p * 16384 + 8192 + tid * 16;
        const size_t bo = (btile + s) * 2048 + tid * 8;
        gload16(&wqt_hi[bo], dst);
        gload16(&wqt_lo[bo], dst + 4096);
    };

    f32x4 acc_h[4] = {}, acc_c[4] = {};
    f32x4 v0 = *(const f32x4*)&qrow[0];
    f32x4 v1 = *(const f32x4*)&qrow[4];
    asplit_write(0, v0, v1);
    stageB(0, 0);
    v0 = *(const f32x4*)&qrow[32];
    v1 = *(const f32x4*)&qrow[36];
    asm volatile("s_waitcnt vmcnt(2) lgkmcnt(0)" ::: "memory");
    __builtin_amdgcn_s_barrier();
    __builtin_amdgcn_sched_barrier(0);

    for (int s = 0; s < 32; ++s) {
        const int p = s & 1;
        if (s < 31) {
            stageB(p ^ 1, s + 1);
            asplit_write(p ^ 1, v0, v1);
            if (s < 30) {
                v0 = *(const f32x4*)&qrow[(s + 2) * 32];
                v1 = *(const f32x4*)&qrow[(s + 2) * 32 + 4];
            }
            asm volatile("s_waitcnt vmcnt(4) lgkmcnt(0)" ::: "memory");
        } else {
            asm volatile("s_waitcnt vmcnt(0)" ::: "memory");
        }
        __builtin_amdgcn_s_barrier();
        __builtin_amdgcn_sched_barrier(0);
        const char* bufc = smem + p * 16384;
        f16x8 afh = *(const f16x8*)((const _Float16*)bufc + wave * 512 + lane * 8);
        f16x8 afl = *(const f16x8*)((const _Float16*)(bufc + 4096) + wave * 512 + lane * 8);
        f16x8 bfh[4], bfl[4];
        #pragma unroll
        for (int nt = 0; nt < 4; ++nt) {
            bfh[nt] = *(const f16x8*)((const _Float16*)(bufc + 8192) + nt * 512 + lane * 8);
            bfl[nt] = *(const f16x8*)((const _Float16*)(bufc + 12288) + nt * 512 + lane * 8);
        }
        #pragma unroll
        for (int nt = 0; nt < 4; ++nt) {
            acc_h[nt] = mfma_f16(afh, bfh[nt], acc_h[nt]);
            acc_c[nt] = mfma_f16(afh, bfl[nt], acc_c[nt]);
            acc_c[nt] = mfma_f16(afl, bfh[nt], acc_c[nt]);
        }
        __builtin_amdgcn_s_barrier();
        __builtin_amdgcn_sched_barrier(0);
    }

    {
        const int mrow0 = wave * 16;
        const float* __restrict__ bias = bq + h * HD;
        float zp[4] = {0.f, 0.f, 0.f, 0.f};
        #pragma unroll
        for (int nt = 0; nt < 4; ++nt) {
            int d = nt * 16 + l15;
            float bia = bias[d];
            float ks  = ks_s[d];
            #pragma unroll
            for (int r = 0; r < 4; ++r) {
                int t = mrow0 + quad * 4 + r;
                float v = acc_h[nt][r] + INV_LOSCALE * acc_c[nt][r] + bia;
                float v2 = v * v;
                qs[t * 68 + d] = v2;
                zp[r] = fmaf(v2, ks, zp[r]);
            }
        }
        #pragma unroll
        for (int r = 0; r < 4; ++r) {
            float p = zp[r];
            p += __shfl_xor(p, 1);
            p += __shfl_xor(p, 2);
            p += __shfl_xor(p, 4);
            p += __shfl_xor(p, 8);
            if (l15 == 0) z_s[mrow0 + quad * 4 + r] = 1.f / (p + 1e-6f);
        }
    }
    __syncthreads();

    float* kvs = (float*)smem;
    {
        const float* __restrict__ kvp = kv_sum + (size_t)(b * NH + h) * HD * HD;
        #pragma unroll
        for (int it = 0; it < 4; ++it) {
            int idx = it * 256 + tid;
            int r = idx >> 4, c = (idx & 15) * 4;
            *(f32x4*)&kvs[r * 64 + c] = *(const f32x4*)&kvp[r * HD + c];
        }
    }
    __syncthreads();

    const int ty = tid >> 4, tx = tid & 15;
    f32x4 sv[4] = {};
    #pragma unroll 4
    for (int d = 0; d < 64; d += 4) {
        f32x4 b0 = *(const f32x4*)&kvs[(d + 0) * 64 + tx * 4];
        f32x4 b1 = *(const f32x4*)&kvs[(d + 1) * 64 + tx * 4];
        f32x4 b2 = *(const f32x4*)&kvs[(d + 2) * 64 + tx * 4];
        f32x4 b3 = *(const f32x4*)&kvs[(d + 3) * 64 + tx * 4];
        #pragma unroll
        for (int i = 0; i < 4; ++i) {
            f32x4 av = *(const f32x4*)&qs[(ty * 4 + i) * 68 + d];
            sv[i] += av.x * b0 + av.y * b1 + av.z * b2 + av.w * b3;
        }
    }
    const size_t opanel = (size_t)b * 64 + bx;
    const int s_out = h * 2 + (tx >> 3);
    const int kq = (tx >> 1) & 3;
    const int rem8 = (tx & 1) * 8;
    #pragma unroll
    for (int i = 0; i < 4; ++i) {
        int t = ty * 4 + i;
        f32x4 o = sv[i] * z_s[t];
        _Float16 hh[4], ll[4];
        #pragma unroll
        for (int j = 0; j < 4; ++j) split1(o[j], hh[j], ll[j]);
        size_t cb = (((opanel * 32 + s_out) * 256 + ((t >> 4) * 4 + kq) * 16 + (t & 15)) << 4) + rem8;
        *(u32x2*)((char*)attn_hi + cb) = (u32x2){pack2(hh[0], hh[1]), pack2(hh[2], hh[3])};
        *(u32x2*)((char*)attn_lo + cb) = (u32x2){pack2(ll[0], ll[1]), pack2(ll[2], ll[3])};
    }
}

// ---------------------------------------------------------------------------
// Kernel 3: out = attn @ Wo^T + bo. T4 counted-vmcnt pipeline, 6 loads/stage.
// ---------------------------------------------------------------------------
__global__ __launch_bounds__(256, 3) void out_proj_kernel(
    const _Float16* __restrict__ attn_hi, const _Float16* __restrict__ attn_lo,
    const _Float16* __restrict__ wo_hi, const _Float16* __restrict__ wo_lo,
    const float* __restrict__ bo, float* __restrict__ out)
{
    const int tid = threadIdx.x;
    const int lane = tid & 63, wave = tid >> 6, quad = lane >> 4, l15 = lane & 15;
    const int n0 = blockIdx.x * 64;
    const size_t m0 = (size_t)blockIdx.y * 128;

    __shared__ __align__(16) char smem[49152];
    float* cs = (float*)smem;

    const size_t ap0 = (m0 >> 6) * 32, ap1 = ap0 + 32;
    const size_t bpn = (size_t)(n0 >> 6) * 32;

    auto stage = [&](int p, int s) {
        char* dst = smem + p * 24576 + tid * 16;
        const size_t co = (size_t)s * 2048 + tid * 8;
        gload16(&attn_hi[ap0 * 2048 + co], dst);
        gload16(&attn_hi[ap1 * 2048 + co], dst + 4096);
        gload16(&attn_lo[ap0 * 2048 + co], dst + 8192);
        gload16(&attn_lo[ap1 * 2048 + co], dst + 12288);
        gload16(&wo_hi[bpn * 2048 + co],  dst + 16384);
        gload16(&wo_lo[bpn * 2048 + co],  dst + 20480);
    };

    const int panel = wave >> 1;
    f32x4 acc_h[2][4] = {}, acc_c[2][4] = {};
    stage(0, 0);
    for (int s = 0; s < 32; ++s) {
        const int p = s & 1;
        if (s < 31) {
            stage(p ^ 1, s + 1);
            asm volatile("s_waitcnt vmcnt(6)" ::: "memory");
        } else {
            asm volatile("s_waitcnt vmcnt(0)" ::: "memory");
        }
        __builtin_amdgcn_s_barrier();
        __builtin_amdgcn_sched_barrier(0);
        const char* bufc = smem + p * 24576;
        f16x8 afh[2], afl[2], bfh[4], bfl[4];
        #pragma unroll
        for (int mt = 0; mt < 2; ++mt) {
            int rbl = (wave & 1) * 2 + mt;
            afh[mt] = *(const f16x8*)((const _Float16*)(bufc + panel * 4096) + rbl * 512 + lane * 8);
            afl[mt] = *(const f16x8*)((const _Float16*)(bufc + 8192 + panel * 4096) + rbl * 512 + lane * 8);
        }
        #pragma unroll
        for (int nt = 0; nt < 4; ++nt) {
            bfh[nt] = *(const f16x8*)((const _Float16*)(bufc + 16384) + nt * 512 + lane * 8);
            bfl[nt] = *(const f16x8*)((const _Float16*)(bufc + 20480) + nt * 512 + lane * 8);
        }
        #pragma unroll
        for (int mt = 0; mt < 2; ++mt)
            #pragma unroll
            for (int nt = 0; nt < 4; ++nt) {
                acc_h[mt][nt] = mfma_f16(afh[mt], bfh[nt], acc_h[mt][nt]);
                acc_c[mt][nt] = mfma_f16(afh[mt], bfl[nt], acc_c[mt][nt]);
                acc_c[mt][nt] = mfma_f16(afl[mt], bfh[nt], acc_c[mt][nt]);
            }
        __builtin_amdgcn_s_barrier();
        __builtin_amdgcn_sched_barrier(0);
    }

    {
        float bia[4];
        #pragma unroll
        for (int nt = 0; nt < 4; ++nt) bia[nt] = bo[n0 + nt * 16 + l15];
        #pragma unroll
        for (int mt = 0; mt < 2; ++mt)
            #pragma unroll
            for (int nt = 0; nt < 4; ++nt)
                #pragma unroll
                for (int r = 0; r < 4; ++r) {
                    int t = wave * 32 + mt * 16 + quad * 4 + r;
                    cs[t * 64 + nt * 16 + l15] =
                        acc_h[mt][nt][r] + INV_LOSCALE * acc_c[mt][nt][r] + bia[nt];
                }
    }
    __syncthreads();
    #pragma unroll
    for (int it = 0; it < 8; ++it) {
        int idx = it * 256 + tid;
        int r = idx >> 4, c = (idx & 15) * 4;
        *(f32x4*)&out[(m0 + r) * DM + n0 + c] = *(f32x4*)&cs[r * 64 + c];
    }
}

// ---------------------------------------------------------------------------
extern "C" void kernel_launch(void* const* d_in, const int* in_sizes, int n_in,
                              void* d_out, int out_size, void* d_ws, size_t ws_size,
                              hipStream_t stream) {
    const float* q  = (const float*)d_in[0];
    const float* kv = (const float*)d_in[1];
    const float* Wq = (const float*)d_in[2];
    const float* bq = (const float*)d_in[3];
    const float* Wk = (const float*)d_in[4];
    const float* bk = (const float*)d_in[5];
    const float* Wv = (const float*)d_in[6];
    const float* bv = (const float*)d_in[7];
    const float* Wo = (const float*)d_in[8];
    const float* bo = (const float*)d_in[9];
    float* out = (float*)d_out;

    // workspace carve-up: fixed ~85 MB; optional q-frag pair +64 MiB (gated).
    char* p = (char*)d_ws;
    float* kv_sum = (float*)p;              p += (size_t)BSZ * NH * HD * HD * 4;
    float* ksum   = (float*)p;              p += (size_t)BSZ * NH * HD * 4;
    _Float16* wqt_hi = (_Float16*)p;        p += (size_t)NH * HD * DM * 2;
    _Float16* wqt_lo = (_Float16*)p;        p += (size_t)NH * HD * DM * 2;
    _Float16* wkt_hi = (_Float16*)p;        p += (size_t)NH * HD * DM * 2;
    _Float16* wkt_lo = (_Float16*)p;        p += (size_t)NH * HD * DM * 2;
    _Float16* wvt_hi = (_Float16*)p;        p += (size_t)NH * HD * DM * 2;
    _Float16* wvt_lo = (_Float16*)p;        p += (size_t)NH * HD * DM * 2;
    _Float16* wo_hi  = (_Float16*)p;        p += (size_t)DM * DM * 2;
    _Float16* wo_lo  = (_Float16*)p;        p += (size_t)DM * DM * 2;
    _Float16* buf_hi = (_Float16*)p;        p += (size_t)BT * DM * 2;   // kv frags, then attn frags
    _Float16* buf_lo = (_Float16*)p;        p += (size_t)BT * DM * 2;
    _Float16* qf_hi  = (_Float16*)p;        p += (size_t)BT * DM * 2;   // optional q frags
    _Float16* qf_lo  = (_Float16*)p;        p += (size_t)BT * DM * 2;
    const bool big = ws_size >= (size_t)(p - (char*)d_ws);

    size_t zero_bytes = ((size_t)BSZ * NH * HD * HD + (size_t)BSZ * NH * HD) * sizeof(float);
    hipMemsetAsync(d_ws, 0, zero_bytes, stream);

    fragsplit_kernel<<<(BT * DM / 8) / 256, 256, 0, stream>>>(kv, buf_hi, buf_lo);
    wsplit_kernel<<<dim3(DM / 64, NH, 3), 256, 0, stream>>>(
        Wq, Wk, Wv, wqt_hi, wqt_lo, wkt_hi, wkt_lo, wvt_hi, wvt_lo);
    fragsplit_kernel<<<(DM * DM / 8) / 256, 256, 0, stream>>>(Wo, wo_hi, wo_lo);

    kv_stats_kernel<<<dim3(TSEQ / 256, NH, BSZ), 256, 0, stream>>>(
        buf_hi, buf_lo, wkt_hi, wkt_lo, wvt_hi, wvt_lo, bk, bv, kv_sum, ksum);

    if (big) {
        // q fragsplit AFTER kv_stats: keeps kv frags L3-resident during
        // kv_stats, and leaves qf L3-warm for q_attn_ps.
        fragsplit_kernel<<<(BT * DM / 8) / 256, 256, 0, stream>>>(q, qf_hi, qf_lo);
        q_attn_ps_kernel<<<dim3(TSEQ / 128, NH, BSZ), 256, 0, stream>>>(
            qf_hi, qf_lo, wqt_hi, wqt_lo, bq, kv_sum, ksum, buf_hi, buf_lo);
    } else {
        q_attn_kernel<<<dim3(TSEQ / 64, NH, BSZ), 256, 0, stream>>>(
            q, wqt_hi, wqt_lo, bq, kv_sum, ksum, buf_hi, buf_lo);
    }
    out_proj_kernel<<<dim3(DM / 64, BT / 128), 256, 0, stream>>>(
        buf_hi, buf_lo, wo_hi, wo_lo, bo, out);
}

// Round 6
// 625.988 us; speedup vs baseline: 1.8601x; 1.0391x over previous
//
#include <hip/hip_runtime.h>

#define BSZ 4
#define TSEQ 4096
#define DM 1024
#define NH 16
#define HD 64
#define BT (BSZ * TSEQ)
#define INV_LOSCALE (1.0f / 4096.0f)

using f32x4 = __attribute__((ext_vector_type(4))) float;
using f16x8 = __attribute__((ext_vector_type(8))) _Float16;
using u32x2 = __attribute__((ext_vector_type(2))) unsigned;
using u32x4 = __attribute__((ext_vector_type(4))) unsigned;

typedef const __attribute__((address_space(1))) void* gas_ptr;
typedef __attribute__((address_space(3))) void* las_ptr;

// Async global->LDS, 16 B per lane. LDS dest = uniform base + lane*16.
__device__ __forceinline__ void gload16(const void* g, void* l) {
    __builtin_amdgcn_global_load_lds((gas_ptr)g, (las_ptr)l, 16, 0, 0);
}

// f16 RTN split: x = hi + lo/4096 + r. lo pre-scaled by 4096 (denormal immunity).
__device__ __forceinline__ void split1(float x, _Float16& h, _Float16& l) {
    h = (_Float16)x;
    l = (_Float16)((x - (float)h) * 4096.0f);
}
__device__ __forceinline__ unsigned pack2(_Float16 a, _Float16 b) {
    return (unsigned)__builtin_bit_cast(unsigned short, a) |
           ((unsigned)__builtin_bit_cast(unsigned short, b) << 16);
}
__device__ __forceinline__ f32x4 mfma_f16(f16x8 a, f16x8 b, f32x4 c) {
    return __builtin_amdgcn_mfma_f32_16x16x32_f16(a, b, c, 0, 0, 0);
}

// ---------------------------------------------------------------------------
// Fragment-linear layout: row-major [R][1024] fp32 -> per 64-row panel, per
// 32-k step, a 64x32 tile stored as 256 x 16B chunks ordered
// chunk = [rb(4)][kquad(4)][l15(16)] (lane i of a wave reads bytes i*16).
// ---------------------------------------------------------------------------
__global__ __launch_bounds__(256) void fragsplit_kernel(const float* __restrict__ in,
        _Float16* __restrict__ hi, _Float16* __restrict__ lo) {
    const int C = blockIdx.x * 256 + threadIdx.x;      // global chunk id
    const int l15 = C & 15, quad = (C >> 4) & 3, rb = (C >> 6) & 3;
    const int s = (C >> 8) & 31, panel = C >> 13;
    const size_t src = ((size_t)(panel * 64 + rb * 16 + l15)) * DM + s * 32 + quad * 8;
    f32x4 v0 = *(const f32x4*)&in[src];
    f32x4 v1 = *(const f32x4*)&in[src + 4];
    _Float16 h[8], l[8];
    #pragma unroll
    for (int j = 0; j < 4; ++j) { split1(v0[j], h[j], l[j]); split1(v1[j], h[4 + j], l[4 + j]); }
    ((u32x4*)hi)[C] = (u32x4){pack2(h[0],h[1]), pack2(h[2],h[3]), pack2(h[4],h[5]), pack2(h[6],h[7])};
    ((u32x4*)lo)[C] = (u32x4){pack2(l[0],l[1]), pack2(l[2],l[3]), pack2(l[4],l[5]), pack2(l[6],l[7])};
}

// ---------------------------------------------------------------------------
// Wq/Wk/Wv [h][k][n] -> transposed fragment-linear hi/lo f16 (panel = head).
// ---------------------------------------------------------------------------
__global__ __launch_bounds__(256) void wsplit_kernel(
    const float* __restrict__ Wq, const float* __restrict__ Wk, const float* __restrict__ Wv,
    _Float16* __restrict__ qh, _Float16* __restrict__ ql,
    _Float16* __restrict__ kh, _Float16* __restrict__ kl,
    _Float16* __restrict__ vh, _Float16* __restrict__ vl) {
    const int tid = threadIdx.x;
    const int k0 = blockIdx.x * 64, h = blockIdx.y, w = blockIdx.z;
    const float* __restrict__ W = (w == 0) ? Wq : (w == 1) ? Wk : Wv;
    _Float16* __restrict__ dh = (w == 0) ? qh : (w == 1) ? kh : vh;
    _Float16* __restrict__ dl = (w == 0) ? ql : (w == 1) ? kl : vl;
    __shared__ __align__(16) float ws_[64][68];
    #pragma unroll
    for (int it = 0; it < 4; ++it) {
        int idx = it * 256 + tid;
        int r = idx >> 4, c4 = (idx & 15) * 4;
        *(f32x4*)&ws_[r][c4] = *(const f32x4*)&W[((size_t)h * DM + k0 + r) * HD + c4];
    }
    __syncthreads();
    const int n = tid >> 2, kq16 = (tid & 3) * 16;
    _Float16 hh[16], ll[16];
    #pragma unroll
    for (int j = 0; j < 16; ++j) split1(ws_[kq16 + j][n], hh[j], ll[j]);
    #pragma unroll
    for (int c = 0; c < 2; ++c) {
        int kg = k0 + kq16 + c * 8;
        int s = kg >> 5, quad = (kg >> 3) & 3;
        size_t chunk = (size_t)(h * 32 + s) * 256 + ((n >> 4) * 4 + quad) * 16 + (n & 15);
        ((u32x4*)dh)[chunk] = (u32x4){pack2(hh[c*8+0],hh[c*8+1]), pack2(hh[c*8+2],hh[c*8+3]),
                                      pack2(hh[c*8+4],hh[c*8+5]), pack2(hh[c*8+6],hh[c*8+7])};
        ((u32x4*)dl)[chunk] = (u32x4){pack2(ll[c*8+0],ll[c*8+1]), pack2(ll[c*8+2],ll[c*8+3]),
                                      pack2(ll[c*8+4],ll[c*8+5]), pack2(ll[c*8+6],ll[c*8+7])};
    }
}

// ---------------------------------------------------------------------------
// Kernel 1: kh2 = (kv@Wk+bk)^2, vh = kv@Wv+bv via 3-term f16-split MFMA.
// M=128 k-step tiles; T4 counted-vmcnt pipeline (8 loads/step, vmcnt(8)).
// NEW: the rank-T reduction kv_sum = kh2^T @ vh is itself done by MFMA:
// the combine step stores kh2/vh TRANSPOSED as f16 hi/lo fragments in LDS
// (t becomes the k-dim), then a 4-kstep MFMA pass accumulates kv_sum and
// ksum (B = ones) into persistent accumulators across the 2 subs.
// ---------------------------------------------------------------------------
__global__ __launch_bounds__(256, 2) void kv_stats_kernel(
    const _Float16* __restrict__ kv_hi, const _Float16* __restrict__ kv_lo,
    const _Float16* __restrict__ wkt_hi, const _Float16* __restrict__ wkt_lo,
    const _Float16* __restrict__ wvt_hi, const _Float16* __restrict__ wvt_lo,
    const float* __restrict__ bk, const float* __restrict__ bv,
    float* __restrict__ kv_sum, float* __restrict__ ksum)
{
    const int tid = threadIdx.x;
    const int lane = tid & 63, wave = tid >> 6, quad = lane >> 4, l15 = lane & 15;
    const int b = blockIdx.z, h = blockIdx.y, bx = blockIdx.x;

    // staging: buffer p at p*32768 (a_hi 0/8K=2 panels, a_lo 8K, wk 16K/20K,
    // wv 24K/28K). Post-drain alias: kh2T_hi @0, kh2T_lo @16K, vhT_hi @32K,
    // vhT_lo @48K (each 4 ksteps x 4KB fragment-linear [feat][t] tiles).
    __shared__ __align__(16) char smem[65536];
    _Float16* khT_h = (_Float16*)smem;
    _Float16* khT_l = (_Float16*)(smem + 16384);
    _Float16* vhT_h = (_Float16*)(smem + 32768);
    _Float16* vhT_l = (_Float16*)(smem + 49152);

    const int isV = wave >> 1, half = wave & 1;
    const size_t btile = (size_t)h * 32;

    // persistent reduction accumulators (accumulate across both subs)
    f32x4 racc_h[4] = {}, racc_c[4] = {};
    f32x4 rk_h = {}, rk_c = {};
    const f16x8 ones = __builtin_bit_cast(f16x8,
        (u32x4){0x3C003C00u, 0x3C003C00u, 0x3C003C00u, 0x3C003C00u});

    for (int sub = 0; sub < 2; ++sub) {
        const size_t apan = (size_t)(b * 64 + bx * 4 + sub * 2);   // 2 panels/step
        auto stage = [&](int p, int s) {
            char* dst = smem + p * 32768 + tid * 16;
            const size_t a0 = (apan * 32 + s) * 2048 + tid * 8;
            const size_t a1 = ((apan + 1) * 32 + s) * 2048 + tid * 8;
            const size_t bo = (btile + s) * 2048 + tid * 8;
            gload16(&kv_hi[a0], dst);
            gload16(&kv_hi[a1], dst + 4096);
            gload16(&kv_lo[a0], dst + 8192);
            gload16(&kv_lo[a1], dst + 12288);
            gload16(&wkt_hi[bo], dst + 16384);
            gload16(&wkt_lo[bo], dst + 20480);
            gload16(&wvt_hi[bo], dst + 24576);
            gload16(&wvt_lo[bo], dst + 28672);
        };

        f32x4 acc_h[4][4] = {}, acc_c[4][4] = {};
        stage(0, 0);                                  // tile 0 in flight (8)
        for (int s = 0; s < 32; ++s) {
            const int p = s & 1;
            if (s < 31) {
                stage(p ^ 1, s + 1);                  // 16 outstanding
                asm volatile("s_waitcnt vmcnt(8)" ::: "memory");
            } else {
                asm volatile("s_waitcnt vmcnt(0)" ::: "memory");
            }
            __builtin_amdgcn_s_barrier();
            __builtin_amdgcn_sched_barrier(0);
            const char* bufc = smem + p * 32768;
            const _Float16* a_hi = (const _Float16*)bufc;
            const _Float16* a_lo = (const _Float16*)(bufc + 8192);
            const _Float16* bh = (const _Float16*)(bufc + (isV ? 24576 : 16384));
            const _Float16* bl = (const _Float16*)(bufc + (isV ? 28672 : 20480));
            f16x8 afh[4], afl[4], bfh[4], bfl[4];
            #pragma unroll
            for (int mt = 0; mt < 4; ++mt) {          // wave's 64 rows: half*64..
                afh[mt] = *(const f16x8*)&a_hi[half * 2048 + mt * 512 + lane * 8];
                afl[mt] = *(const f16x8*)&a_lo[half * 2048 + mt * 512 + lane * 8];
            }
            #pragma unroll
            for (int nt = 0; nt < 4; ++nt) {
                bfh[nt] = *(const f16x8*)&bh[nt * 512 + lane * 8];
                bfl[nt] = *(const f16x8*)&bl[nt * 512 + lane * 8];
            }
            #pragma unroll
            for (int mt = 0; mt < 4; ++mt)
                #pragma unroll
                for (int nt = 0; nt < 4; ++nt) {
                    acc_h[mt][nt] = mfma_f16(afh[mt], bfh[nt], acc_h[mt][nt]);
                    acc_c[mt][nt] = mfma_f16(afh[mt], bfl[nt], acc_c[mt][nt]);
                    acc_c[mt][nt] = mfma_f16(afl[mt], bfh[nt], acc_c[mt][nt]);
                }
            __builtin_amdgcn_s_barrier();
            __builtin_amdgcn_sched_barrier(0);
        }

        // combine (+bias, square for K) and TRANSPOSED split-store:
        // value (t_local = half*64+mt*16+quad*4+r, d = nt*16+l15) goes to
        // fragment position [d-row][t-k]: 4 consecutive r = one b64 write.
        {
            const float* __restrict__ bias = (isV ? bv : bk) + h * HD;
            _Float16* __restrict__ dh = isV ? vhT_h : khT_h;
            _Float16* __restrict__ dl = isV ? vhT_l : khT_l;
            float bia[4];
            #pragma unroll
            for (int nt = 0; nt < 4; ++nt) bia[nt] = bias[nt * 16 + l15];
            #pragma unroll
            for (int mt = 0; mt < 4; ++mt) {
                const int S = half * 2 + (mt >> 1);
                const int tq = (mt & 1) * 2 + (quad >> 1);
                const int eo = (quad & 1) * 4;
                #pragma unroll
                for (int nt = 0; nt < 4; ++nt) {
                    _Float16 hh[4], ll[4];
                    #pragma unroll
                    for (int r = 0; r < 4; ++r) {
                        float v = acc_h[mt][nt][r] + INV_LOSCALE * acc_c[mt][nt][r] + bia[nt];
                        if (!isV) v = v * v;          // wave-uniform branch
                        split1(v, hh[r], ll[r]);
                    }
                    int fo = S * 2048 + (nt * 4 + tq) * 128 + l15 * 8 + eo;
                    *(u32x2*)&dh[fo] = (u32x2){pack2(hh[0], hh[1]), pack2(hh[2], hh[3])};
                    *(u32x2*)&dl[fo] = (u32x2){pack2(ll[0], ll[1]), pack2(ll[2], ll[3])};
                }
            }
        }
        __syncthreads();

        // MFMA reduction: kv_sum[d][e] += sum_t kh2[t][d]*vh[t][e], K=128.
        // Wave w owns d-rowblock w; ksum via B = ones.
        #pragma unroll
        for (int S = 0; S < 4; ++S) {
            f16x8 ah = *(const f16x8*)&khT_h[S * 2048 + wave * 512 + lane * 8];
            f16x8 al = *(const f16x8*)&khT_l[S * 2048 + wave * 512 + lane * 8];
            rk_h = mfma_f16(ah, ones, rk_h);
            rk_c = mfma_f16(al, ones, rk_c);
            #pragma unroll
            for (int nt = 0; nt < 4; ++nt) {
                f16x8 bh = *(const f16x8*)&vhT_h[S * 2048 + nt * 512 + lane * 8];
                f16x8 bl = *(const f16x8*)&vhT_l[S * 2048 + nt * 512 + lane * 8];
                racc_h[nt] = mfma_f16(ah, bh, racc_h[nt]);
                racc_c[nt] = mfma_f16(ah, bl, racc_c[nt]);
                racc_c[nt] = mfma_f16(al, bh, racc_c[nt]);
            }
        }
        __syncthreads();                              // reads done before next staging
    }

    // commit: D layout col=l15(e), row=quad*4+r; d = wave*16+quad*4+r.
    float* kvp = kv_sum + (size_t)(b * NH + h) * HD * HD;
    #pragma unroll
    for (int nt = 0; nt < 4; ++nt)
        #pragma unroll
        for (int r = 0; r < 4; ++r)
            atomicAdd(&kvp[(wave * 16 + quad * 4 + r) * HD + nt * 16 + l15],
                      racc_h[nt][r] + INV_LOSCALE * racc_c[nt][r]);
    if (l15 == 0) {
        float* ksp = ksum + (b * NH + h) * HD;
        #pragma unroll
        for (int r = 0; r < 4; ++r)
            atomicAdd(&ksp[wave * 16 + quad * 4 + r], rk_h[r] + INV_LOSCALE * rk_c[r]);
    }
}

// ---------------------------------------------------------------------------
// P-fusion precompute: Pt[b][o][(h,d)] = (1/4096) * sum_e kv_sum[b,h][d][e]
// * Wo[o][h*64+e], written fragment-linear f16 hi/lo (B-operand of out GEMM).
// Folds the qh2@kv_sum mini-GEMM into the out projection algebraically.
// ---------------------------------------------------------------------------
__global__ __launch_bounds__(256) void pmat_kernel(
    const float* __restrict__ kv_sum, const float* __restrict__ Wo,
    _Float16* __restrict__ pt_hi, _Float16* __restrict__ pt_lo)
{
    const int tid = threadIdx.x;
    const int opan = blockIdx.x, h = blockIdx.y, b = blockIdx.z;
    __shared__ __align__(16) float kvsT[64][68];      // [e][d]
    __shared__ __align__(16) float wos[64][68];       // [o-local][e]
    const float* __restrict__ kvp = kv_sum + (size_t)(b * NH + h) * HD * HD;
    #pragma unroll
    for (int it = 0; it < 4; ++it) {
        int idx = it * 256 + tid;
        int d = idx >> 4, e4 = (idx & 15) * 4;
        f32x4 v = *(const f32x4*)&kvp[d * HD + e4];
        kvsT[e4 + 0][d] = v.x; kvsT[e4 + 1][d] = v.y;
        kvsT[e4 + 2][d] = v.z; kvsT[e4 + 3][d] = v.w;
        int o = idx >> 4;
        *(f32x4*)&wos[o][e4] = *(const f32x4*)&Wo[(size_t)(opan * 64 + o) * DM + h * HD + e4];
    }
    __syncthreads();
    const int ty = tid >> 4, tx = tid & 15;           // o-rows ty*4.., d-cols tx*4..
    f32x4 sv[4] = {};
    #pragma unroll 8
    for (int e = 0; e < 64; ++e) {
        f32x4 kv4 = *(const f32x4*)&kvsT[e][tx * 4];
        #pragma unroll
        for (int i = 0; i < 4; ++i) sv[i] += wos[ty * 4 + i][e] * kv4;
    }
    const int d0 = tx * 4;
    const int S = h * 2 + (d0 >> 5);
    const int kq = (d0 >> 3) & 3;
    const int rem8 = (d0 & 4) ? 8 : 0;
    #pragma unroll
    for (int i = 0; i < 4; ++i) {
        int ol = ty * 4 + i;
        f32x4 o4 = sv[i] * INV_LOSCALE;               // exact 2^-12 scale
        _Float16 hh[4], ll[4];
        #pragma unroll
        for (int j = 0; j < 4; ++j) split1(o4[j], hh[j], ll[j]);
        size_t cb = ((((size_t)(b * 16 + opan) * 32 + S) * 256 +
                      ((ol >> 4) * 4 + kq) * 16 + (ol & 15)) << 4) + rem8;
        *(u32x2*)((char*)pt_hi + cb) = (u32x2){pack2(hh[0], hh[1]), pack2(hh[2], hh[3])};
        *(u32x2*)((char*)pt_lo + cb) = (u32x2){pack2(ll[0], ll[1]), pack2(ll[2], ll[3])};
    }
}

// ---------------------------------------------------------------------------
// Kernel 2a (pre-split q path): qh = qf@Wq+bq, M=128 tiles, 6 loads/step.
// NEW epilogue: z' = 4096*z; writes qz = z'*qh2 as fragment-linear f16
// split (coalesced chunk writes from qs LDS). No mini-GEMM, no kv_sum.
// ---------------------------------------------------------------------------
__global__ __launch_bounds__(256, 3) void q_attn_ps_kernel(
    const _Float16* __restrict__ qf_hi, const _Float16* __restrict__ qf_lo,
    const _Float16* __restrict__ wqt_hi, const _Float16* __restrict__ wqt_lo,
    const float* __restrict__ bq, const float* __restrict__ ksum,
    _Float16* __restrict__ attn_hi, _Float16* __restrict__ attn_lo)
{
    const int tid = threadIdx.x;
    const int lane = tid & 63, wave = tid >> 6, quad = lane >> 4, l15 = lane & 15;
    const int b = blockIdx.z, h = blockIdx.y, bx = blockIdx.x;

    // staging: buffer p at p*24576 (a_hi 0/8K, a_lo 8K, b_hi 16K, b_lo 20K);
    // epilogue alias: qs fp32 [128][68] over [0, 34816).
    __shared__ __align__(16) char smem[49152];
    __shared__ float z_s[128], ks_s[64];

    if (tid < 64) ks_s[tid] = ksum[(b * NH + h) * HD + tid];

    const size_t apan = (size_t)(b * 64 + bx * 2);
    const size_t btile = (size_t)h * 32;

    auto stage = [&](int p, int s) {
        char* dst = smem + p * 24576 + tid * 16;
        const size_t a0 = (apan * 32 + s) * 2048 + tid * 8;
        const size_t a1 = ((apan + 1) * 32 + s) * 2048 + tid * 8;
        const size_t bo = (btile + s) * 2048 + tid * 8;
        gload16(&qf_hi[a0], dst);
        gload16(&qf_hi[a1], dst + 4096);
        gload16(&qf_lo[a0], dst + 8192);
        gload16(&qf_lo[a1], dst + 12288);
        gload16(&wqt_hi[bo], dst + 16384);
        gload16(&wqt_lo[bo], dst + 20480);
    };

    f32x4 acc_h[2][4] = {}, acc_c[2][4] = {};
    stage(0, 0);
    for (int s = 0; s < 32; ++s) {
        const int p = s & 1;
        if (s < 31) {
            stage(p ^ 1, s + 1);
            asm volatile("s_waitcnt vmcnt(6)" ::: "memory");
        } else {
            asm volatile("s_waitcnt vmcnt(0)" ::: "memory");
        }
        __builtin_amdgcn_s_barrier();
        __builtin_amdgcn_sched_barrier(0);
        const char* bufc = smem + p * 24576;
        const _Float16* a_hi = (const _Float16*)bufc;
        const _Float16* a_lo = (const _Float16*)(bufc + 8192);
        f16x8 afh[2], afl[2], bfh[4], bfl[4];
        #pragma unroll
        for (int mt = 0; mt < 2; ++mt) {
            int fo = (wave * 2 + mt) * 512 + lane * 8;
            afh[mt] = *(const f16x8*)&a_hi[fo];
            afl[mt] = *(const f16x8*)&a_lo[fo];
        }
        #pragma unroll
        for (int nt = 0; nt < 4; ++nt) {
            bfh[nt] = *(const f16x8*)((const _Float16*)(bufc + 16384) + nt * 512 + lane * 8);
            bfl[nt] = *(const f16x8*)((const _Float16*)(bufc + 20480) + nt * 512 + lane * 8);
        }
        #pragma unroll
        for (int mt = 0; mt < 2; ++mt)
            #pragma unroll
            for (int nt = 0; nt < 4; ++nt) {
                acc_h[mt][nt] = mfma_f16(afh[mt], bfh[nt], acc_h[mt][nt]);
                acc_c[mt][nt] = mfma_f16(afh[mt], bfl[nt], acc_c[mt][nt]);
                acc_c[mt][nt] = mfma_f16(afl[mt], bfh[nt], acc_c[mt][nt]);
            }
        __builtin_amdgcn_s_barrier();
        __builtin_amdgcn_sched_barrier(0);
    }

    // epilogue: qh2 -> qs; z' = 4096*z via shfl over the 16 n-lanes
    float* qs = (float*)smem;
    {
        const float* __restrict__ bias = bq + h * HD;
        float zp[2][4] = {};
        #pragma unroll
        for (int nt = 0; nt < 4; ++nt) {
            int d = nt * 16 + l15;
            float bia = bias[d];
            float ks  = ks_s[d];
            #pragma unroll
            for (int mt = 0; mt < 2; ++mt)
                #pragma unroll
                for (int r = 0; r < 4; ++r) {
                    int t = wave * 32 + mt * 16 + quad * 4 + r;
                    float v = acc_h[mt][nt][r] + INV_LOSCALE * acc_c[mt][nt][r] + bia;
                    float v2 = v * v;
                    qs[t * 68 + d] = v2;
                    zp[mt][r] = fmaf(v2, ks, zp[mt][r]);
                }
        }
        #pragma unroll
        for (int mt = 0; mt < 2; ++mt)
            #pragma unroll
            for (int r = 0; r < 4; ++r) {
                float p = zp[mt][r];
                p += __shfl_xor(p, 1);
                p += __shfl_xor(p, 2);
                p += __shfl_xor(p, 4);
                p += __shfl_xor(p, 8);
                if (l15 == 0) z_s[wave * 32 + mt * 16 + quad * 4 + r] = 4096.0f / (p + 1e-6f);
            }
    }
    __syncthreads();

    // qz chunk-split writes: 1024 chunks (2 panels x 2 ksteps x 256), each
    // chunk = 8 consecutive d of one t row -> 2 f32x4 LDS reads + u32x4 store.
    #pragma unroll
    for (int it = 0; it < 4; ++it) {
        int cid = it * 256 + tid;
        int lp = cid >> 9, Sl = (cid >> 8) & 1, c = cid & 255;
        int t = lp * 64 + (c >> 6) * 16 + (c & 15);
        int d = Sl * 32 + ((c >> 4) & 3) * 8;
        f32x4 a0 = *(const f32x4*)&qs[t * 68 + d];
        f32x4 a1 = *(const f32x4*)&qs[t * 68 + d + 4];
        float z = z_s[t];
        _Float16 hh[8], ll[8];
        #pragma unroll
        for (int j = 0; j < 4; ++j) {
            split1(z * a0[j], hh[j], ll[j]);
            split1(z * a1[j], hh[4 + j], ll[4 + j]);
        }
        size_t cb = (((size_t)(b * 64 + bx * 2 + lp) * 32 + h * 2 + Sl) * 256 + c) << 4;
        *(u32x4*)((char*)attn_hi + cb) =
            (u32x4){pack2(hh[0],hh[1]), pack2(hh[2],hh[3]), pack2(hh[4],hh[5]), pack2(hh[6],hh[7])};
        *(u32x4*)((char*)attn_lo + cb) =
            (u32x4){pack2(ll[0],ll[1]), pack2(ll[2],ll[3]), pack2(ll[4],ll[5]), pack2(ll[6],ll[7])};
    }
}

// ---------------------------------------------------------------------------
// Kernel 2b (fallback, ws too small): on-the-fly q split (R3 version).
// ---------------------------------------------------------------------------
__global__ __launch_bounds__(256, 3) void q_attn_kernel(
    const float* __restrict__ q,
    const _Float16* __restrict__ wqt_hi, const _Float16* __restrict__ wqt_lo,
    const float* __restrict__ bq,
    const float* __restrict__ kv_sum, const float* __restrict__ ksum,
    _Float16* __restrict__ attn_hi, _Float16* __restrict__ attn_lo)
{
    const int tid = threadIdx.x;
    const int lane = tid & 63, wave = tid >> 6, quad = lane >> 4, l15 = lane & 15;
    const int b = blockIdx.z, h = blockIdx.y, bx = blockIdx.x;
    const int t0 = bx * 64;

    __shared__ __align__(16) char smem[32768];
    __shared__ __align__(16) float qs[64 * 68];
    __shared__ float z_s[64], ks_s[64];

    if (tid < 64) ks_s[tid] = ksum[(b * NH + h) * HD + tid];

    const int arb = tid >> 6, aquad = (tid >> 4) & 3, al15 = tid & 15;
    const float* __restrict__ qrow =
        q + ((size_t)b * TSEQ + t0 + arb * 16 + al15) * DM + aquad * 8;
    const size_t btile = (size_t)h * 32;

    auto asplit_write = [&](int p, f32x4 v0, f32x4 v1) {
        _Float16 hh[8], ll[8];
        #pragma unroll
        for (int j = 0; j < 4; ++j) { split1(v0[j], hh[j], ll[j]); split1(v1[j], hh[4+j], ll[4+j]); }
        char* dst = smem + p * 16384 + tid * 16;
        *(u32x4*)dst =
            (u32x4){pack2(hh[0],hh[1]), pack2(hh[2],hh[3]), pack2(hh[4],hh[5]), pack2(hh[6],hh[7])};
        *(u32x4*)(dst + 4096) =
            (u32x4){pack2(ll[0],ll[1]), pack2(ll[2],ll[3]), pack2(ll[4],ll[5]), pack2(ll[6],ll[7])};
    };
    auto stageB = [&](int p, int s) {
        char* dst = smem + p * 16384 + 8192 + tid * 16;
        const size_t bo = (btile + s) * 2048 + tid * 8;
        gload16(&wqt_hi[bo], dst);
        gload16(&wqt_lo[bo], dst + 4096);
    };

    f32x4 acc_h[4] = {}, acc_c[4] = {};
    f32x4 v0 = *(const f32x4*)&qrow[0];
    f32x4 v1 = *(const f32x4*)&qrow[4];
    asplit_write(0, v0, v1);
    stageB(0, 0);
    v0 = *(const f32x4*)&qrow[32];
    v1 = *(const f32x4*)&qrow[36];
    asm volatile("s_waitcnt vmcnt(2) lgkmcnt(0)" ::: "memory");
    __builtin_amdgcn_s_barrier();
    __builtin_amdgcn_sched_barrier(0);

    for (int s = 0; s < 32; ++s) {
        const int p = s & 1;
        if (s < 31) {
            stageB(p ^ 1, s + 1);
            asplit_write(p ^ 1, v0, v1);
            if (s < 30) {
                v0 = *(const f32x4*)&qrow[(s + 2) * 32];
                v1 = *(const f32x4*)&qrow[(s + 2) * 32 + 4];
            }
            asm volatile("s_waitcnt vmcnt(4) lgkmcnt(0)" ::: "memory");
        } else {
            asm volatile("s_waitcnt vmcnt(0)" ::: "memory");
        }
        __builtin_amdgcn_s_barrier();
        __builtin_amdgcn_sched_barrier(0);
        const char* bufc = smem + p * 16384;
        f16x8 afh = *(const f16x8*)((const _Float16*)bufc + wave * 512 + lane * 8);
        f16x8 afl = *(const f16x8*)((const _Float16*)(bufc + 4096) + wave * 512 + lane * 8);
        f16x8 bfh[4], bfl[4];
        #pragma unroll
        for (int nt = 0; nt < 4; ++nt) {
            bfh[nt] = *(const f16x8*)((const _Float16*)(bufc + 8192) + nt * 512 + lane * 8);
            bfl[nt] = *(const f16x8*)((const _Float16*)(bufc + 12288) + nt * 512 + lane * 8);
        }
        #pragma unroll
        for (int nt = 0; nt < 4; ++nt) {
            acc_h[nt] = mfma_f16(afh, bfh[nt], acc_h[nt]);
            acc_c[nt] = mfma_f16(afh, bfl[nt], acc_c[nt]);
            acc_c[nt] = mfma_f16(afl, bfh[nt], acc_c[nt]);
        }
        __builtin_amdgcn_s_barrier();
        __builtin_amdgcn_sched_barrier(0);
    }

    {
        const int mrow0 = wave * 16;
        const float* __restrict__ bias = bq + h * HD;
        float zp[4] = {0.f, 0.f, 0.f, 0.f};
        #pragma unroll
        for (int nt = 0; nt < 4; ++nt) {
            int d = nt * 16 + l15;
            float bia = bias[d];
            float ks  = ks_s[d];
            #pragma unroll
            for (int r = 0; r < 4; ++r) {
                int t = mrow0 + quad * 4 + r;
                float v = acc_h[nt][r] + INV_LOSCALE * acc_c[nt][r] + bia;
                float v2 = v * v;
                qs[t * 68 + d] = v2;
                zp[r] = fmaf(v2, ks, zp[r]);
            }
        }
        #pragma unroll
        for (int r = 0; r < 4; ++r) {
            float p = zp[r];
            p += __shfl_xor(p, 1);
            p += __shfl_xor(p, 2);
            p += __shfl_xor(p, 4);
            p += __shfl_xor(p, 8);
            if (l15 == 0) z_s[mrow0 + quad * 4 + r] = 1.f / (p + 1e-6f);
        }
    }
    __syncthreads();

    float* kvs = (float*)smem;
    {
        const float* __restrict__ kvp = kv_sum + (size_t)(b * NH + h) * HD * HD;
        #pragma unroll
        for (int it = 0; it < 4; ++it) {
            int idx = it * 256 + tid;
            int r = idx >> 4, c = (idx & 15) * 4;
            *(f32x4*)&kvs[r * 64 + c] = *(const f32x4*)&kvp[r * HD + c];
        }
    }
    __syncthreads();

    const int ty = tid >> 4, tx = tid & 15;
    f32x4 sv[4] = {};
    #pragma unroll 4
    for (int d = 0; d < 64; d += 4) {
        f32x4 b0 = *(const f32x4*)&kvs[(d + 0) * 64 + tx * 4];
        f32x4 b1 = *(const f32x4*)&kvs[(d + 1) * 64 + tx * 4];
        f32x4 b2 = *(const f32x4*)&kvs[(d + 2) * 64 + tx * 4];
        f32x4 b3 = *(const f32x4*)&kvs[(d + 3) * 64 + tx * 4];
        #pragma unroll
        for (int i = 0; i < 4; ++i) {
            f32x4 av = *(const f32x4*)&qs[(ty * 4 + i) * 68 + d];
            sv[i] += av.x * b0 + av.y * b1 + av.z * b2 + av.w * b3;
        }
    }
    const size_t opanel = (size_t)b * 64 + bx;
    const int s_out = h * 2 + (tx >> 3);
    const int kq = (tx >> 1) & 3;
    const int rem8 = (tx & 1) * 8;
    #pragma unroll
    for (int i = 0; i < 4; ++i) {
        int t = ty * 4 + i;
        f32x4 o = sv[i] * z_s[t];
        _Float16 hh[4], ll[4];
        #pragma unroll
        for (int j = 0; j < 4; ++j) split1(o[j], hh[j], ll[j]);
        size_t cb = (((opanel * 32 + s_out) * 256 + ((t >> 4) * 4 + kq) * 16 + (t & 15)) << 4) + rem8;
        *(u32x2*)((char*)attn_hi + cb) = (u32x2){pack2(hh[0], hh[1]), pack2(hh[2], hh[3])};
        *(u32x2*)((char*)attn_lo + cb) = (u32x2){pack2(ll[0], ll[1]), pack2(ll[2], ll[3])};
    }
}

// ---------------------------------------------------------------------------
// Kernel 3a (big path): out = qz @ Pt[b] + bo. Per-batch B fragments.
// ---------------------------------------------------------------------------
__global__ __launch_bounds__(256, 3) void out_proj_p_kernel(
    const _Float16* __restrict__ attn_hi, const _Float16* __restrict__ attn_lo,
    const _Float16* __restrict__ pt_hi, const _Float16* __restrict__ pt_lo,
    const float* __restrict__ bo, float* __restrict__ out)
{
    const int tid = threadIdx.x;
    const int lane = tid & 63, wave = tid >> 6, quad = lane >> 4, l15 = lane & 15;
    const int n0 = blockIdx.x * 64;
    const size_t m0 = (size_t)blockIdx.y * 128;

    __shared__ __align__(16) char smem[49152];
    float* cs = (float*)smem;

    const size_t ap0 = (m0 >> 6) * 32, ap1 = ap0 + 32;
    const int bb = (int)(m0 >> 12);                   // batch of this row block
    const _Float16* __restrict__ pbh = pt_hi + (size_t)bb * 16 * 32 * 2048;
    const _Float16* __restrict__ pbl = pt_lo + (size_t)bb * 16 * 32 * 2048;
    const size_t bpn = (size_t)(n0 >> 6) * 32;

    auto stage = [&](int p, int s) {
        char* dst = smem + p * 24576 + tid * 16;
        const size_t co = (size_t)s * 2048 + tid * 8;
        gload16(&attn_hi[ap0 * 2048 + co], dst);
        gload16(&attn_hi[ap1 * 2048 + co], dst + 4096);
        gload16(&attn_lo[ap0 * 2048 + co], dst + 8192);
        gload16(&attn_lo[ap1 * 2048 + co], dst + 12288);
        gload16(&pbh[(bpn + s) * 2048 + tid * 8], dst + 16384);
        gload16(&pbl[(bpn + s) * 2048 + tid * 8], dst + 20480);
    };

    const int panel = wave >> 1;
    f32x4 acc_h[2][4] = {}, acc_c[2][4] = {};
    stage(0, 0);
    for (int s = 0; s < 32; ++s) {
        const int p = s & 1;
        if (s < 31) {
            stage(p ^ 1, s + 1);
            asm volatile("s_waitcnt vmcnt(6)" ::: "memory");
        } else {
            asm volatile("s_waitcnt vmcnt(0)" ::: "memory");
        }
        __builtin_amdgcn_s_barrier();
        __builtin_amdgcn_sched_barrier(0);
        const char* bufc = smem + p * 24576;
        f16x8 afh[2], afl[2], bfh[4], bfl[4];
        #pragma unroll
        for (int mt = 0; mt < 2; ++mt) {
            int rbl = (wave & 1) * 2 + mt;
            afh[mt] = *(const f16x8*)((const _Float16*)(bufc + panel * 4096) + rbl * 512 + lane * 8);
            afl[mt] = *(const f16x8*)((const _Float16*)(bufc + 8192 + panel * 4096) + rbl * 512 + lane * 8);
        }
        #pragma unroll
        for (int nt = 0; nt < 4; ++nt) {
            bfh[nt] = *(const f16x8*)((const _Float16*)(bufc + 16384) + nt * 512 + lane * 8);
            bfl[nt] = *(const f16x8*)((const _Float16*)(bufc + 20480) + nt * 512 + lane * 8);
        }
        #pragma unroll
        for (int mt = 0; mt < 2; ++mt)
            #pragma unroll
            for (int nt = 0; nt < 4; ++nt) {
                acc_h[mt][nt] = mfma_f16(afh[mt], bfh[nt], acc_h[mt][nt]);
                acc_c[mt][nt] = mfma_f16(afh[mt], bfl[nt], acc_c[mt][nt]);
                acc_c[mt][nt] = mfma_f16(afl[mt], bfh[nt], acc_c[mt][nt]);
            }
        __builtin_amdgcn_s_barrier();
        __builtin_amdgcn_sched_barrier(0);
    }

    {
        float bia[4];
        #pragma unroll
        for (int nt = 0; nt < 4; ++nt) bia[nt] = bo[n0 + nt * 16 + l15];
        #pragma unroll
        for (int mt = 0; mt < 2; ++mt)
            #pragma unroll
            for (int nt = 0; nt < 4; ++nt)
                #pragma unroll
                for (int r = 0; r < 4; ++r) {
                    int t = wave * 32 + mt * 16 + quad * 4 + r;
                    cs[t * 64 + nt * 16 + l15] =
                        acc_h[mt][nt][r] + INV_LOSCALE * acc_c[mt][nt][r] + bia[nt];
                }
    }
    __syncthreads();
    #pragma unroll
    for (int it = 0; it < 8; ++it) {
        int idx = it * 256 + tid;
        int r = idx >> 4, c = (idx & 15) * 4;
        *(f32x4*)&out[(m0 + r) * DM + n0 + c] = *(f32x4*)&cs[r * 64 + c];
    }
}

// ---------------------------------------------------------------------------
// Kernel 3b (fallback): out = attn @ Wo^T + bo with Wo fragments.
// ---------------------------------------------------------------------------
__global__ __launch_bounds__(256, 3) void out_proj_kernel(
    const _Float16* __restrict__ attn_hi, const _Float16* __restrict__ attn_lo,
    const _Float16* __restrict__ wo_hi, const _Float16* __restrict__ wo_lo,
    const float* __restrict__ bo, float* __restrict__ out)
{
    const int tid = threadIdx.x;
    const int lane = tid & 63, wave = tid >> 6, quad = lane >> 4, l15 = lane & 15;
    const int n0 = blockIdx.x * 64;
    const size_t m0 = (size_t)blockIdx.y * 128;

    __shared__ __align__(16) char smem[49152];
    float* cs = (float*)smem;

    const size_t ap0 = (m0 >> 6) * 32, ap1 = ap0 + 32;
    const size_t bpn = (size_t)(n0 >> 6) * 32;

    auto stage = [&](int p, int s) {
        char* dst = smem + p * 24576 + tid * 16;
        const size_t co = (size_t)s * 2048 + tid * 8;
        gload16(&attn_hi[ap0 * 2048 + co], dst);
        gload16(&attn_hi[ap1 * 2048 + co], dst + 4096);
        gload16(&attn_lo[ap0 * 2048 + co], dst + 8192);
        gload16(&attn_lo[ap1 * 2048 + co], dst + 12288);
        gload16(&wo_hi[(bpn + s) * 2048 + tid * 8], dst + 16384);
        gload16(&wo_lo[(bpn + s) * 2048 + tid * 8], dst + 20480);
    };

    const int panel = wave >> 1;
    f32x4 acc_h[2][4] = {}, acc_c[2][4] = {};
    stage(0, 0);
    for (int s = 0; s < 32; ++s) {
        const int p = s & 1;
        if (s < 31) {
            stage(p ^ 1, s + 1);
            asm volatile("s_waitcnt vmcnt(6)" ::: "memory");
        } else {
            asm volatile("s_waitcnt vmcnt(0)" ::: "memory");
        }
        __builtin_amdgcn_s_barrier();
        __builtin_amdgcn_sched_barrier(0);
        const char* bufc = smem + p * 24576;
        f16x8 afh[2], afl[2], bfh[4], bfl[4];
        #pragma unroll
        for (int mt = 0; mt < 2; ++mt) {
            int rbl = (wave & 1) * 2 + mt;
            afh[mt] = *(const f16x8*)((const _Float16*)(bufc + panel * 4096) + rbl * 512 + lane * 8);
            afl[mt] = *(const f16x8*)((const _Float16*)(bufc + 8192 + panel * 4096) + rbl * 512 + lane * 8);
        }
        #pragma unroll
        for (int nt = 0; nt < 4; ++nt) {
            bfh[nt] = *(const f16x8*)((const _Float16*)(bufc + 16384) + nt * 512 + lane * 8);
            bfl[nt] = *(const f16x8*)((const _Float16*)(bufc + 20480) + nt * 512 + lane * 8);
        }
        #pragma unroll
        for (int mt = 0; mt < 2; ++mt)
            #pragma unroll
            for (int nt = 0; nt < 4; ++nt) {
                acc_h[mt][nt] = mfma_f16(afh[mt], bfh[nt], acc_h[mt][nt]);
                acc_c[mt][nt] = mfma_f16(afh[mt], bfl[nt], acc_c[mt][nt]);
                acc_c[mt][nt] = mfma_f16(afl[mt], bfh[nt], acc_c[mt][nt]);
            }
        __builtin_amdgcn_s_barrier();
        __builtin_amdgcn_sched_barrier(0);
    }

    {
        float bia[4];
        #pragma unroll
        for (int nt = 0; nt < 4; ++nt) bia[nt] = bo[n0 + nt * 16 + l15];
        #pragma unroll
        for (int mt = 0; mt < 2; ++mt)
            #pragma unroll
            for (int nt = 0; nt < 4; ++nt)
                #pragma unroll
                for (int r = 0; r < 4; ++r) {
                    int t = wave * 32 + mt * 16 + quad * 4 + r;
                    cs[t * 64 + nt * 16 + l15] =
                        acc_h[mt][nt][r] + INV_LOSCALE * acc_c[mt][nt][r] + bia[nt];
                }
    }
    __syncthreads();
    #pragma unroll
    for (int it = 0; it < 8; ++it) {
        int idx = it * 256 + tid;
        int r = idx >> 4, c = (idx & 15) * 4;
        *(f32x4*)&out[(m0 + r) * DM + n0 + c] = *(f32x4*)&cs[r * 64 + c];
    }
}

// ---------------------------------------------------------------------------
extern "C" void kernel_launch(void* const* d_in, const int* in_sizes, int n_in,
                              void* d_out, int out_size, void* d_ws, size_t ws_size,
                              hipStream_t stream) {
    const float* q  = (const float*)d_in[0];
    const float* kv = (const float*)d_in[1];
    const float* Wq = (const float*)d_in[2];
    const float* bq = (const float*)d_in[3];
    const float* Wk = (const float*)d_in[4];
    const float* bk = (const float*)d_in[5];
    const float* Wv = (const float*)d_in[6];
    const float* bv = (const float*)d_in[7];
    const float* Wo = (const float*)d_in[8];
    const float* bo = (const float*)d_in[9];
    float* out = (float*)d_out;

    // workspace: fixed ~85 MB; big path adds q frags (+134 MB) + Pt (+16 MB).
    char* p = (char*)d_ws;
    float* kv_sum = (float*)p;              p += (size_t)BSZ * NH * HD * HD * 4;
    float* ksum   = (float*)p;              p += (size_t)BSZ * NH * HD * 4;
    _Float16* wqt_hi = (_Float16*)p;        p += (size_t)NH * HD * DM * 2;
    _Float16* wqt_lo = (_Float16*)p;        p += (size_t)NH * HD * DM * 2;
    _Float16* wkt_hi = (_Float16*)p;        p += (size_t)NH * HD * DM * 2;
    _Float16* wkt_lo = (_Float16*)p;        p += (size_t)NH * HD * DM * 2;
    _Float16* wvt_hi = (_Float16*)p;        p += (size_t)NH * HD * DM * 2;
    _Float16* wvt_lo = (_Float16*)p;        p += (size_t)NH * HD * DM * 2;
    _Float16* wo_hi  = (_Float16*)p;        p += (size_t)DM * DM * 2;
    _Float16* wo_lo  = (_Float16*)p;        p += (size_t)DM * DM * 2;
    _Float16* buf_hi = (_Float16*)p;        p += (size_t)BT * DM * 2;   // kv frags, then qz/attn
    _Float16* buf_lo = (_Float16*)p;        p += (size_t)BT * DM * 2;
    _Float16* qf_hi  = (_Float16*)p;        p += (size_t)BT * DM * 2;   // big: q frags
    _Float16* qf_lo  = (_Float16*)p;        p += (size_t)BT * DM * 2;
    _Float16* pt_hi  = (_Float16*)p;        p += (size_t)BSZ * DM * DM * 2;  // big: Pt
    _Float16* pt_lo  = (_Float16*)p;        p += (size_t)BSZ * DM * DM * 2;
    const bool big = ws_size >= (size_t)(p - (char*)d_ws);

    size_t zero_bytes = ((size_t)BSZ * NH * HD * HD + (size_t)BSZ * NH * HD) * sizeof(float);
    hipMemsetAsync(d_ws, 0, zero_bytes, stream);

    fragsplit_kernel<<<(BT * DM / 8) / 256, 256, 0, stream>>>(kv, buf_hi, buf_lo);
    wsplit_kernel<<<dim3(DM / 64, NH, 3), 256, 0, stream>>>(
        Wq, Wk, Wv, wqt_hi, wqt_lo, wkt_hi, wkt_lo, wvt_hi, wvt_lo);
    if (!big)
        fragsplit_kernel<<<(DM * DM / 8) / 256, 256, 0, stream>>>(Wo, wo_hi, wo_lo);

    kv_stats_kernel<<<dim3(TSEQ / 256, NH, BSZ), 256, 0, stream>>>(
        buf_hi, buf_lo, wkt_hi, wkt_lo, wvt_hi, wvt_lo, bk, bv, kv_sum, ksum);

    if (big) {
        fragsplit_kernel<<<(BT * DM / 8) / 256, 256, 0, stream>>>(q, qf_hi, qf_lo);
        pmat_kernel<<<dim3(16, NH, BSZ), 256, 0, stream>>>(kv_sum, Wo, pt_hi, pt_lo);
        q_attn_ps_kernel<<<dim3(TSEQ / 128, NH, BSZ), 256, 0, stream>>>(
            qf_hi, qf_lo, wqt_hi, wqt_lo, bq, ksum, buf_hi, buf_lo);
        out_proj_p_kernel<<<dim3(DM / 64, BT / 128), 256, 0, stream>>>(
            buf_hi, buf_lo, pt_hi, pt_lo, bo, out);
    } else {
        q_attn_kernel<<<dim3(TSEQ / 64, NH, BSZ), 256, 0, stream>>>(
            q, wqt_hi, wqt_lo, bq, kv_sum, ksum, buf_hi, buf_lo);
        out_proj_kernel<<<dim3(DM / 64, BT / 128), 256, 0, stream>>>(
            buf_hi, buf_lo, wo_hi, wo_lo, bo, out);
    }
}

// Round 7
// 606.524 us; speedup vs baseline: 1.9198x; 1.0321x over previous
//
#include <hip/hip_runtime.h>

#define BSZ 4
#define TSEQ 4096
#define DM 1024
#define NH 16
#define HD 64
#define BT (BSZ * TSEQ)
#define INV_LOSCALE (1.0f / 4096.0f)

using f32x4 = __attribute__((ext_vector_type(4))) float;
using f16x8 = __attribute__((ext_vector_type(8))) _Float16;
using u32x2 = __attribute__((ext_vector_type(2))) unsigned;
using u32x4 = __attribute__((ext_vector_type(4))) unsigned;

typedef const __attribute__((address_space(1))) void* gas_ptr;
typedef __attribute__((address_space(3))) void* las_ptr;

// Async global->LDS, 16 B per lane. LDS dest = uniform base + lane*16.
__device__ __forceinline__ void gload16(const void* g, void* l) {
    __builtin_amdgcn_global_load_lds((gas_ptr)g, (las_ptr)l, 16, 0, 0);
}

// f16 RTN split: x = hi + lo/4096 + r. lo pre-scaled by 4096 (denormal immunity).
__device__ __forceinline__ void split1(float x, _Float16& h, _Float16& l) {
    h = (_Float16)x;
    l = (_Float16)((x - (float)h) * 4096.0f);
}
__device__ __forceinline__ unsigned pack2(_Float16 a, _Float16 b) {
    return (unsigned)__builtin_bit_cast(unsigned short, a) |
           ((unsigned)__builtin_bit_cast(unsigned short, b) << 16);
}
__device__ __forceinline__ f32x4 mfma_f16(f16x8 a, f16x8 b, f32x4 c) {
    return __builtin_amdgcn_mfma_f32_16x16x32_f16(a, b, c, 0, 0, 0);
}

// ---------------------------------------------------------------------------
// Fragment-linear layout: row-major [R][1024] fp32 -> per 64-row panel, per
// 32-k step, a 64x32 tile stored as 256 x 16B chunks ordered
// chunk = [rb(4)][kquad(4)][l15(16)] (lane i of a wave reads bytes i*16).
// ---------------------------------------------------------------------------
__global__ __launch_bounds__(256) void fragsplit_kernel(const float* __restrict__ in,
        _Float16* __restrict__ hi, _Float16* __restrict__ lo) {
    const int C = blockIdx.x * 256 + threadIdx.x;      // global chunk id
    const int l15 = C & 15, quad = (C >> 4) & 3, rb = (C >> 6) & 3;
    const int s = (C >> 8) & 31, panel = C >> 13;
    const size_t src = ((size_t)(panel * 64 + rb * 16 + l15)) * DM + s * 32 + quad * 8;
    f32x4 v0 = *(const f32x4*)&in[src];
    f32x4 v1 = *(const f32x4*)&in[src + 4];
    _Float16 h[8], l[8];
    #pragma unroll
    for (int j = 0; j < 4; ++j) { split1(v0[j], h[j], l[j]); split1(v1[j], h[4 + j], l[4 + j]); }
    ((u32x4*)hi)[C] = (u32x4){pack2(h[0],h[1]), pack2(h[2],h[3]), pack2(h[4],h[5]), pack2(h[6],h[7])};
    ((u32x4*)lo)[C] = (u32x4){pack2(l[0],l[1]), pack2(l[2],l[3]), pack2(l[4],l[5]), pack2(l[6],l[7])};
}

// ---------------------------------------------------------------------------
// Wq/Wk/Wv [h][k][n] -> transposed fragment-linear hi/lo f16 (panel = head).
// ---------------------------------------------------------------------------
__global__ __launch_bounds__(256) void wsplit_kernel(
    const float* __restrict__ Wq, const float* __restrict__ Wk, const float* __restrict__ Wv,
    _Float16* __restrict__ qh, _Float16* __restrict__ ql,
    _Float16* __restrict__ kh, _Float16* __restrict__ kl,
    _Float16* __restrict__ vh, _Float16* __restrict__ vl) {
    const int tid = threadIdx.x;
    const int k0 = blockIdx.x * 64, h = blockIdx.y, w = blockIdx.z;
    const float* __restrict__ W = (w == 0) ? Wq : (w == 1) ? Wk : Wv;
    _Float16* __restrict__ dh = (w == 0) ? qh : (w == 1) ? kh : vh;
    _Float16* __restrict__ dl = (w == 0) ? ql : (w == 1) ? kl : vl;
    __shared__ __align__(16) float ws_[64][68];
    #pragma unroll
    for (int it = 0; it < 4; ++it) {
        int idx = it * 256 + tid;
        int r = idx >> 4, c4 = (idx & 15) * 4;
        *(f32x4*)&ws_[r][c4] = *(const f32x4*)&W[((size_t)h * DM + k0 + r) * HD + c4];
    }
    __syncthreads();
    const int n = tid >> 2, kq16 = (tid & 3) * 16;
    _Float16 hh[16], ll[16];
    #pragma unroll
    for (int j = 0; j < 16; ++j) split1(ws_[kq16 + j][n], hh[j], ll[j]);
    #pragma unroll
    for (int c = 0; c < 2; ++c) {
        int kg = k0 + kq16 + c * 8;
        int s = kg >> 5, quad = (kg >> 3) & 3;
        size_t chunk = (size_t)(h * 32 + s) * 256 + ((n >> 4) * 4 + quad) * 16 + (n & 15);
        ((u32x4*)dh)[chunk] = (u32x4){pack2(hh[c*8+0],hh[c*8+1]), pack2(hh[c*8+2],hh[c*8+3]),
                                      pack2(hh[c*8+4],hh[c*8+5]), pack2(hh[c*8+6],hh[c*8+7])};
        ((u32x4*)dl)[chunk] = (u32x4){pack2(ll[c*8+0],ll[c*8+1]), pack2(ll[c*8+2],ll[c*8+3]),
                                      pack2(ll[c*8+4],ll[c*8+5]), pack2(ll[c*8+6],ll[c*8+7])};
    }
}

// ---------------------------------------------------------------------------
// Kernel 1: kh2 = (kv@Wk+bk)^2, vh = kv@Wv+bv via 3-term f16-split MFMA.
// M=128 k-step tiles; T4 counted-vmcnt pipeline; MFMA rank-T reduction.
// XCD-chunk 1D grid: all 16 head-blocks of one A-strip land on one XCD so
// the kv strip is fetched into that XCD's L2 once (not 16x through L3).
// ---------------------------------------------------------------------------
__global__ __launch_bounds__(256, 2) void kv_stats_kernel(
    const _Float16* __restrict__ kv_hi, const _Float16* __restrict__ kv_lo,
    const _Float16* __restrict__ wkt_hi, const _Float16* __restrict__ wkt_lo,
    const _Float16* __restrict__ wvt_hi, const _Float16* __restrict__ wvt_lo,
    const float* __restrict__ bk, const float* __restrict__ bv,
    float* __restrict__ kv_sum, float* __restrict__ ksum)
{
    const int tid = threadIdx.x;
    const int lane = tid & 63, wave = tid >> 6, quad = lane >> 4, l15 = lane & 15;
    // XCD-chunk decode: g%8 = XCD (round-robin dispatch); within an XCD,
    // 16 consecutive blocks share one A-strip (h varies fastest).
    const int g = blockIdx.x;
    const int xcd = g & 7, kk = g >> 3;
    const int h = kk & 15, sg = kk >> 4;
    const int strip = xcd + 8 * sg;                   // 0..63
    const int b = strip >> 4, bx = strip & 15;

    __shared__ __align__(16) char smem[65536];
    _Float16* khT_h = (_Float16*)smem;
    _Float16* khT_l = (_Float16*)(smem + 16384);
    _Float16* vhT_h = (_Float16*)(smem + 32768);
    _Float16* vhT_l = (_Float16*)(smem + 49152);

    const int isV = wave >> 1, half = wave & 1;
    const size_t btile = (size_t)h * 32;

    f32x4 racc_h[4] = {}, racc_c[4] = {};
    f32x4 rk_h = {}, rk_c = {};
    const f16x8 ones = __builtin_bit_cast(f16x8,
        (u32x4){0x3C003C00u, 0x3C003C00u, 0x3C003C00u, 0x3C003C00u});

    for (int sub = 0; sub < 2; ++sub) {
        const size_t apan = (size_t)(b * 64 + bx * 4 + sub * 2);   // 2 panels/step
        auto stage = [&](int p, int s) {
            char* dst = smem + p * 32768 + tid * 16;
            const size_t a0 = (apan * 32 + s) * 2048 + tid * 8;
            const size_t a1 = ((apan + 1) * 32 + s) * 2048 + tid * 8;
            const size_t bo = (btile + s) * 2048 + tid * 8;
            gload16(&kv_hi[a0], dst);
            gload16(&kv_hi[a1], dst + 4096);
            gload16(&kv_lo[a0], dst + 8192);
            gload16(&kv_lo[a1], dst + 12288);
            gload16(&wkt_hi[bo], dst + 16384);
            gload16(&wkt_lo[bo], dst + 20480);
            gload16(&wvt_hi[bo], dst + 24576);
            gload16(&wvt_lo[bo], dst + 28672);
        };

        f32x4 acc_h[4][4] = {}, acc_c[4][4] = {};
        stage(0, 0);                                  // tile 0 in flight (8)
        for (int s = 0; s < 32; ++s) {
            const int p = s & 1;
            if (s < 31) {
                stage(p ^ 1, s + 1);                  // 16 outstanding
                asm volatile("s_waitcnt vmcnt(8)" ::: "memory");
            } else {
                asm volatile("s_waitcnt vmcnt(0)" ::: "memory");
            }
            __builtin_amdgcn_s_barrier();
            __builtin_amdgcn_sched_barrier(0);
            const char* bufc = smem + p * 32768;
            const _Float16* a_hi = (const _Float16*)bufc;
            const _Float16* a_lo = (const _Float16*)(bufc + 8192);
            const _Float16* bh = (const _Float16*)(bufc + (isV ? 24576 : 16384));
            const _Float16* bl = (const _Float16*)(bufc + (isV ? 28672 : 20480));
            f16x8 afh[4], afl[4], bfh[4], bfl[4];
            #pragma unroll
            for (int mt = 0; mt < 4; ++mt) {          // wave's 64 rows: half*64..
                afh[mt] = *(const f16x8*)&a_hi[half * 2048 + mt * 512 + lane * 8];
                afl[mt] = *(const f16x8*)&a_lo[half * 2048 + mt * 512 + lane * 8];
            }
            #pragma unroll
            for (int nt = 0; nt < 4; ++nt) {
                bfh[nt] = *(const f16x8*)&bh[nt * 512 + lane * 8];
                bfl[nt] = *(const f16x8*)&bl[nt * 512 + lane * 8];
            }
            #pragma unroll
            for (int mt = 0; mt < 4; ++mt)
                #pragma unroll
                for (int nt = 0; nt < 4; ++nt) {
                    acc_h[mt][nt] = mfma_f16(afh[mt], bfh[nt], acc_h[mt][nt]);
                    acc_c[mt][nt] = mfma_f16(afh[mt], bfl[nt], acc_c[mt][nt]);
                    acc_c[mt][nt] = mfma_f16(afl[mt], bfh[nt], acc_c[mt][nt]);
                }
            __builtin_amdgcn_s_barrier();
            __builtin_amdgcn_sched_barrier(0);
        }

        // combine (+bias, square for K) and TRANSPOSED split-store.
        {
            const float* __restrict__ bias = (isV ? bv : bk) + h * HD;
            _Float16* __restrict__ dh = isV ? vhT_h : khT_h;
            _Float16* __restrict__ dl = isV ? vhT_l : khT_l;
            float bia[4];
            #pragma unroll
            for (int nt = 0; nt < 4; ++nt) bia[nt] = bias[nt * 16 + l15];
            #pragma unroll
            for (int mt = 0; mt < 4; ++mt) {
                const int S = half * 2 + (mt >> 1);
                const int tq = (mt & 1) * 2 + (quad >> 1);
                const int eo = (quad & 1) * 4;
                #pragma unroll
                for (int nt = 0; nt < 4; ++nt) {
                    _Float16 hh[4], ll[4];
                    #pragma unroll
                    for (int r = 0; r < 4; ++r) {
                        float v = acc_h[mt][nt][r] + INV_LOSCALE * acc_c[mt][nt][r] + bia[nt];
                        if (!isV) v = v * v;          // wave-uniform branch
                        split1(v, hh[r], ll[r]);
                    }
                    int fo = S * 2048 + (nt * 4 + tq) * 128 + l15 * 8 + eo;
                    *(u32x2*)&dh[fo] = (u32x2){pack2(hh[0], hh[1]), pack2(hh[2], hh[3])};
                    *(u32x2*)&dl[fo] = (u32x2){pack2(ll[0], ll[1]), pack2(ll[2], ll[3])};
                }
            }
        }
        __syncthreads();

        // MFMA reduction: kv_sum[d][e] += sum_t kh2[t][d]*vh[t][e], K=128.
        #pragma unroll
        for (int S = 0; S < 4; ++S) {
            f16x8 ah = *(const f16x8*)&khT_h[S * 2048 + wave * 512 + lane * 8];
            f16x8 al = *(const f16x8*)&khT_l[S * 2048 + wave * 512 + lane * 8];
            rk_h = mfma_f16(ah, ones, rk_h);
            rk_c = mfma_f16(al, ones, rk_c);
            #pragma unroll
            for (int nt = 0; nt < 4; ++nt) {
                f16x8 bh = *(const f16x8*)&vhT_h[S * 2048 + nt * 512 + lane * 8];
                f16x8 bl = *(const f16x8*)&vhT_l[S * 2048 + nt * 512 + lane * 8];
                racc_h[nt] = mfma_f16(ah, bh, racc_h[nt]);
                racc_c[nt] = mfma_f16(ah, bl, racc_c[nt]);
                racc_c[nt] = mfma_f16(al, bh, racc_c[nt]);
            }
        }
        __syncthreads();                              // reads done before next staging
    }

    float* kvp = kv_sum + (size_t)(b * NH + h) * HD * HD;
    #pragma unroll
    for (int nt = 0; nt < 4; ++nt)
        #pragma unroll
        for (int r = 0; r < 4; ++r)
            atomicAdd(&kvp[(wave * 16 + quad * 4 + r) * HD + nt * 16 + l15],
                      racc_h[nt][r] + INV_LOSCALE * racc_c[nt][r]);
    if (l15 == 0) {
        float* ksp = ksum + (b * NH + h) * HD;
        #pragma unroll
        for (int r = 0; r < 4; ++r)
            atomicAdd(&ksp[wave * 16 + quad * 4 + r], rk_h[r] + INV_LOSCALE * rk_c[r]);
    }
}

// ---------------------------------------------------------------------------
// P-fusion precompute: Pt[b][o][(h,d)] = (1/4096) * sum_e kv_sum[b,h][d][e]
// * Wo[o][h*64+e], written fragment-linear f16 hi/lo.
// ---------------------------------------------------------------------------
__global__ __launch_bounds__(256) void pmat_kernel(
    const float* __restrict__ kv_sum, const float* __restrict__ Wo,
    _Float16* __restrict__ pt_hi, _Float16* __restrict__ pt_lo)
{
    const int tid = threadIdx.x;
    const int opan = blockIdx.x, h = blockIdx.y, b = blockIdx.z;
    __shared__ __align__(16) float kvsT[64][68];      // [e][d]
    __shared__ __align__(16) float wos[64][68];       // [o-local][e]
    const float* __restrict__ kvp = kv_sum + (size_t)(b * NH + h) * HD * HD;
    #pragma unroll
    for (int it = 0; it < 4; ++it) {
        int idx = it * 256 + tid;
        int d = idx >> 4, e4 = (idx & 15) * 4;
        f32x4 v = *(const f32x4*)&kvp[d * HD + e4];
        kvsT[e4 + 0][d] = v.x; kvsT[e4 + 1][d] = v.y;
        kvsT[e4 + 2][d] = v.z; kvsT[e4 + 3][d] = v.w;
        int o = idx >> 4;
        *(f32x4*)&wos[o][e4] = *(const f32x4*)&Wo[(size_t)(opan * 64 + o) * DM + h * HD + e4];
    }
    __syncthreads();
    const int ty = tid >> 4, tx = tid & 15;
    f32x4 sv[4] = {};
    #pragma unroll 8
    for (int e = 0; e < 64; ++e) {
        f32x4 kv4 = *(const f32x4*)&kvsT[e][tx * 4];
        #pragma unroll
        for (int i = 0; i < 4; ++i) sv[i] += wos[ty * 4 + i][e] * kv4;
    }
    const int d0 = tx * 4;
    const int S = h * 2 + (d0 >> 5);
    const int kq = (d0 >> 3) & 3;
    const int rem8 = (d0 & 4) ? 8 : 0;
    #pragma unroll
    for (int i = 0; i < 4; ++i) {
        int ol = ty * 4 + i;
        f32x4 o4 = sv[i] * INV_LOSCALE;               // exact 2^-12 scale
        _Float16 hh[4], ll[4];
        #pragma unroll
        for (int j = 0; j < 4; ++j) split1(o4[j], hh[j], ll[j]);
        size_t cb = ((((size_t)(b * 16 + opan) * 32 + S) * 256 +
                      ((ol >> 4) * 4 + kq) * 16 + (ol & 15)) << 4) + rem8;
        *(u32x2*)((char*)pt_hi + cb) = (u32x2){pack2(hh[0], hh[1]), pack2(hh[2], hh[3])};
        *(u32x2*)((char*)pt_lo + cb) = (u32x2){pack2(ll[0], ll[1]), pack2(ll[2], ll[3])};
    }
}

// ---------------------------------------------------------------------------
// Kernel 2a (pre-split q path): qh = qf@Wq+bq, M=128 tiles, 6 loads/step.
// XCD-chunk 1D grid (A-strip reuse across the 16 heads within one XCD L2).
// Epilogue writes qz = 4096z*qh2 as SINGLE f16 (hi-only) fragments.
// ---------------------------------------------------------------------------
__global__ __launch_bounds__(256, 3) void q_attn_ps_kernel(
    const _Float16* __restrict__ qf_hi, const _Float16* __restrict__ qf_lo,
    const _Float16* __restrict__ wqt_hi, const _Float16* __restrict__ wqt_lo,
    const float* __restrict__ bq, const float* __restrict__ ksum,
    _Float16* __restrict__ attn_hi)
{
    const int tid = threadIdx.x;
    const int lane = tid & 63, wave = tid >> 6, quad = lane >> 4, l15 = lane & 15;
    const int g = blockIdx.x;
    const int xcd = g & 7, kk = g >> 3;
    const int h = kk & 15, sg = kk >> 4;
    const int strip = xcd + 8 * sg;                   // 0..127
    const int b = strip >> 5, bx = strip & 31;

    __shared__ __align__(16) char smem[49152];
    __shared__ float z_s[128], ks_s[64];

    if (tid < 64) ks_s[tid] = ksum[(b * NH + h) * HD + tid];

    const size_t apan = (size_t)(b * 64 + bx * 2);
    const size_t btile = (size_t)h * 32;

    auto stage = [&](int p, int s) {
        char* dst = smem + p * 24576 + tid * 16;
        const size_t a0 = (apan * 32 + s) * 2048 + tid * 8;
        const size_t a1 = ((apan + 1) * 32 + s) * 2048 + tid * 8;
        const size_t bo = (btile + s) * 2048 + tid * 8;
        gload16(&qf_hi[a0], dst);
        gload16(&qf_hi[a1], dst + 4096);
        gload16(&qf_lo[a0], dst + 8192);
        gload16(&qf_lo[a1], dst + 12288);
        gload16(&wqt_hi[bo], dst + 16384);
        gload16(&wqt_lo[bo], dst + 20480);
    };

    f32x4 acc_h[2][4] = {}, acc_c[2][4] = {};
    stage(0, 0);
    for (int s = 0; s < 32; ++s) {
        const int p = s & 1;
        if (s < 31) {
            stage(p ^ 1, s + 1);
            asm volatile("s_waitcnt vmcnt(6)" ::: "memory");
        } else {
            asm volatile("s_waitcnt vmcnt(0)" ::: "memory");
        }
        __builtin_amdgcn_s_barrier();
        __builtin_amdgcn_sched_barrier(0);
        const char* bufc = smem + p * 24576;
        const _Float16* a_hi = (const _Float16*)bufc;
        const _Float16* a_lo = (const _Float16*)(bufc + 8192);
        f16x8 afh[2], afl[2], bfh[4], bfl[4];
        #pragma unroll
        for (int mt = 0; mt < 2; ++mt) {
            int fo = (wave * 2 + mt) * 512 + lane * 8;
            afh[mt] = *(const f16x8*)&a_hi[fo];
            afl[mt] = *(const f16x8*)&a_lo[fo];
        }
        #pragma unroll
        for (int nt = 0; nt < 4; ++nt) {
            bfh[nt] = *(const f16x8*)((const _Float16*)(bufc + 16384) + nt * 512 + lane * 8);
            bfl[nt] = *(const f16x8*)((const _Float16*)(bufc + 20480) + nt * 512 + lane * 8);
        }
        #pragma unroll
        for (int mt = 0; mt < 2; ++mt)
            #pragma unroll
            for (int nt = 0; nt < 4; ++nt) {
                acc_h[mt][nt] = mfma_f16(afh[mt], bfh[nt], acc_h[mt][nt]);
                acc_c[mt][nt] = mfma_f16(afh[mt], bfl[nt], acc_c[mt][nt]);
                acc_c[mt][nt] = mfma_f16(afl[mt], bfh[nt], acc_c[mt][nt]);
            }
        __builtin_amdgcn_s_barrier();
        __builtin_amdgcn_sched_barrier(0);
    }

    // epilogue: qh2 -> qs; z' = 4096*z via shfl over the 16 n-lanes
    float* qs = (float*)smem;
    {
        const float* __restrict__ bias = bq + h * HD;
        float zp[2][4] = {};
        #pragma unroll
        for (int nt = 0; nt < 4; ++nt) {
            int d = nt * 16 + l15;
            float bia = bias[d];
            float ks  = ks_s[d];
            #pragma unroll
            for (int mt = 0; mt < 2; ++mt)
                #pragma unroll
                for (int r = 0; r < 4; ++r) {
                    int t = wave * 32 + mt * 16 + quad * 4 + r;
                    float v = acc_h[mt][nt][r] + INV_LOSCALE * acc_c[mt][nt][r] + bia;
                    float v2 = v * v;
                    qs[t * 68 + d] = v2;
                    zp[mt][r] = fmaf(v2, ks, zp[mt][r]);
                }
        }
        #pragma unroll
        for (int mt = 0; mt < 2; ++mt)
            #pragma unroll
            for (int r = 0; r < 4; ++r) {
                float p = zp[mt][r];
                p += __shfl_xor(p, 1);
                p += __shfl_xor(p, 2);
                p += __shfl_xor(p, 4);
                p += __shfl_xor(p, 8);
                if (l15 == 0) z_s[wave * 32 + mt * 16 + quad * 4 + r] = 4096.0f / (p + 1e-6f);
            }
    }
    __syncthreads();

    // qz chunk writes (hi-only): 1024 chunks, u32x4 each.
    #pragma unroll
    for (int it = 0; it < 4; ++it) {
        int cid = it * 256 + tid;
        int lp = cid >> 9, Sl = (cid >> 8) & 1, c = cid & 255;
        int t = lp * 64 + (c >> 6) * 16 + (c & 15);
        int d = Sl * 32 + ((c >> 4) & 3) * 8;
        f32x4 a0 = *(const f32x4*)&qs[t * 68 + d];
        f32x4 a1 = *(const f32x4*)&qs[t * 68 + d + 4];
        float z = z_s[t];
        _Float16 hh[8];
        #pragma unroll
        for (int j = 0; j < 4; ++j) {
            hh[j]     = (_Float16)(z * a0[j]);
            hh[4 + j] = (_Float16)(z * a1[j]);
        }
        size_t cb = (((size_t)(b * 64 + bx * 2 + lp) * 32 + h * 2 + Sl) * 256 + c) << 4;
        *(u32x4*)((char*)attn_hi + cb) =
            (u32x4){pack2(hh[0],hh[1]), pack2(hh[2],hh[3]), pack2(hh[4],hh[5]), pack2(hh[6],hh[7])};
    }
}

// ---------------------------------------------------------------------------
// Kernel 2b (fallback, ws too small): on-the-fly q split (R3 version).
// ---------------------------------------------------------------------------
__global__ __launch_bounds__(256, 3) void q_attn_kernel(
    const float* __restrict__ q,
    const _Float16* __restrict__ wqt_hi, const _Float16* __restrict__ wqt_lo,
    const float* __restrict__ bq,
    const float* __restrict__ kv_sum, const float* __restrict__ ksum,
    _Float16* __restrict__ attn_hi, _Float16* __restrict__ attn_lo)
{
    const int tid = threadIdx.x;
    const int lane = tid & 63, wave = tid >> 6, quad = lane >> 4, l15 = lane & 15;
    const int b = blockIdx.z, h = blockIdx.y, bx = blockIdx.x;
    const int t0 = bx * 64;

    __shared__ __align__(16) char smem[32768];
    __shared__ __align__(16) float qs[64 * 68];
    __shared__ float z_s[64], ks_s[64];

    if (tid < 64) ks_s[tid] = ksum[(b * NH + h) * HD + tid];

    const int arb = tid >> 6, aquad = (tid >> 4) & 3, al15 = tid & 15;
    const float* __restrict__ qrow =
        q + ((size_t)b * TSEQ + t0 + arb * 16 + al15) * DM + aquad * 8;
    const size_t btile = (size_t)h * 32;

    auto asplit_write = [&](int p, f32x4 v0, f32x4 v1) {
        _Float16 hh[8], ll[8];
        #pragma unroll
        for (int j = 0; j < 4; ++j) { split1(v0[j], hh[j], ll[j]); split1(v1[j], hh[4+j], ll[4+j]); }
        char* dst = smem + p * 16384 + tid * 16;
        *(u32x4*)dst =
            (u32x4){pack2(hh[0],hh[1]), pack2(hh[2],hh[3]), pack2(hh[4],hh[5]), pack2(hh[6],hh[7])};
        *(u32x4*)(dst + 4096) =
            (u32x4){pack2(ll[0],ll[1]), pack2(ll[2],ll[3]), pack2(ll[4],ll[5]), pack2(ll[6],ll[7])};
    };
    auto stageB = [&](int p, int s) {
        char* dst = smem + p * 16384 + 8192 + tid * 16;
        const size_t bo = (btile + s) * 2048 + tid * 8;
        gload16(&wqt_hi[bo], dst);
        gload16(&wqt_lo[bo], dst + 4096);
    };

    f32x4 acc_h[4] = {}, acc_c[4] = {};
    f32x4 v0 = *(const f32x4*)&qrow[0];
    f32x4 v1 = *(const f32x4*)&qrow[4];
    asplit_write(0, v0, v1);
    stageB(0, 0);
    v0 = *(const f32x4*)&qrow[32];
    v1 = *(const f32x4*)&qrow[36];
    asm volatile("s_waitcnt vmcnt(2) lgkmcnt(0)" ::: "memory");
    __builtin_amdgcn_s_barrier();
    __builtin_amdgcn_sched_barrier(0);

    for (int s = 0; s < 32; ++s) {
        const int p = s & 1;
        if (s < 31) {
            stageB(p ^ 1, s + 1);
            asplit_write(p ^ 1, v0, v1);
            if (s < 30) {
                v0 = *(const f32x4*)&qrow[(s + 2) * 32];
                v1 = *(const f32x4*)&qrow[(s + 2) * 32 + 4];
            }
            asm volatile("s_waitcnt vmcnt(4) lgkmcnt(0)" ::: "memory");
        } else {
            asm volatile("s_waitcnt vmcnt(0)" ::: "memory");
        }
        __builtin_amdgcn_s_barrier();
        __builtin_amdgcn_sched_barrier(0);
        const char* bufc = smem + p * 16384;
        f16x8 afh = *(const f16x8*)((const _Float16*)bufc + wave * 512 + lane * 8);
        f16x8 afl = *(const f16x8*)((const _Float16*)(bufc + 4096) + wave * 512 + lane * 8);
        f16x8 bfh[4], bfl[4];
        #pragma unroll
        for (int nt = 0; nt < 4; ++nt) {
            bfh[nt] = *(const f16x8*)((const _Float16*)(bufc + 8192) + nt * 512 + lane * 8);
            bfl[nt] = *(const f16x8*)((const _Float16*)(bufc + 12288) + nt * 512 + lane * 8);
        }
        #pragma unroll
        for (int nt = 0; nt < 4; ++nt) {
            acc_h[nt] = mfma_f16(afh, bfh[nt], acc_h[nt]);
            acc_c[nt] = mfma_f16(afh, bfl[nt], acc_c[nt]);
            acc_c[nt] = mfma_f16(afl, bfh[nt], acc_c[nt]);
        }
        __builtin_amdgcn_s_barrier();
        __builtin_amdgcn_sched_barrier(0);
    }

    {
        const int mrow0 = wave * 16;
        const float* __restrict__ bias = bq + h * HD;
        float zp[4] = {0.f, 0.f, 0.f, 0.f};
        #pragma unroll
        for (int nt = 0; nt < 4; ++nt) {
            int d = nt * 16 + l15;
            float bia = bias[d];
            float ks  = ks_s[d];
            #pragma unroll
            for (int r = 0; r < 4; ++r) {
                int t = mrow0 + quad * 4 + r;
                float v = acc_h[nt][r] + INV_LOSCALE * acc_c[nt][r] + bia;
                float v2 = v * v;
                qs[t * 68 + d] = v2;
                zp[r] = fmaf(v2, ks, zp[r]);
            }
        }
        #pragma unroll
        for (int r = 0; r < 4; ++r) {
            float p = zp[r];
            p += __shfl_xor(p, 1);
            p += __shfl_xor(p, 2);
            p += __shfl_xor(p, 4);
            p += __shfl_xor(p, 8);
            if (l15 == 0) z_s[mrow0 + quad * 4 + r] = 1.f / (p + 1e-6f);
        }
    }
    __syncthreads();

    float* kvs = (float*)smem;
    {
        const float* __restrict__ kvp = kv_sum + (size_t)(b * NH + h) * HD * HD;
        #pragma unroll
        for (int it = 0; it < 4; ++it) {
            int idx = it * 256 + tid;
            int r = idx >> 4, c = (idx & 15) * 4;
            *(f32x4*)&kvs[r * 64 + c] = *(const f32x4*)&kvp[r * HD + c];
        }
    }
    __syncthreads();

    const int ty = tid >> 4, tx = tid & 15;
    f32x4 sv[4] = {};
    #pragma unroll 4
    for (int d = 0; d < 64; d += 4) {
        f32x4 b0 = *(const f32x4*)&kvs[(d + 0) * 64 + tx * 4];
        f32x4 b1 = *(const f32x4*)&kvs[(d + 1) * 64 + tx * 4];
        f32x4 b2 = *(const f32x4*)&kvs[(d + 2) * 64 + tx * 4];
        f32x4 b3 = *(const f32x4*)&kvs[(d + 3) * 64 + tx * 4];
        #pragma unroll
        for (int i = 0; i < 4; ++i) {
            f32x4 av = *(const f32x4*)&qs[(ty * 4 + i) * 68 + d];
            sv[i] += av.x * b0 + av.y * b1 + av.z * b2 + av.w * b3;
        }
    }
    const size_t opanel = (size_t)b * 64 + bx;
    const int s_out = h * 2 + (tx >> 3);
    const int kq = (tx >> 1) & 3;
    const int rem8 = (tx & 1) * 8;
    #pragma unroll
    for (int i = 0; i < 4; ++i) {
        int t = ty * 4 + i;
        f32x4 o = sv[i] * z_s[t];
        _Float16 hh[4], ll[4];
        #pragma unroll
        for (int j = 0; j < 4; ++j) split1(o[j], hh[j], ll[j]);
        size_t cb = (((opanel * 32 + s_out) * 256 + ((t >> 4) * 4 + kq) * 16 + (t & 15)) << 4) + rem8;
        *(u32x2*)((char*)attn_hi + cb) = (u32x2){pack2(hh[0], hh[1]), pack2(hh[2], hh[3])};
        *(u32x2*)((char*)attn_lo + cb) = (u32x2){pack2(ll[0], ll[1]), pack2(ll[2], ll[3])};
    }
}

// ---------------------------------------------------------------------------
// Kernel 3a (big path): out = qz(hi-only) @ Pt[b] + bo. 2-term MFMA,
// 4 loads/step, 32 KB LDS -> 4 blocks/CU. XCD-chunk 1D grid (attn m-strip
// reused across the 16 n-blocks within one XCD L2).
// ---------------------------------------------------------------------------
__global__ __launch_bounds__(256, 4) void out_proj_p_kernel(
    const _Float16* __restrict__ attn_hi,
    const _Float16* __restrict__ pt_hi, const _Float16* __restrict__ pt_lo,
    const float* __restrict__ bo, float* __restrict__ out)
{
    const int tid = threadIdx.x;
    const int lane = tid & 63, wave = tid >> 6, quad = lane >> 4, l15 = lane & 15;
    const int g = blockIdx.x;
    const int xcd = g & 7, kk = g >> 3;
    const int nidx = kk & 15, sg = kk >> 4;
    const int mstrip = xcd + 8 * sg;                  // 0..127
    const int n0 = nidx * 64;
    const size_t m0 = (size_t)mstrip * 128;

    __shared__ __align__(16) char smem[32768];
    float* cs = (float*)smem;                         // epilogue alias, 32K

    const size_t ap0 = (m0 >> 6) * 32, ap1 = ap0 + 32;
    const int bb = (int)(m0 >> 12);                   // batch of this row block
    const _Float16* __restrict__ pbh = pt_hi + (size_t)bb * 16 * 32 * 2048;
    const _Float16* __restrict__ pbl = pt_lo + (size_t)bb * 16 * 32 * 2048;
    const size_t bpn = (size_t)(n0 >> 6) * 32;

    // buffer p at p*16384: a_hi panel0 @0, panel1 @4K, pt_hi @8K, pt_lo @12K
    auto stage = [&](int p, int s) {
        char* dst = smem + p * 16384 + tid * 16;
        const size_t co = (size_t)s * 2048 + tid * 8;
        gload16(&attn_hi[ap0 * 2048 + co], dst);
        gload16(&attn_hi[ap1 * 2048 + co], dst + 4096);
        gload16(&pbh[(bpn + s) * 2048 + tid * 8], dst + 8192);
        gload16(&pbl[(bpn + s) * 2048 + tid * 8], dst + 12288);
    };

    const int panel = wave >> 1;
    f32x4 acc_h[2][4] = {}, acc_c[2][4] = {};
    stage(0, 0);
    for (int s = 0; s < 32; ++s) {
        const int p = s & 1;
        if (s < 31) {
            stage(p ^ 1, s + 1);
            asm volatile("s_waitcnt vmcnt(4)" ::: "memory");
        } else {
            asm volatile("s_waitcnt vmcnt(0)" ::: "memory");
        }
        __builtin_amdgcn_s_barrier();
        __builtin_amdgcn_sched_barrier(0);
        const char* bufc = smem + p * 16384;
        f16x8 afh[2], bfh[4], bfl[4];
        #pragma unroll
        for (int mt = 0; mt < 2; ++mt) {
            int rbl = (wave & 1) * 2 + mt;
            afh[mt] = *(const f16x8*)((const _Float16*)(bufc + panel * 4096) + rbl * 512 + lane * 8);
        }
        #pragma unroll
        for (int nt = 0; nt < 4; ++nt) {
            bfh[nt] = *(const f16x8*)((const _Float16*)(bufc + 8192) + nt * 512 + lane * 8);
            bfl[nt] = *(const f16x8*)((const _Float16*)(bufc + 12288) + nt * 512 + lane * 8);
        }
        #pragma unroll
        for (int mt = 0; mt < 2; ++mt)
            #pragma unroll
            for (int nt = 0; nt < 4; ++nt) {
                acc_h[mt][nt] = mfma_f16(afh[mt], bfh[nt], acc_h[mt][nt]);
                acc_c[mt][nt] = mfma_f16(afh[mt], bfl[nt], acc_c[mt][nt]);
            }
        __builtin_amdgcn_s_barrier();
        __builtin_amdgcn_sched_barrier(0);
    }

    {
        float bia[4];
        #pragma unroll
        for (int nt = 0; nt < 4; ++nt) bia[nt] = bo[n0 + nt * 16 + l15];
        #pragma unroll
        for (int mt = 0; mt < 2; ++mt)
            #pragma unroll
            for (int nt = 0; nt < 4; ++nt)
                #pragma unroll
                for (int r = 0; r < 4; ++r) {
                    int t = wave * 32 + mt * 16 + quad * 4 + r;
                    cs[t * 64 + nt * 16 + l15] =
                        acc_h[mt][nt][r] + INV_LOSCALE * acc_c[mt][nt][r] + bia[nt];
                }
    }
    __syncthreads();
    #pragma unroll
    for (int it = 0; it < 8; ++it) {
        int idx = it * 256 + tid;
        int r = idx >> 4, c = (idx & 15) * 4;
        *(f32x4*)&out[(m0 + r) * DM + n0 + c] = *(f32x4*)&cs[r * 64 + c];
    }
}

// ---------------------------------------------------------------------------
// Kernel 3b (fallback): out = attn @ Wo^T + bo with Wo fragments.
// ---------------------------------------------------------------------------
__global__ __launch_bounds__(256, 3) void out_proj_kernel(
    const _Float16* __restrict__ attn_hi, const _Float16* __restrict__ attn_lo,
    const _Float16* __restrict__ wo_hi, const _Float16* __restrict__ wo_lo,
    const float* __restrict__ bo, float* __restrict__ out)
{
    const int tid = threadIdx.x;
    const int lane = tid & 63, wave = tid >> 6, quad = lane >> 4, l15 = lane & 15;
    const int n0 = blockIdx.x * 64;
    const size_t m0 = (size_t)blockIdx.y * 128;

    __shared__ __align__(16) char smem[49152];
    float* cs = (float*)smem;

    const size_t ap0 = (m0 >> 6) * 32, ap1 = ap0 + 32;
    const size_t bpn = (size_t)(n0 >> 6) * 32;

    auto stage = [&](int p, int s) {
        char* dst = smem + p * 24576 + tid * 16;
        const size_t co = (size_t)s * 2048 + tid * 8;
        gload16(&attn_hi[ap0 * 2048 + co], dst);
        gload16(&attn_hi[ap1 * 2048 + co], dst + 4096);
        gload16(&attn_lo[ap0 * 2048 + co], dst + 8192);
        gload16(&attn_lo[ap1 * 2048 + co], dst + 12288);
        gload16(&wo_hi[(bpn + s) * 2048 + tid * 8], dst + 16384);
        gload16(&wo_lo[(bpn + s) * 2048 + tid * 8], dst + 20480);
    };

    const int panel = wave >> 1;
    f32x4 acc_h[2][4] = {}, acc_c[2][4] = {};
    stage(0, 0);
    for (int s = 0; s < 32; ++s) {
        const int p = s & 1;
        if (s < 31) {
            stage(p ^ 1, s + 1);
            asm volatile("s_waitcnt vmcnt(6)" ::: "memory");
        } else {
            asm volatile("s_waitcnt vmcnt(0)" ::: "memory");
        }
        __builtin_amdgcn_s_barrier();
        __builtin_amdgcn_sched_barrier(0);
        const char* bufc = smem + p * 24576;
        f16x8 afh[2], afl[2], bfh[4], bfl[4];
        #pragma unroll
        for (int mt = 0; mt < 2; ++mt) {
            int rbl = (wave & 1) * 2 + mt;
            afh[mt] = *(const f16x8*)((const _Float16*)(bufc + panel * 4096) + rbl * 512 + lane * 8);
            afl[mt] = *(const f16x8*)((const _Float16*)(bufc + 8192 + panel * 4096) + rbl * 512 + lane * 8);
        }
        #pragma unroll
        for (int nt = 0; nt < 4; ++nt) {
            bfh[nt] = *(const f16x8*)((const _Float16*)(bufc + 16384) + nt * 512 + lane * 8);
            bfl[nt] = *(const f16x8*)((const _Float16*)(bufc + 20480) + nt * 512 + lane * 8);
        }
        #pragma unroll
        for (int mt = 0; mt < 2; ++mt)
            #pragma unroll
            for (int nt = 0; nt < 4; ++nt) {
                acc_h[mt][nt] = mfma_f16(afh[mt], bfh[nt], acc_h[mt][nt]);
                acc_c[mt][nt] = mfma_f16(afh[mt], bfl[nt], acc_c[mt][nt]);
                acc_c[mt][nt] = mfma_f16(afl[mt], bfh[nt], acc_c[mt][nt]);
            }
        __builtin_amdgcn_s_barrier();
        __builtin_amdgcn_sched_barrier(0);
    }

    {
        float bia[4];
        #pragma unroll
        for (int nt = 0; nt < 4; ++nt) bia[nt] = bo[n0 + nt * 16 + l15];
        #pragma unroll
        for (int mt = 0; mt < 2; ++mt)
            #pragma unroll
            for (int nt = 0; nt < 4; ++nt)
                #pragma unroll
                for (int r = 0; r < 4; ++r) {
                    int t = wave * 32 + mt * 16 + quad * 4 + r;
                    cs[t * 64 + nt * 16 + l15] =
                        acc_h[mt][nt][r] + INV_LOSCALE * acc_c[mt][nt][r] + bia[nt];
                }
    }
    __syncthreads();
    #pragma unroll
    for (int it = 0; it < 8; ++it) {
        int idx = it * 256 + tid;
        int r = idx >> 4, c = (idx & 15) * 4;
        *(f32x4*)&out[(m0 + r) * DM + n0 + c] = *(f32x4*)&cs[r * 64 + c];
    }
}

// ---------------------------------------------------------------------------
extern "C" void kernel_launch(void* const* d_in, const int* in_sizes, int n_in,
                              void* d_out, int out_size, void* d_ws, size_t ws_size,
                              hipStream_t stream) {
    const float* q  = (const float*)d_in[0];
    const float* kv = (const float*)d_in[1];
    const float* Wq = (const float*)d_in[2];
    const float* bq = (const float*)d_in[3];
    const float* Wk = (const float*)d_in[4];
    const float* bk = (const float*)d_in[5];
    const float* Wv = (const float*)d_in[6];
    const float* bv = (const float*)d_in[7];
    const float* Wo = (const float*)d_in[8];
    const float* bo = (const float*)d_in[9];
    float* out = (float*)d_out;

    // workspace: fixed ~85 MB; big path adds q frags (+134 MB) + Pt (+16 MB).
    char* p = (char*)d_ws;
    float* kv_sum = (float*)p;              p += (size_t)BSZ * NH * HD * HD * 4;
    float* ksum   = (float*)p;              p += (size_t)BSZ * NH * HD * 4;
    _Float16* wqt_hi = (_Float16*)p;        p += (size_t)NH * HD * DM * 2;
    _Float16* wqt_lo = (_Float16*)p;        p += (size_t)NH * HD * DM * 2;
    _Float16* wkt_hi = (_Float16*)p;        p += (size_t)NH * HD * DM * 2;
    _Float16* wkt_lo = (_Float16*)p;        p += (size_t)NH * HD * DM * 2;
    _Float16* wvt_hi = (_Float16*)p;        p += (size_t)NH * HD * DM * 2;
    _Float16* wvt_lo = (_Float16*)p;        p += (size_t)NH * HD * DM * 2;
    _Float16* wo_hi  = (_Float16*)p;        p += (size_t)DM * DM * 2;
    _Float16* wo_lo  = (_Float16*)p;        p += (size_t)DM * DM * 2;
    _Float16* buf_hi = (_Float16*)p;        p += (size_t)BT * DM * 2;   // kv frags, then qz/attn
    _Float16* buf_lo = (_Float16*)p;        p += (size_t)BT * DM * 2;
    _Float16* qf_hi  = (_Float16*)p;        p += (size_t)BT * DM * 2;   // big: q frags
    _Float16* qf_lo  = (_Float16*)p;        p += (size_t)BT * DM * 2;
    _Float16* pt_hi  = (_Float16*)p;        p += (size_t)BSZ * DM * DM * 2;  // big: Pt
    _Float16* pt_lo  = (_Float16*)p;        p += (size_t)BSZ * DM * DM * 2;
    const bool big = ws_size >= (size_t)(p - (char*)d_ws);

    size_t zero_bytes = ((size_t)BSZ * NH * HD * HD + (size_t)BSZ * NH * HD) * sizeof(float);
    hipMemsetAsync(d_ws, 0, zero_bytes, stream);

    fragsplit_kernel<<<(BT * DM / 8) / 256, 256, 0, stream>>>(kv, buf_hi, buf_lo);
    wsplit_kernel<<<dim3(DM / 64, NH, 3), 256, 0, stream>>>(
        Wq, Wk, Wv, wqt_hi, wqt_lo, wkt_hi, wkt_lo, wvt_hi, wvt_lo);
    if (!big)
        fragsplit_kernel<<<(DM * DM / 8) / 256, 256, 0, stream>>>(Wo, wo_hi, wo_lo);

    kv_stats_kernel<<<NH * (TSEQ / 256) * BSZ, 256, 0, stream>>>(
        buf_hi, buf_lo, wkt_hi, wkt_lo, wvt_hi, wvt_lo, bk, bv, kv_sum, ksum);

    if (big) {
        fragsplit_kernel<<<(BT * DM / 8) / 256, 256, 0, stream>>>(q, qf_hi, qf_lo);
        pmat_kernel<<<dim3(16, NH, BSZ), 256, 0, stream>>>(kv_sum, Wo, pt_hi, pt_lo);
        q_attn_ps_kernel<<<NH * (TSEQ / 128) * BSZ, 256, 0, stream>>>(
            qf_hi, qf_lo, wqt_hi, wqt_lo, bq, ksum, buf_hi);
        out_proj_p_kernel<<<(DM / 64) * (BT / 128), 256, 0, stream>>>(
            buf_hi, pt_hi, pt_lo, bo, out);
    } else {
        q_attn_kernel<<<dim3(TSEQ / 64, NH, BSZ), 256, 0, stream>>>(
            q, wqt_hi, wqt_lo, bq, kv_sum, ksum, buf_hi, buf_lo);
        out_proj_kernel<<<dim3(DM / 64, BT / 128), 256, 0, stream>>>(
            buf_hi, buf_lo, wo_hi, wo_lo, bo, out);
    }
}